// Round 10
// baseline (408.341 us; speedup 1.0000x reference)
//
#include <hip/hip_runtime.h>
#include <hip/hip_bf16.h>

#define NB 2
#define NS 2048
#define NH 16
#define ND 128
#define HID2 2048
#define MROWS 4096   // NB*NS

typedef __bf16 bf16;
typedef bf16 bf16x8 __attribute__((ext_vector_type(8)));
typedef bf16 bf16x4 __attribute__((ext_vector_type(4)));
typedef float f32x4 __attribute__((ext_vector_type(4)));
typedef unsigned int u32;

#define GLOBAL_AS __attribute__((address_space(1)))
#define LDS_AS __attribute__((address_space(3)))

__device__ __forceinline__ void async16(void* lds, const void* g) {
    __builtin_amdgcn_global_load_lds((const GLOBAL_AS u32*)g, (LDS_AS u32*)lds, 16, 0, 0);
}

// ---------------------------------------------------------------- converts
__global__ void cvt_f32_bf16(const float* __restrict__ src, bf16* __restrict__ dst, int n8) {
    int i = blockIdx.x * blockDim.x + threadIdx.x;
    if (i >= n8) return;
    const float4* s4 = (const float4*)src;
    float4 a = s4[2 * i], b = s4[2 * i + 1];
    bf16x8 o;
    o[0] = (bf16)a.x; o[1] = (bf16)a.y; o[2] = (bf16)a.z; o[3] = (bf16)a.w;
    o[4] = (bf16)b.x; o[5] = (bf16)b.y; o[6] = (bf16)b.z; o[7] = (bf16)b.w;
    ((bf16x8*)dst)[i] = o;
}

__global__ void cvt_w4(const float* __restrict__ Wq, const float* __restrict__ Wk,
                       const float* __restrict__ Wv, const float* __restrict__ Wo,
                       bf16* __restrict__ dst) {
    int z = blockIdx.y;
    const float* src = (z == 0) ? Wq : (z == 1) ? Wk : (z == 2) ? Wv : Wo;
    int i = blockIdx.x * blockDim.x + threadIdx.x;
    const float4* s4 = (const float4*)src;
    float4 a = s4[2 * i], b = s4[2 * i + 1];
    bf16x8 o;
    o[0] = (bf16)a.x; o[1] = (bf16)a.y; o[2] = (bf16)a.z; o[3] = (bf16)a.w;
    o[4] = (bf16)b.x; o[5] = (bf16)b.y; o[6] = (bf16)b.z; o[7] = (bf16)b.w;
    ((bf16x8*)(dst + (size_t)z * HID2 * HID2))[i] = o;
}

__global__ void qscale_kernel(const float* qr, const float* qi, const float* qm,
                              const float* kr, const float* ki, const float* km,
                              const float* vr, const float* vi, const float* vm,
                              float* out) {
    int i = blockIdx.x * blockDim.x + threadIdx.x;
    if (i >= HID2) return;
    out[i]            = sqrtf(qr[i] * qr[i] + qi[i] * qi[i]) * fabsf(qm[i]);
    out[HID2 + i]     = sqrtf(kr[i] * kr[i] + ki[i] * ki[i]) * fabsf(km[i]);
    out[2 * HID2 + i] = sqrtf(vr[i] * vr[i] + vi[i] * vi[i]) * fabsf(vm[i]);
}

// ---------------------------------------------------------------- loose GEMM (runtime mode, 3 blocks/CU)
// C[M,N] = A[M,K] @ Bt[N,K]^T. Block tile 128x256, BK=64, 4 waves (2M x 2N),
// per-wave 64x128 out (acc[4][8]). stage-all -> sync -> compute -> sync.
// SINGLE instantiation (runtime mode) so LDS stays 48KB -> 3 blocks/CU,
// all 768 blocks co-resident, no dispatch tail. Swizzle (r&7)<<4: 0-conflict.
// mode 0: bf16 out = |acc+bias|*scale (row-major)
// mode 2: bf16 out = |acc+bias|*scale transposed to Vt[(b*16+h)*128+d][s]
__device__ __forceinline__ void stage12(const char* gA, const char* gB,
                                        char* sa, char* sb, int w, int lane, size_t kb) {
    int r8 = lane >> 3;
    int cx = (lane & 7) * 16;
#pragma unroll
    for (int j = 0; j < 4; ++j) {
        int r = w * 32 + j * 8 + r8;
        async16(sa + (w * 32 + j * 8) * 128,
                gA + (size_t)r * (HID2 * 2) + kb + (cx ^ ((r & 7) << 4)));
    }
#pragma unroll
    for (int j = 0; j < 8; ++j) {
        int r = w * 64 + j * 8 + r8;
        async16(sb + (w * 64 + j * 8) * 128,
                gB + (size_t)r * (HID2 * 2) + kb + (cx ^ ((r & 7) << 4)));
    }
}

__global__ __launch_bounds__(256, 3) void gemm_qkv(
    const bf16* __restrict__ X, const bf16* __restrict__ Wb,
    const float* __restrict__ bq, const float* __restrict__ bk, const float* __restrict__ bv,
    const float* __restrict__ scales, bf16* __restrict__ QKV, bf16* __restrict__ Vt) {
    __shared__ bf16 sA[128 * 64];   // 16 KB
    __shared__ bf16 sB[256 * 64];   // 32 KB
    int z = blockIdx.y;
    int bid = blockIdx.x;             // 0..255 per z; all 768 blocks co-resident (3/CU)
    int tn = bid & 7, tm = bid >> 3;  // XCD p keeps B-panel p L2-resident
    const bf16* A = X;
    const bf16* Bt = Wb + (size_t)z * HID2 * HID2;
    const float* bias = (z == 0) ? bq : (z == 1) ? bk : bv;
    const float* scale = scales + z * HID2;
    bf16* Cq = QKV + (size_t)z * MROWS * HID2;   // used for z=0,1

    int tid = threadIdx.x, w = tid >> 6, lane = tid & 63;
    int wr = w >> 1, wc = w & 1;
    int l15 = lane & 15, l4 = lane >> 4;
    int xorb = (l15 & 7) << 4;

    const char* gA = (const char*)A + (size_t)tm * 128 * (HID2 * 2);
    const char* gB = (const char*)Bt + (size_t)tn * 256 * (HID2 * 2);
    const char* pa = (const char*)sA;
    const char* pb = (const char*)sB;

    f32x4 acc[4][8] = {};

    for (int t = 0; t < HID2 / 64; ++t) {
        stage12(gA, gB, (char*)sA, (char*)sB, w, lane, (size_t)t * 128);
        __syncthreads();
#pragma unroll
        for (int kk = 0; kk < 2; ++kk) {
            int kc = (kk * 64 + l4 * 16) ^ xorb;
            bf16x8 af[4], bg[4];
#pragma unroll
            for (int m = 0; m < 4; ++m)
                af[m] = *(const bf16x8*)(pa + (wr * 64 + m * 16 + l15) * 128 + kc);
#pragma unroll
            for (int n = 0; n < 4; ++n)
                bg[n] = *(const bf16x8*)(pb + (wc * 128 + n * 16 + l15) * 128 + kc);
#pragma unroll
            for (int m = 0; m < 4; ++m)
#pragma unroll
                for (int n = 0; n < 4; ++n)
                    acc[m][n] = __builtin_amdgcn_mfma_f32_16x16x32_bf16(af[m], bg[n], acc[m][n], 0, 0, 0);
#pragma unroll
            for (int n = 0; n < 4; ++n)
                bg[n] = *(const bf16x8*)(pb + (wc * 128 + (n + 4) * 16 + l15) * 128 + kc);
#pragma unroll
            for (int m = 0; m < 4; ++m)
#pragma unroll
                for (int n = 0; n < 4; ++n)
                    acc[m][n + 4] = __builtin_amdgcn_mfma_f32_16x16x32_bf16(af[m], bg[n], acc[m][n + 4], 0, 0, 0);
        }
        __syncthreads();
    }

    // epilogue (runtime branch, executed once)
#pragma unroll
    for (int n = 0; n < 8; ++n) {
        int col = tn * 256 + wc * 128 + n * 16 + l15;
        float bv2 = bias[col];
        float sc = scale[col];
#pragma unroll
        for (int m = 0; m < 4; ++m) {
            int row = tm * 128 + wr * 64 + m * 16 + l4 * 4;
            if (z != 2) {
#pragma unroll
                for (int r = 0; r < 4; ++r)
                    Cq[(size_t)(row + r) * HID2 + col] = (bf16)(fabsf(acc[m][n][r] + bv2) * sc);
            } else {
                int h = col >> 7, d = col & 127;
                int bb = row >> 11, s = row & 2047;
                bf16x4 pv;
#pragma unroll
                for (int r = 0; r < 4; ++r)
                    pv[r] = (bf16)(fabsf(acc[m][n][r] + bv2) * sc);
                *(bf16x4*)(Vt + ((size_t)(bb * NH + h) * ND + d) * NS + s) = pv;
            }
        }
    }
}

// ---------------------------------------------------------------- phased GEMM (r8, for out)
__device__ __forceinline__ void stage2A(const char* gA, char* sa, int w, int lane, size_t kb) {
#pragma unroll
    for (int j = 0; j < 2; ++j) {
        int r = w * 16 + j * 8 + (lane >> 3);
        async16(sa + (w * 16 + j * 8) * 128,
                gA + (size_t)r * (HID2 * 2) + kb + (((lane & 7) * 16) ^ ((r & 7) << 4)));
    }
}
__device__ __forceinline__ void stage2B(const char* gB, char* sb, int w, int lane, int half, size_t kb) {
#pragma unroll
    for (int j = 0; j < 2; ++j) {
        int r = half * 128 + w * 16 + j * 8 + (lane >> 3);
        async16(sb + (half * 128 + w * 16 + j * 8) * 128,
                gB + (size_t)r * (HID2 * 2) + kb + (((lane & 7) * 16) ^ ((r & 7) << 4)));
    }
}

#define G_BARRIER() do { asm volatile("" ::: "memory"); __builtin_amdgcn_s_barrier(); \
                         asm volatile("" ::: "memory"); } while (0)

__global__ __launch_bounds__(512, 2) void gemm_out(
    const bf16* __restrict__ Ctx, const bf16* __restrict__ Wo,
    const float* __restrict__ bo, float* __restrict__ out) {
    __shared__ bf16 sA[3][128 * 64];
    __shared__ bf16 sB[3][256 * 64];
    const int NT = HID2 / 64;  // 32
    int bid = blockIdx.x;             // 0..255 = 1 exact round
    int tn = bid & 7, tm = bid >> 3;
    int tid = threadIdx.x, w = tid >> 6, lane = tid & 63;
    int wr = w >> 2, wc = w & 3;
    int l15 = lane & 15, l4 = lane >> 4;
    int xorb = (l15 & 7) << 4;

    const char* gA = (const char*)Ctx + (size_t)tm * 128 * (HID2 * 2);
    const char* gB = (const char*)Wo + (size_t)tn * 256 * (HID2 * 2);

    f32x4 acc[4][4] = {};

    stage2A(gA, (char*)sA[0], w, lane, 0);
    stage2B(gB, (char*)sB[0], w, lane, 0, 0);
    stage2B(gB, (char*)sB[0], w, lane, 1, 0);
    stage2A(gA, (char*)sA[1], w, lane, 128);
    stage2B(gB, (char*)sB[1], w, lane, 0, 128);
    stage2B(gB, (char*)sB[1], w, lane, 1, 128);
    asm volatile("s_waitcnt vmcnt(6)" ::: "memory");
    G_BARRIER();

    int cur = 0;
    for (int t = 0; t < NT; ++t) {
        const char* pa = (const char*)sA[cur];
        const char* pb = (const char*)sB[cur];
        int nb = cur + 2; if (nb >= 3) nb -= 3;
        const bool pre = (t + 2 < NT);
        size_t kb = (size_t)(t + 2) * 128;
        bf16x8 af[4], bg[4];

        {
            int kc = (l4 * 16) ^ xorb;
#pragma unroll
            for (int m = 0; m < 4; ++m)
                af[m] = *(const bf16x8*)(pa + (wr * 64 + m * 16 + l15) * 128 + kc);
#pragma unroll
            for (int n = 0; n < 4; ++n)
                bg[n] = *(const bf16x8*)(pb + (wc * 64 + n * 16 + l15) * 128 + kc);
        }
        if (pre) { stage2A(gA, (char*)sA[nb], w, lane, kb); stage2B(gB, (char*)sB[nb], w, lane, 0, kb); }
        G_BARRIER();
        asm volatile("s_waitcnt lgkmcnt(0)" ::: "memory");
        __builtin_amdgcn_sched_barrier(0);
        __builtin_amdgcn_s_setprio(1);
#pragma unroll
        for (int m = 0; m < 4; ++m)
#pragma unroll
            for (int n = 0; n < 4; ++n)
                acc[m][n] = __builtin_amdgcn_mfma_f32_16x16x32_bf16(af[m], bg[n], acc[m][n], 0, 0, 0);
        __builtin_amdgcn_s_setprio(0);
        G_BARRIER();

        {
            int kc = (64 + l4 * 16) ^ xorb;
#pragma unroll
            for (int m = 0; m < 4; ++m)
                af[m] = *(const bf16x8*)(pa + (wr * 64 + m * 16 + l15) * 128 + kc);
#pragma unroll
            for (int n = 0; n < 4; ++n)
                bg[n] = *(const bf16x8*)(pb + (wc * 64 + n * 16 + l15) * 128 + kc);
        }
        if (pre) stage2B(gB, (char*)sB[nb], w, lane, 1, kb);
        G_BARRIER();
        asm volatile("s_waitcnt lgkmcnt(0)" ::: "memory");
        __builtin_amdgcn_sched_barrier(0);
        __builtin_amdgcn_s_setprio(1);
#pragma unroll
        for (int m = 0; m < 4; ++m)
#pragma unroll
            for (int n = 0; n < 4; ++n)
                acc[m][n] = __builtin_amdgcn_mfma_f32_16x16x32_bf16(af[m], bg[n], acc[m][n], 0, 0, 0);
        __builtin_amdgcn_s_setprio(0);
        if (pre)               { asm volatile("s_waitcnt vmcnt(6)" ::: "memory"); }
        else if (t + 2 == NT)  { asm volatile("s_waitcnt vmcnt(0)" ::: "memory"); }
        G_BARRIER();

        cur = cur + 1; if (cur == 3) cur = 0;
    }

#pragma unroll
    for (int n = 0; n < 4; ++n) {
        int col = tn * 256 + wc * 64 + n * 16 + l15;
        float bv = bo[col];
#pragma unroll
        for (int m = 0; m < 4; ++m) {
            int row = tm * 128 + wr * 64 + m * 16 + l4 * 4;
#pragma unroll
            for (int r = 0; r < 4; ++r)
                out[(size_t)(row + r) * HID2 + col] = acc[m][n][r] + bv;
        }
    }
}

// ---------------------------------------------------------------- flash attention (v2)
__device__ __forceinline__ void stage_load(const bf16* __restrict__ Kp, const bf16* __restrict__ Vp,
                                           int kt, int tid, bf16x8 kreg[4], bf16x8 vreg[4]) {
#pragma unroll
    for (int i = 0; i < 4; ++i) {
        kreg[i] = *(const bf16x8*)(Kp + (size_t)(kt * 64 + i * 16 + (tid >> 4)) * HID2 + (tid & 15) * 8);
        vreg[i] = *(const bf16x8*)(Vp + (size_t)(i * 32 + (tid >> 3)) * NS + kt * 64 + (tid & 7) * 8);
    }
}

__global__ __launch_bounds__(256, 2) void flash_kernel(
    const bf16* __restrict__ Qb, const bf16* __restrict__ Kb, const bf16* __restrict__ Vt,
    const float* __restrict__ ent, const float* __restrict__ mask, bf16* __restrict__ Ctx) {
    int qt = blockIdx.x;   // 0..15
    int bh = blockIdx.y;   // 0..31
    int b = bh >> 4, h = bh & 15;
    int tid = threadIdx.x, wid = tid >> 6, lane = tid & 63;
    int l15 = lane & 15, l4 = lane >> 4;

    __shared__ bf16 Ks[64 * 136];
    __shared__ bf16 Vs[128 * 72];
    __shared__ bf16 Ps[4][32 * 72];

    const bf16* Qp = Qb + ((size_t)b * NS + qt * 128) * HID2 + h * ND;
    const bf16* Kp = Kb + (size_t)b * NS * HID2 + h * ND;
    const bf16* Vp = Vt + (size_t)(b * NH + h) * ND * NS;
    const float* maskp = mask + (size_t)b * NS;

    bf16x8 qf[2][4];
#pragma unroll
    for (int m = 0; m < 2; ++m)
#pragma unroll
        for (int kk = 0; kk < 4; ++kk)
            qf[m][kk] = *(const bf16x8*)(Qp + (size_t)(wid * 32 + m * 16 + l15) * HID2 + kk * 32 + l4 * 8);

    float eb[4];
#pragma unroll
    for (int r = 0; r < 4; ++r) eb[r] = ent[h * NH + l4 * 4 + r];
    const float RSQD = 0.08838834764831845f;

    float mrun[2], lrun[2];
    mrun[0] = mrun[1] = -INFINITY;
    lrun[0] = lrun[1] = 0.f;
    f32x4 oacc[2][8] = {};

    bf16x8 kreg[4], vreg[4];
    stage_load(Kp, Vp, 0, tid, kreg, vreg);
#pragma unroll
    for (int i = 0; i < 4; ++i) {
        *(bf16x8*)(&Ks[(i * 16 + (tid >> 4)) * 136 + (tid & 15) * 8]) = kreg[i];
        *(bf16x8*)(&Vs[(i * 32 + (tid >> 3)) * 72 + (tid & 7) * 8]) = vreg[i];
    }

    for (int kt = 0; kt < NS / 64; ++kt) {
        __syncthreads();
        if (kt + 1 < NS / 64) stage_load(Kp, Vp, kt + 1, tid, kreg, vreg);

        f32x4 s[2][4] = {};
#pragma unroll
        for (int kk = 0; kk < 4; ++kk) {
            bf16x8 kf[4];
#pragma unroll
            for (int n = 0; n < 4; ++n)
                kf[n] = *(const bf16x8*)(&Ks[(n * 16 + l15) * 136 + kk * 32 + l4 * 8]);
#pragma unroll
            for (int m = 0; m < 2; ++m)
#pragma unroll
                for (int n = 0; n < 4; ++n)
                    s[m][n] = __builtin_amdgcn_mfma_f32_16x16x32_bf16(kf[n], qf[m][kk], s[m][n], 0, 0, 0);
        }

        float4 mk[4];
#pragma unroll
        for (int n = 0; n < 4; ++n)
            mk[n] = *(const float4*)(maskp + kt * 64 + n * 16 + l4 * 4);

#pragma unroll
        for (int mq = 0; mq < 2; ++mq) {
            float sv[4][4];
#pragma unroll
            for (int n = 0; n < 4; ++n) {
                sv[n][0] = s[mq][n][0] * RSQD + eb[0] + mk[n].x;
                sv[n][1] = s[mq][n][1] * RSQD + eb[1] + mk[n].y;
                sv[n][2] = s[mq][n][2] * RSQD + eb[2] + mk[n].z;
                sv[n][3] = s[mq][n][3] * RSQD + eb[3] + mk[n].w;
            }
            float tmax = sv[0][0];
#pragma unroll
            for (int n = 0; n < 4; ++n)
#pragma unroll
                for (int r = 0; r < 4; ++r) tmax = fmaxf(tmax, sv[n][r]);
            tmax = fmaxf(tmax, __shfl_xor(tmax, 16));
            tmax = fmaxf(tmax, __shfl_xor(tmax, 32));

            if (__any(tmax > mrun[mq] + 8.0f)) {
                float mnew = fmaxf(mrun[mq], tmax);
                float corr = __expf(mrun[mq] - mnew);
                mrun[mq] = mnew;
                lrun[mq] *= corr;
#pragma unroll
                for (int r = 0; r < 4; ++r) {
                    float cr = __shfl(corr, l4 * 4 + r);
#pragma unroll
                    for (int n = 0; n < 8; ++n) oacc[mq][n][r] *= cr;
                }
            }

            float psum = 0.f;
#pragma unroll
            for (int n = 0; n < 4; ++n) {
                bf16x4 pv;
#pragma unroll
                for (int r = 0; r < 4; ++r) {
                    float p = __expf(sv[n][r] - mrun[mq]);
                    psum += p;
                    pv[r] = (bf16)p;
                }
                *(bf16x4*)(&Ps[wid][(mq * 16 + l15) * 72 + n * 16 + l4 * 4]) = pv;
            }
            psum += __shfl_xor(psum, 16);
            psum += __shfl_xor(psum, 32);
            lrun[mq] += psum;
        }

#pragma unroll
        for (int kk = 0; kk < 2; ++kk) {
            bf16x8 pa[2], vb[8];
#pragma unroll
            for (int m = 0; m < 2; ++m)
                pa[m] = *(const bf16x8*)(&Ps[wid][(m * 16 + l15) * 72 + kk * 32 + l4 * 8]);
#pragma unroll
            for (int n = 0; n < 8; ++n)
                vb[n] = *(const bf16x8*)(&Vs[(n * 16 + l15) * 72 + kk * 32 + l4 * 8]);
#pragma unroll
            for (int m = 0; m < 2; ++m)
#pragma unroll
                for (int n = 0; n < 8; ++n)
                    oacc[m][n] = __builtin_amdgcn_mfma_f32_16x16x32_bf16(pa[m], vb[n], oacc[m][n], 0, 0, 0);
        }
        __syncthreads();
        if (kt + 1 < NS / 64) {
#pragma unroll
            for (int i = 0; i < 4; ++i) {
                *(bf16x8*)(&Ks[(i * 16 + (tid >> 4)) * 136 + (tid & 15) * 8]) = kreg[i];
                *(bf16x8*)(&Vs[(i * 32 + (tid >> 3)) * 72 + (tid & 7) * 8]) = vreg[i];
            }
        }
    }

#pragma unroll
    for (int m = 0; m < 2; ++m) {
        float inv = 1.0f / lrun[m];
        float invr[4];
#pragma unroll
        for (int r = 0; r < 4; ++r) invr[r] = __shfl(inv, l4 * 4 + r);
#pragma unroll
        for (int r = 0; r < 4; ++r) {
            int row = qt * 128 + wid * 32 + m * 16 + l4 * 4 + r;
            bf16* Cp = Ctx + ((size_t)b * NS + row) * HID2 + h * ND;
#pragma unroll
            for (int n = 0; n < 8; ++n)
                Cp[n * 16 + l15] = (bf16)(oacc[m][n][r] * invr[r]);
        }
    }
}

// ---------------------------------------------------------------- launch
extern "C" void kernel_launch(void* const* d_in, const int* in_sizes, int n_in,
                              void* d_out, int out_size, void* d_ws, size_t ws_size,
                              hipStream_t stream) {
    const float* hidden = (const float*)d_in[0];
    const float* mask   = (const float*)d_in[1];
    const float* q_real = (const float*)d_in[2];
    const float* q_imag = (const float*)d_in[3];
    const float* q_mag  = (const float*)d_in[5];
    const float* k_real = (const float*)d_in[6];
    const float* k_imag = (const float*)d_in[7];
    const float* k_mag  = (const float*)d_in[9];
    const float* v_real = (const float*)d_in[10];
    const float* v_imag = (const float*)d_in[11];
    const float* v_mag  = (const float*)d_in[13];
    const float* Wq = (const float*)d_in[14];
    const float* bq = (const float*)d_in[15];
    const float* Wk = (const float*)d_in[16];
    const float* bk = (const float*)d_in[17];
    const float* Wv = (const float*)d_in[18];
    const float* bv = (const float*)d_in[19];
    const float* Wo = (const float*)d_in[20];
    const float* bo = (const float*)d_in[21];
    const float* ent = (const float*)d_in[22];

    char* ws = (char*)d_ws;
    bf16* Xb    = (bf16*)(ws);
    bf16* Wb    = (bf16*)(ws + 16777216);        // Wq,Wk,Wv,Wo bf16 contiguous
    bf16* Wob   = (bf16*)(ws + 41943040);
    bf16* QKV   = (bf16*)(ws + 50331648);        // Q,K bf16 (V slot unused)
    bf16* Vt    = (bf16*)(ws + 100663296);
    bf16* Ctx   = (bf16*)(ws + 117440512);
    float* scales = (float*)(ws + 134217728);

    cvt_f32_bf16<<<4096, 256, 0, stream>>>(hidden, Xb, MROWS * HID2 / 8);
    cvt_w4<<<dim3(2048, 4), 256, 0, stream>>>(Wq, Wk, Wv, Wo, Wb);
    qscale_kernel<<<8, 256, 0, stream>>>(q_real, q_imag, q_mag, k_real, k_imag, k_mag,
                                         v_real, v_imag, v_mag, scales);
    gemm_qkv<<<dim3(256, 3), 256, 0, stream>>>(Xb, Wb, bq, bk, bv, scales, QKV, Vt);
    flash_kernel<<<dim3(16, 32), 256, 0, stream>>>(QKV, QKV + (size_t)MROWS * HID2, Vt, ent, mask, Ctx);
    gemm_out<<<256, 512, 0, stream>>>(Ctx, Wob, bo, (float*)d_out);
}

// Round 11
// 294.467 us; speedup vs baseline: 1.3867x; 1.3867x over previous
//
#include <hip/hip_runtime.h>
#include <hip/hip_bf16.h>

#define NB 2
#define NS 2048
#define NH 16
#define ND 128
#define HID2 2048
#define MROWS 4096   // NB*NS

typedef __bf16 bf16;
typedef bf16 bf16x8 __attribute__((ext_vector_type(8)));
typedef bf16 bf16x4 __attribute__((ext_vector_type(4)));
typedef float f32x4 __attribute__((ext_vector_type(4)));
typedef unsigned int u32;

#define GLOBAL_AS __attribute__((address_space(1)))
#define LDS_AS __attribute__((address_space(3)))

__device__ __forceinline__ void async16(void* lds, const void* g) {
    __builtin_amdgcn_global_load_lds((const GLOBAL_AS u32*)g, (LDS_AS u32*)lds, 16, 0, 0);
}

// ---------------------------------------------------------------- converts
__global__ void cvt_f32_bf16(const float* __restrict__ src, bf16* __restrict__ dst, int n8) {
    int i = blockIdx.x * blockDim.x + threadIdx.x;
    if (i >= n8) return;
    const float4* s4 = (const float4*)src;
    float4 a = s4[2 * i], b = s4[2 * i + 1];
    bf16x8 o;
    o[0] = (bf16)a.x; o[1] = (bf16)a.y; o[2] = (bf16)a.z; o[3] = (bf16)a.w;
    o[4] = (bf16)b.x; o[5] = (bf16)b.y; o[6] = (bf16)b.z; o[7] = (bf16)b.w;
    ((bf16x8*)dst)[i] = o;
}

__global__ void cvt_w4(const float* __restrict__ Wq, const float* __restrict__ Wk,
                       const float* __restrict__ Wv, const float* __restrict__ Wo,
                       bf16* __restrict__ dst) {
    int z = blockIdx.y;
    const float* src = (z == 0) ? Wq : (z == 1) ? Wk : (z == 2) ? Wv : Wo;
    int i = blockIdx.x * blockDim.x + threadIdx.x;
    const float4* s4 = (const float4*)src;
    float4 a = s4[2 * i], b = s4[2 * i + 1];
    bf16x8 o;
    o[0] = (bf16)a.x; o[1] = (bf16)a.y; o[2] = (bf16)a.z; o[3] = (bf16)a.w;
    o[4] = (bf16)b.x; o[5] = (bf16)b.y; o[6] = (bf16)b.z; o[7] = (bf16)b.w;
    ((bf16x8*)(dst + (size_t)z * HID2 * HID2))[i] = o;
}

// Q scale absorbs 1/sqrt(D): flash softmax then skips the per-element mul.
__global__ void qscale_kernel(const float* qr, const float* qi, const float* qm,
                              const float* kr, const float* ki, const float* km,
                              const float* vr, const float* vi, const float* vm,
                              float* out) {
    int i = blockIdx.x * blockDim.x + threadIdx.x;
    if (i >= HID2) return;
    const float RSQD = 0.08838834764831845f;  // 1/sqrt(128)
    out[i]            = sqrtf(qr[i] * qr[i] + qi[i] * qi[i]) * fabsf(qm[i]) * RSQD;
    out[HID2 + i]     = sqrtf(kr[i] * kr[i] + ki[i] * ki[i]) * fabsf(km[i]);
    out[2 * HID2 + i] = sqrtf(vr[i] * vr[i] + vi[i] * vi[i]) * fabsf(vm[i]);
}

// ---------------------------------------------------------------- loose GEMM (r7-exact)
// C[M,N] = A[M,K] @ Bt[N,K]^T. Block tile 128x256, BK=64, 4 waves (2M x 2N),
// per-wave 64x128 out (acc[4][8]). stage-all -> sync -> compute -> sync.
// launch_bounds(256,2): 2 blocks/CU, NO tighter (3/CU spills acc -> r10 252us).
// Swizzle byte ^= (r&7)<<4: proven zero-conflict (r5/r7).
__device__ __forceinline__ void stage12(const char* gA, const char* gB,
                                        char* sa, char* sb, int w, int lane, size_t kb) {
    int r8 = lane >> 3;
    int cx = (lane & 7) * 16;
#pragma unroll
    for (int j = 0; j < 4; ++j) {
        int r = w * 32 + j * 8 + r8;
        async16(sa + (w * 32 + j * 8) * 128,
                gA + (size_t)r * (HID2 * 2) + kb + (cx ^ ((r & 7) << 4)));
    }
#pragma unroll
    for (int j = 0; j < 8; ++j) {
        int r = w * 64 + j * 8 + r8;
        async16(sb + (w * 64 + j * 8) * 128,
                gB + (size_t)r * (HID2 * 2) + kb + (cx ^ ((r & 7) << 4)));
    }
}

__global__ __launch_bounds__(256, 2) void gemm_qkv(
    const bf16* __restrict__ X, const bf16* __restrict__ Wb,
    const float* __restrict__ bq, const float* __restrict__ bk, const float* __restrict__ bv,
    const float* __restrict__ scales, bf16* __restrict__ QKV) {
    __shared__ bf16 sA[128 * 64];   // 16 KB
    __shared__ bf16 sB[256 * 64];   // 32 KB
    int bid = blockIdx.x;           // 0..767
    int p = bid & 7, q = bid >> 3;  // XCD p keeps B-panel p resident per z
    int z = q >> 5, tm = q & 31, tn = p;
    const bf16* Bt = Wb + (size_t)z * HID2 * HID2;
    const float* bias = (z == 0) ? bq : (z == 1) ? bk : bv;
    const float* scale = scales + z * HID2;
    bf16* Cout = QKV + (size_t)z * MROWS * HID2;

    int tid = threadIdx.x, w = tid >> 6, lane = tid & 63;
    int wr = w >> 1, wc = w & 1;
    int l15 = lane & 15, l4 = lane >> 4;
    int xorb = (l15 & 7) << 4;

    const char* gA = (const char*)X + (size_t)tm * 128 * (HID2 * 2);
    const char* gB = (const char*)Bt + (size_t)tn * 256 * (HID2 * 2);
    const char* pa = (const char*)sA;
    const char* pb = (const char*)sB;

    f32x4 acc[4][8] = {};

    for (int t = 0; t < HID2 / 64; ++t) {
        stage12(gA, gB, (char*)sA, (char*)sB, w, lane, (size_t)t * 128);
        __syncthreads();
#pragma unroll
        for (int kk = 0; kk < 2; ++kk) {
            int kc = (kk * 64 + l4 * 16) ^ xorb;
            bf16x8 af[4], bg[4];
#pragma unroll
            for (int m = 0; m < 4; ++m)
                af[m] = *(const bf16x8*)(pa + (wr * 64 + m * 16 + l15) * 128 + kc);
#pragma unroll
            for (int n = 0; n < 4; ++n)
                bg[n] = *(const bf16x8*)(pb + (wc * 128 + n * 16 + l15) * 128 + kc);
#pragma unroll
            for (int m = 0; m < 4; ++m)
#pragma unroll
                for (int n = 0; n < 4; ++n)
                    acc[m][n] = __builtin_amdgcn_mfma_f32_16x16x32_bf16(af[m], bg[n], acc[m][n], 0, 0, 0);
#pragma unroll
            for (int n = 0; n < 4; ++n)
                bg[n] = *(const bf16x8*)(pb + (wc * 128 + (n + 4) * 16 + l15) * 128 + kc);
#pragma unroll
            for (int m = 0; m < 4; ++m)
#pragma unroll
                for (int n = 0; n < 4; ++n)
                    acc[m][n + 4] = __builtin_amdgcn_mfma_f32_16x16x32_bf16(af[m], bg[n], acc[m][n + 4], 0, 0, 0);
        }
        __syncthreads();
    }

    // epilogue: bf16 out = |acc + bias| * scale
#pragma unroll
    for (int n = 0; n < 8; ++n) {
        int col = tn * 256 + wc * 128 + n * 16 + l15;
        float bv2 = bias[col];
        float sc = scale[col];
#pragma unroll
        for (int m = 0; m < 4; ++m) {
            int row = tm * 128 + wr * 64 + m * 16 + l4 * 4;
#pragma unroll
            for (int r = 0; r < 4; ++r)
                Cout[(size_t)(row + r) * HID2 + col] = (bf16)(fabsf(acc[m][n][r] + bv2) * sc);
        }
    }
}

// ---------------------------------------------------------------- phased GEMM (r8, for out)
__device__ __forceinline__ void stage2A(const char* gA, char* sa, int w, int lane, size_t kb) {
#pragma unroll
    for (int j = 0; j < 2; ++j) {
        int r = w * 16 + j * 8 + (lane >> 3);
        async16(sa + (w * 16 + j * 8) * 128,
                gA + (size_t)r * (HID2 * 2) + kb + (((lane & 7) * 16) ^ ((r & 7) << 4)));
    }
}
__device__ __forceinline__ void stage2B(const char* gB, char* sb, int w, int lane, int half, size_t kb) {
#pragma unroll
    for (int j = 0; j < 2; ++j) {
        int r = half * 128 + w * 16 + j * 8 + (lane >> 3);
        async16(sb + (half * 128 + w * 16 + j * 8) * 128,
                gB + (size_t)r * (HID2 * 2) + kb + (((lane & 7) * 16) ^ ((r & 7) << 4)));
    }
}

#define G_BARRIER() do { asm volatile("" ::: "memory"); __builtin_amdgcn_s_barrier(); \
                         asm volatile("" ::: "memory"); } while (0)

__global__ __launch_bounds__(512, 2) void gemm_out(
    const bf16* __restrict__ Ctx, const bf16* __restrict__ Wo,
    const float* __restrict__ bo, float* __restrict__ out) {
    __shared__ bf16 sA[3][128 * 64];
    __shared__ bf16 sB[3][256 * 64];
    const int NT = HID2 / 64;  // 32
    int bid = blockIdx.x;             // 0..255 = 1 exact round
    int tn = bid & 7, tm = bid >> 3;
    int tid = threadIdx.x, w = tid >> 6, lane = tid & 63;
    int wr = w >> 2, wc = w & 3;
    int l15 = lane & 15, l4 = lane >> 4;
    int xorb = (l15 & 7) << 4;

    const char* gA = (const char*)Ctx + (size_t)tm * 128 * (HID2 * 2);
    const char* gB = (const char*)Wo + (size_t)tn * 256 * (HID2 * 2);

    f32x4 acc[4][4] = {};

    stage2A(gA, (char*)sA[0], w, lane, 0);
    stage2B(gB, (char*)sB[0], w, lane, 0, 0);
    stage2B(gB, (char*)sB[0], w, lane, 1, 0);
    stage2A(gA, (char*)sA[1], w, lane, 128);
    stage2B(gB, (char*)sB[1], w, lane, 0, 128);
    stage2B(gB, (char*)sB[1], w, lane, 1, 128);
    asm volatile("s_waitcnt vmcnt(6)" ::: "memory");
    G_BARRIER();

    int cur = 0;
    for (int t = 0; t < NT; ++t) {
        const char* pa = (const char*)sA[cur];
        const char* pb = (const char*)sB[cur];
        int nb = cur + 2; if (nb >= 3) nb -= 3;
        const bool pre = (t + 2 < NT);
        size_t kb = (size_t)(t + 2) * 128;
        bf16x8 af[4], bg[4];

        {
            int kc = (l4 * 16) ^ xorb;
#pragma unroll
            for (int m = 0; m < 4; ++m)
                af[m] = *(const bf16x8*)(pa + (wr * 64 + m * 16 + l15) * 128 + kc);
#pragma unroll
            for (int n = 0; n < 4; ++n)
                bg[n] = *(const bf16x8*)(pb + (wc * 64 + n * 16 + l15) * 128 + kc);
        }
        if (pre) { stage2A(gA, (char*)sA[nb], w, lane, kb); stage2B(gB, (char*)sB[nb], w, lane, 0, kb); }
        G_BARRIER();
        asm volatile("s_waitcnt lgkmcnt(0)" ::: "memory");
        __builtin_amdgcn_sched_barrier(0);
        __builtin_amdgcn_s_setprio(1);
#pragma unroll
        for (int m = 0; m < 4; ++m)
#pragma unroll
            for (int n = 0; n < 4; ++n)
                acc[m][n] = __builtin_amdgcn_mfma_f32_16x16x32_bf16(af[m], bg[n], acc[m][n], 0, 0, 0);
        __builtin_amdgcn_s_setprio(0);
        G_BARRIER();

        {
            int kc = (64 + l4 * 16) ^ xorb;
#pragma unroll
            for (int m = 0; m < 4; ++m)
                af[m] = *(const bf16x8*)(pa + (wr * 64 + m * 16 + l15) * 128 + kc);
#pragma unroll
            for (int n = 0; n < 4; ++n)
                bg[n] = *(const bf16x8*)(pb + (wc * 64 + n * 16 + l15) * 128 + kc);
        }
        if (pre) stage2B(gB, (char*)sB[nb], w, lane, 1, kb);
        G_BARRIER();
        asm volatile("s_waitcnt lgkmcnt(0)" ::: "memory");
        __builtin_amdgcn_sched_barrier(0);
        __builtin_amdgcn_s_setprio(1);
#pragma unroll
        for (int m = 0; m < 4; ++m)
#pragma unroll
            for (int n = 0; n < 4; ++n)
                acc[m][n] = __builtin_amdgcn_mfma_f32_16x16x32_bf16(af[m], bg[n], acc[m][n], 0, 0, 0);
        __builtin_amdgcn_s_setprio(0);
        if (pre)               { asm volatile("s_waitcnt vmcnt(6)" ::: "memory"); }
        else if (t + 2 == NT)  { asm volatile("s_waitcnt vmcnt(0)" ::: "memory"); }
        G_BARRIER();

        cur = cur + 1; if (cur == 3) cur = 0;
    }

#pragma unroll
    for (int n = 0; n < 4; ++n) {
        int col = tn * 256 + wc * 64 + n * 16 + l15;
        float bv = bo[col];
#pragma unroll
        for (int m = 0; m < 4; ++m) {
            int row = tm * 128 + wr * 64 + m * 16 + l4 * 4;
#pragma unroll
            for (int r = 0; r < 4; ++r)
                out[(size_t)(row + r) * HID2 + col] = acc[m][n][r] + bv;
        }
    }
}

// ---------------------------------------------------------------- V transpose
__global__ void transpose_v(const bf16* __restrict__ Vb, bf16* __restrict__ Vt) {
    int bh = blockIdx.z;
    int b = bh >> 4, h = bh & 15;
    int s0 = blockIdx.x * 64, d0 = blockIdx.y * 64;
    int tid = threadIdx.x;
    __shared__ bf16 T[64][72];
    const bf16* src = Vb + ((size_t)b * NS + s0) * HID2 + h * ND + d0;
#pragma unroll
    for (int i = 0; i < 2; ++i) {
        int r = i * 32 + (tid >> 3);
        int c = (tid & 7) * 8;
        *(bf16x8*)(&T[r][c]) = *(const bf16x8*)(src + (size_t)r * HID2 + c);
    }
    __syncthreads();
    bf16* dst = Vt + ((size_t)(b * NH + h) * ND + d0) * NS + s0;
#pragma unroll
    for (int i = 0; i < 2; ++i) {
        int dr = i * 32 + (tid >> 3);
        int sc = (tid & 7) * 8;
        bf16x8 o;
#pragma unroll
        for (int j = 0; j < 8; ++j) o[j] = T[sc + j][dr];
        *(bf16x8*)(dst + (size_t)dr * NS + sc) = o;
    }
}

// ---------------------------------------------------------------- flash attention (v3)
// Swapped QK^T; 1/sqrt(D) pre-folded into Q scale; setprio around MFMA clusters.
__device__ __forceinline__ void stage_load(const bf16* __restrict__ Kp, const bf16* __restrict__ Vp,
                                           int kt, int tid, bf16x8 kreg[4], bf16x8 vreg[4]) {
#pragma unroll
    for (int i = 0; i < 4; ++i) {
        kreg[i] = *(const bf16x8*)(Kp + (size_t)(kt * 64 + i * 16 + (tid >> 4)) * HID2 + (tid & 15) * 8);
        vreg[i] = *(const bf16x8*)(Vp + (size_t)(i * 32 + (tid >> 3)) * NS + kt * 64 + (tid & 7) * 8);
    }
}

__global__ __launch_bounds__(256, 2) void flash_kernel(
    const bf16* __restrict__ Qb, const bf16* __restrict__ Kb, const bf16* __restrict__ Vt,
    const float* __restrict__ ent, const float* __restrict__ mask, bf16* __restrict__ Ctx) {
    int qt = blockIdx.x;   // 0..15
    int bh = blockIdx.y;   // 0..31
    int b = bh >> 4, h = bh & 15;
    int tid = threadIdx.x, wid = tid >> 6, lane = tid & 63;
    int l15 = lane & 15, l4 = lane >> 4;

    __shared__ bf16 Ks[64 * 136];
    __shared__ bf16 Vs[128 * 72];
    __shared__ bf16 Ps[4][32 * 72];

    const bf16* Qp = Qb + ((size_t)b * NS + qt * 128) * HID2 + h * ND;
    const bf16* Kp = Kb + (size_t)b * NS * HID2 + h * ND;
    const bf16* Vp = Vt + (size_t)(b * NH + h) * ND * NS;
    const float* maskp = mask + (size_t)b * NS;

    bf16x8 qf[2][4];
#pragma unroll
    for (int m = 0; m < 2; ++m)
#pragma unroll
        for (int kk = 0; kk < 4; ++kk)
            qf[m][kk] = *(const bf16x8*)(Qp + (size_t)(wid * 32 + m * 16 + l15) * HID2 + kk * 32 + l4 * 8);

    float eb[4];
#pragma unroll
    for (int r = 0; r < 4; ++r) eb[r] = ent[h * NH + l4 * 4 + r];

    float mrun[2], lrun[2];
    mrun[0] = mrun[1] = -INFINITY;
    lrun[0] = lrun[1] = 0.f;
    f32x4 oacc[2][8] = {};

    bf16x8 kreg[4], vreg[4];
    stage_load(Kp, Vp, 0, tid, kreg, vreg);
#pragma unroll
    for (int i = 0; i < 4; ++i) {
        *(bf16x8*)(&Ks[(i * 16 + (tid >> 4)) * 136 + (tid & 15) * 8]) = kreg[i];
        *(bf16x8*)(&Vs[(i * 32 + (tid >> 3)) * 72 + (tid & 7) * 8]) = vreg[i];
    }

    for (int kt = 0; kt < NS / 64; ++kt) {
        __syncthreads();
        if (kt + 1 < NS / 64) stage_load(Kp, Vp, kt + 1, tid, kreg, vreg);

        f32x4 s[2][4] = {};
        __builtin_amdgcn_s_setprio(1);
#pragma unroll
        for (int kk = 0; kk < 4; ++kk) {
            bf16x8 kf[4];
#pragma unroll
            for (int n = 0; n < 4; ++n)
                kf[n] = *(const bf16x8*)(&Ks[(n * 16 + l15) * 136 + kk * 32 + l4 * 8]);
#pragma unroll
            for (int m = 0; m < 2; ++m)
#pragma unroll
                for (int n = 0; n < 4; ++n)
                    s[m][n] = __builtin_amdgcn_mfma_f32_16x16x32_bf16(kf[n], qf[m][kk], s[m][n], 0, 0, 0);
        }
        __builtin_amdgcn_s_setprio(0);

        float4 mk[4];
#pragma unroll
        for (int n = 0; n < 4; ++n)
            mk[n] = *(const float4*)(maskp + kt * 64 + n * 16 + l4 * 4);

#pragma unroll
        for (int mq = 0; mq < 2; ++mq) {
            float sv[4][4];
#pragma unroll
            for (int n = 0; n < 4; ++n) {
                sv[n][0] = s[mq][n][0] + eb[0] + mk[n].x;
                sv[n][1] = s[mq][n][1] + eb[1] + mk[n].y;
                sv[n][2] = s[mq][n][2] + eb[2] + mk[n].z;
                sv[n][3] = s[mq][n][3] + eb[3] + mk[n].w;
            }
            float tmax = sv[0][0];
#pragma unroll
            for (int n = 0; n < 4; ++n)
#pragma unroll
                for (int r = 0; r < 4; ++r) tmax = fmaxf(tmax, sv[n][r]);
            tmax = fmaxf(tmax, __shfl_xor(tmax, 16));
            tmax = fmaxf(tmax, __shfl_xor(tmax, 32));

            if (__any(tmax > mrun[mq] + 8.0f)) {
                float mnew = fmaxf(mrun[mq], tmax);
                float corr = __expf(mrun[mq] - mnew);
                mrun[mq] = mnew;
                lrun[mq] *= corr;
#pragma unroll
                for (int r = 0; r < 4; ++r) {
                    float cr = __shfl(corr, l4 * 4 + r);
#pragma unroll
                    for (int n = 0; n < 8; ++n) oacc[mq][n][r] *= cr;
                }
            }

            float psum = 0.f;
#pragma unroll
            for (int n = 0; n < 4; ++n) {
                bf16x4 pv;
#pragma unroll
                for (int r = 0; r < 4; ++r) {
                    float p = __expf(sv[n][r] - mrun[mq]);
                    psum += p;
                    pv[r] = (bf16)p;
                }
                *(bf16x4*)(&Ps[wid][(mq * 16 + l15) * 72 + n * 16 + l4 * 4]) = pv;
            }
            psum += __shfl_xor(psum, 16);
            psum += __shfl_xor(psum, 32);
            lrun[mq] += psum;
        }

        __builtin_amdgcn_s_setprio(1);
#pragma unroll
        for (int kk = 0; kk < 2; ++kk) {
            bf16x8 pa[2], vb[8];
#pragma unroll
            for (int m = 0; m < 2; ++m)
                pa[m] = *(const bf16x8*)(&Ps[wid][(m * 16 + l15) * 72 + kk * 32 + l4 * 8]);
#pragma unroll
            for (int n = 0; n < 8; ++n)
                vb[n] = *(const bf16x8*)(&Vs[(n * 16 + l15) * 72 + kk * 32 + l4 * 8]);
#pragma unroll
            for (int m = 0; m < 2; ++m)
#pragma unroll
                for (int n = 0; n < 8; ++n)
                    oacc[m][n] = __builtin_amdgcn_mfma_f32_16x16x32_bf16(pa[m], vb[n], oacc[m][n], 0, 0, 0);
        }
        __builtin_amdgcn_s_setprio(0);
        __syncthreads();
        if (kt + 1 < NS / 64) {
#pragma unroll
            for (int i = 0; i < 4; ++i) {
                *(bf16x8*)(&Ks[(i * 16 + (tid >> 4)) * 136 + (tid & 15) * 8]) = kreg[i];
                *(bf16x8*)(&Vs[(i * 32 + (tid >> 3)) * 72 + (tid & 7) * 8]) = vreg[i];
            }
        }
    }

#pragma unroll
    for (int m = 0; m < 2; ++m) {
        float inv = 1.0f / lrun[m];
        float invr[4];
#pragma unroll
        for (int r = 0; r < 4; ++r) invr[r] = __shfl(inv, l4 * 4 + r);
#pragma unroll
        for (int r = 0; r < 4; ++r) {
            int row = qt * 128 + wid * 32 + m * 16 + l4 * 4 + r;
            bf16* Cp = Ctx + ((size_t)b * NS + row) * HID2 + h * ND;
#pragma unroll
            for (int n = 0; n < 8; ++n)
                Cp[n * 16 + l15] = (bf16)(oacc[m][n][r] * invr[r]);
        }
    }
}

// ---------------------------------------------------------------- launch
extern "C" void kernel_launch(void* const* d_in, const int* in_sizes, int n_in,
                              void* d_out, int out_size, void* d_ws, size_t ws_size,
                              hipStream_t stream) {
    const float* hidden = (const float*)d_in[0];
    const float* mask   = (const float*)d_in[1];
    const float* q_real = (const float*)d_in[2];
    const float* q_imag = (const float*)d_in[3];
    const float* q_mag  = (const float*)d_in[5];
    const float* k_real = (const float*)d_in[6];
    const float* k_imag = (const float*)d_in[7];
    const float* k_mag  = (const float*)d_in[9];
    const float* v_real = (const float*)d_in[10];
    const float* v_imag = (const float*)d_in[11];
    const float* v_mag  = (const float*)d_in[13];
    const float* Wq = (const float*)d_in[14];
    const float* bq = (const float*)d_in[15];
    const float* Wk = (const float*)d_in[16];
    const float* bk = (const float*)d_in[17];
    const float* Wv = (const float*)d_in[18];
    const float* bv = (const float*)d_in[19];
    const float* Wo = (const float*)d_in[20];
    const float* bo = (const float*)d_in[21];
    const float* ent = (const float*)d_in[22];

    char* ws = (char*)d_ws;
    bf16* Xb    = (bf16*)(ws);
    bf16* Wb    = (bf16*)(ws + 16777216);        // Wq,Wk,Wv,Wo bf16 contiguous
    bf16* Wob   = (bf16*)(ws + 41943040);
    bf16* QKV   = (bf16*)(ws + 50331648);        // Q,K,V bf16 stacked
    bf16* Vt    = (bf16*)(ws + 100663296);
    bf16* Ctx   = (bf16*)(ws + 117440512);
    float* scales = (float*)(ws + 134217728);

    cvt_f32_bf16<<<4096, 256, 0, stream>>>(hidden, Xb, MROWS * HID2 / 8);
    cvt_w4<<<dim3(2048, 4), 256, 0, stream>>>(Wq, Wk, Wv, Wo, Wb);
    qscale_kernel<<<8, 256, 0, stream>>>(q_real, q_imag, q_mag, k_real, k_imag, k_mag,
                                         v_real, v_imag, v_mag, scales);
    gemm_qkv<<<768, 256, 0, stream>>>(Xb, Wb, bq, bk, bv, scales, QKV);
    const bf16* Vb = QKV + (size_t)2 * MROWS * HID2;
    transpose_v<<<dim3(32, 2, 32), 256, 0, stream>>>(Vb, Vt);
    flash_kernel<<<dim3(16, 32), 256, 0, stream>>>(QKV, QKV + (size_t)MROWS * HID2, Vt, ent, mask, Ctx);
    gemm_out<<<256, 512, 0, stream>>>(Ctx, Wob, bo, (float*)d_out);
}

// Round 12
// 294.292 us; speedup vs baseline: 1.3875x; 1.0006x over previous
//
#include <hip/hip_runtime.h>
#include <hip/hip_bf16.h>

#define NB 2
#define NS 2048
#define NH 16
#define ND 128
#define HID2 2048
#define MROWS 4096   // NB*NS

typedef __bf16 bf16;
typedef bf16 bf16x8 __attribute__((ext_vector_type(8)));
typedef bf16 bf16x4 __attribute__((ext_vector_type(4)));
typedef float f32x4 __attribute__((ext_vector_type(4)));
typedef unsigned int u32;

#define GLOBAL_AS __attribute__((address_space(1)))
#define LDS_AS __attribute__((address_space(3)))

__device__ __forceinline__ void async16(void* lds, const void* g) {
    __builtin_amdgcn_global_load_lds((const GLOBAL_AS u32*)g, (LDS_AS u32*)lds, 16, 0, 0);
}

// ---------------------------------------------------------------- converts
__global__ void cvt_f32_bf16(const float* __restrict__ src, bf16* __restrict__ dst, int n8) {
    int i = blockIdx.x * blockDim.x + threadIdx.x;
    if (i >= n8) return;
    const float4* s4 = (const float4*)src;
    float4 a = s4[2 * i], b = s4[2 * i + 1];
    bf16x8 o;
    o[0] = (bf16)a.x; o[1] = (bf16)a.y; o[2] = (bf16)a.z; o[3] = (bf16)a.w;
    o[4] = (bf16)b.x; o[5] = (bf16)b.y; o[6] = (bf16)b.z; o[7] = (bf16)b.w;
    ((bf16x8*)dst)[i] = o;
}

__global__ void cvt_w4(const float* __restrict__ Wq, const float* __restrict__ Wk,
                       const float* __restrict__ Wv, const float* __restrict__ Wo,
                       bf16* __restrict__ dst) {
    int z = blockIdx.y;
    const float* src = (z == 0) ? Wq : (z == 1) ? Wk : (z == 2) ? Wv : Wo;
    int i = blockIdx.x * blockDim.x + threadIdx.x;
    const float4* s4 = (const float4*)src;
    float4 a = s4[2 * i], b = s4[2 * i + 1];
    bf16x8 o;
    o[0] = (bf16)a.x; o[1] = (bf16)a.y; o[2] = (bf16)a.z; o[3] = (bf16)a.w;
    o[4] = (bf16)b.x; o[5] = (bf16)b.y; o[6] = (bf16)b.z; o[7] = (bf16)b.w;
    ((bf16x8*)(dst + (size_t)z * HID2 * HID2))[i] = o;
}

// Q scale absorbs 1/sqrt(D): flash softmax then skips the per-element mul.
__global__ void qscale_kernel(const float* qr, const float* qi, const float* qm,
                              const float* kr, const float* ki, const float* km,
                              const float* vr, const float* vi, const float* vm,
                              float* out) {
    int i = blockIdx.x * blockDim.x + threadIdx.x;
    if (i >= HID2) return;
    const float RSQD = 0.08838834764831845f;  // 1/sqrt(128)
    out[i]            = sqrtf(qr[i] * qr[i] + qi[i] * qi[i]) * fabsf(qm[i]) * RSQD;
    out[HID2 + i]     = sqrtf(kr[i] * kr[i] + ki[i] * ki[i]) * fabsf(km[i]);
    out[2 * HID2 + i] = sqrtf(vr[i] * vr[i] + vi[i] * vi[i]) * fabsf(vm[i]);
}

// ---------------------------------------------------------------- loose GEMM (r7 core, balanced multi-tile)
// C[M,N] = A[M,K] @ Bt[N,K]^T. Block tile 128x256, BK=64, 4 waves (2M x 2N),
// per-wave 64x128 out (acc[4][8]). stage-all -> sync -> compute -> sync.
// launch_bounds(256,2): 2 blocks/CU (3/CU spills acc -> r10 252us).
// GRID 512: blocks 0..255 do tiles {b, 512+b}, 256..511 do {b} ->
// every CU hosts one 2-tile + one 1-tile block = 3 tiles/CU, zero tail.
// Tile 512+b has SAME tm (X rows L2-warm) and same tn XCD panel.
// Swizzle byte ^= (r&7)<<4: proven zero-conflict (r5/r7).
__device__ __forceinline__ void stage12(const char* gA, const char* gB,
                                        char* sa, char* sb, int w, int lane, size_t kb) {
    int r8 = lane >> 3;
    int cx = (lane & 7) * 16;
#pragma unroll
    for (int j = 0; j < 4; ++j) {
        int r = w * 32 + j * 8 + r8;
        async16(sa + (w * 32 + j * 8) * 128,
                gA + (size_t)r * (HID2 * 2) + kb + (cx ^ ((r & 7) << 4)));
    }
#pragma unroll
    for (int j = 0; j < 8; ++j) {
        int r = w * 64 + j * 8 + r8;
        async16(sb + (w * 64 + j * 8) * 128,
                gB + (size_t)r * (HID2 * 2) + kb + (cx ^ ((r & 7) << 4)));
    }
}

__global__ __launch_bounds__(256, 2) void gemm_qkv(
    const bf16* __restrict__ X, const bf16* __restrict__ Wb,
    const float* __restrict__ bq, const float* __restrict__ bk, const float* __restrict__ bv,
    const float* __restrict__ scales, bf16* __restrict__ QKV) {
    __shared__ bf16 sA[128 * 64];   // 16 KB
    __shared__ bf16 sB[256 * 64];   // 32 KB
    int b0 = blockIdx.x;            // 0..511
    int tid = threadIdx.x, w = tid >> 6, lane = tid & 63;
    int wr = w >> 1, wc = w & 1;
    int l15 = lane & 15, l4 = lane >> 4;
    int xorb = (l15 & 7) << 4;
    int ntile = (b0 < 256) ? 2 : 1;

    for (int it = 0; it < ntile; ++it) {
        int t = (it == 0) ? b0 : 512 + b0;
        int p = t & 7, q = t >> 3;      // XCD p keeps B-panel p resident
        int z = q >> 5, tm = q & 31, tn = p;
        const bf16* Bt = Wb + (size_t)z * HID2 * HID2;
        const float* bias = (z == 0) ? bq : (z == 1) ? bk : bv;
        const float* scale = scales + z * HID2;
        bf16* Cout = QKV + (size_t)z * MROWS * HID2;

        const char* gA = (const char*)X + (size_t)tm * 128 * (HID2 * 2);
        const char* gB = (const char*)Bt + (size_t)tn * 256 * (HID2 * 2);
        const char* pa = (const char*)sA;
        const char* pb = (const char*)sB;

        f32x4 acc[4][8] = {};

        for (int kt = 0; kt < HID2 / 64; ++kt) {
            stage12(gA, gB, (char*)sA, (char*)sB, w, lane, (size_t)kt * 128);
            __syncthreads();
#pragma unroll
            for (int kk = 0; kk < 2; ++kk) {
                int kc = (kk * 64 + l4 * 16) ^ xorb;
                bf16x8 af[4], bg[4];
#pragma unroll
                for (int m = 0; m < 4; ++m)
                    af[m] = *(const bf16x8*)(pa + (wr * 64 + m * 16 + l15) * 128 + kc);
#pragma unroll
                for (int n = 0; n < 4; ++n)
                    bg[n] = *(const bf16x8*)(pb + (wc * 128 + n * 16 + l15) * 128 + kc);
#pragma unroll
                for (int m = 0; m < 4; ++m)
#pragma unroll
                    for (int n = 0; n < 4; ++n)
                        acc[m][n] = __builtin_amdgcn_mfma_f32_16x16x32_bf16(af[m], bg[n], acc[m][n], 0, 0, 0);
#pragma unroll
                for (int n = 0; n < 4; ++n)
                    bg[n] = *(const bf16x8*)(pb + (wc * 128 + (n + 4) * 16 + l15) * 128 + kc);
#pragma unroll
                for (int m = 0; m < 4; ++m)
#pragma unroll
                    for (int n = 0; n < 4; ++n)
                        acc[m][n + 4] = __builtin_amdgcn_mfma_f32_16x16x32_bf16(af[m], bg[n], acc[m][n + 4], 0, 0, 0);
            }
            __syncthreads();
        }

        // epilogue: bf16 out = |acc + bias| * scale
#pragma unroll
        for (int n = 0; n < 8; ++n) {
            int col = tn * 256 + wc * 128 + n * 16 + l15;
            float bv2 = bias[col];
            float sc = scale[col];
#pragma unroll
            for (int m = 0; m < 4; ++m) {
                int row = tm * 128 + wr * 64 + m * 16 + l4 * 4;
#pragma unroll
                for (int r = 0; r < 4; ++r)
                    Cout[(size_t)(row + r) * HID2 + col] = (bf16)(fabsf(acc[m][n][r] + bv2) * sc);
            }
        }
    }
}

// ---------------------------------------------------------------- phased GEMM (r8, for out)
__device__ __forceinline__ void stage2A(const char* gA, char* sa, int w, int lane, size_t kb) {
#pragma unroll
    for (int j = 0; j < 2; ++j) {
        int r = w * 16 + j * 8 + (lane >> 3);
        async16(sa + (w * 16 + j * 8) * 128,
                gA + (size_t)r * (HID2 * 2) + kb + (((lane & 7) * 16) ^ ((r & 7) << 4)));
    }
}
__device__ __forceinline__ void stage2B(const char* gB, char* sb, int w, int lane, int half, size_t kb) {
#pragma unroll
    for (int j = 0; j < 2; ++j) {
        int r = half * 128 + w * 16 + j * 8 + (lane >> 3);
        async16(sb + (half * 128 + w * 16 + j * 8) * 128,
                gB + (size_t)r * (HID2 * 2) + kb + (((lane & 7) * 16) ^ ((r & 7) << 4)));
    }
}

#define G_BARRIER() do { asm volatile("" ::: "memory"); __builtin_amdgcn_s_barrier(); \
                         asm volatile("" ::: "memory"); } while (0)

__global__ __launch_bounds__(512, 2) void gemm_out(
    const bf16* __restrict__ Ctx, const bf16* __restrict__ Wo,
    const float* __restrict__ bo, float* __restrict__ out) {
    __shared__ bf16 sA[3][128 * 64];
    __shared__ bf16 sB[3][256 * 64];
    const int NT = HID2 / 64;  // 32
    int bid = blockIdx.x;             // 0..255 = 1 exact round
    int tn = bid & 7, tm = bid >> 3;
    int tid = threadIdx.x, w = tid >> 6, lane = tid & 63;
    int wr = w >> 2, wc = w & 3;
    int l15 = lane & 15, l4 = lane >> 4;
    int xorb = (l15 & 7) << 4;

    const char* gA = (const char*)Ctx + (size_t)tm * 128 * (HID2 * 2);
    const char* gB = (const char*)Wo + (size_t)tn * 256 * (HID2 * 2);

    f32x4 acc[4][4] = {};

    stage2A(gA, (char*)sA[0], w, lane, 0);
    stage2B(gB, (char*)sB[0], w, lane, 0, 0);
    stage2B(gB, (char*)sB[0], w, lane, 1, 0);
    stage2A(gA, (char*)sA[1], w, lane, 128);
    stage2B(gB, (char*)sB[1], w, lane, 0, 128);
    stage2B(gB, (char*)sB[1], w, lane, 1, 128);
    asm volatile("s_waitcnt vmcnt(6)" ::: "memory");
    G_BARRIER();

    int cur = 0;
    for (int t = 0; t < NT; ++t) {
        const char* pa = (const char*)sA[cur];
        const char* pb = (const char*)sB[cur];
        int nb = cur + 2; if (nb >= 3) nb -= 3;
        const bool pre = (t + 2 < NT);
        size_t kb = (size_t)(t + 2) * 128;
        bf16x8 af[4], bg[4];

        {
            int kc = (l4 * 16) ^ xorb;
#pragma unroll
            for (int m = 0; m < 4; ++m)
                af[m] = *(const bf16x8*)(pa + (wr * 64 + m * 16 + l15) * 128 + kc);
#pragma unroll
            for (int n = 0; n < 4; ++n)
                bg[n] = *(const bf16x8*)(pb + (wc * 64 + n * 16 + l15) * 128 + kc);
        }
        if (pre) { stage2A(gA, (char*)sA[nb], w, lane, kb); stage2B(gB, (char*)sB[nb], w, lane, 0, kb); }
        G_BARRIER();
        asm volatile("s_waitcnt lgkmcnt(0)" ::: "memory");
        __builtin_amdgcn_sched_barrier(0);
        __builtin_amdgcn_s_setprio(1);
#pragma unroll
        for (int m = 0; m < 4; ++m)
#pragma unroll
            for (int n = 0; n < 4; ++n)
                acc[m][n] = __builtin_amdgcn_mfma_f32_16x16x32_bf16(af[m], bg[n], acc[m][n], 0, 0, 0);
        __builtin_amdgcn_s_setprio(0);
        G_BARRIER();

        {
            int kc = (64 + l4 * 16) ^ xorb;
#pragma unroll
            for (int m = 0; m < 4; ++m)
                af[m] = *(const bf16x8*)(pa + (wr * 64 + m * 16 + l15) * 128 + kc);
#pragma unroll
            for (int n = 0; n < 4; ++n)
                bg[n] = *(const bf16x8*)(pb + (wc * 64 + n * 16 + l15) * 128 + kc);
        }
        if (pre) stage2B(gB, (char*)sB[nb], w, lane, 1, kb);
        G_BARRIER();
        asm volatile("s_waitcnt lgkmcnt(0)" ::: "memory");
        __builtin_amdgcn_sched_barrier(0);
        __builtin_amdgcn_s_setprio(1);
#pragma unroll
        for (int m = 0; m < 4; ++m)
#pragma unroll
            for (int n = 0; n < 4; ++n)
                acc[m][n] = __builtin_amdgcn_mfma_f32_16x16x32_bf16(af[m], bg[n], acc[m][n], 0, 0, 0);
        __builtin_amdgcn_s_setprio(0);
        if (pre)               { asm volatile("s_waitcnt vmcnt(6)" ::: "memory"); }
        else if (t + 2 == NT)  { asm volatile("s_waitcnt vmcnt(0)" ::: "memory"); }
        G_BARRIER();

        cur = cur + 1; if (cur == 3) cur = 0;
    }

#pragma unroll
    for (int n = 0; n < 4; ++n) {
        int col = tn * 256 + wc * 64 + n * 16 + l15;
        float bv = bo[col];
#pragma unroll
        for (int m = 0; m < 4; ++m) {
            int row = tm * 128 + wr * 64 + m * 16 + l4 * 4;
#pragma unroll
            for (int r = 0; r < 4; ++r)
                out[(size_t)(row + r) * HID2 + col] = acc[m][n][r] + bv;
        }
    }
}

// ---------------------------------------------------------------- V transpose
__global__ void transpose_v(const bf16* __restrict__ Vb, bf16* __restrict__ Vt) {
    int bh = blockIdx.z;
    int b = bh >> 4, h = bh & 15;
    int s0 = blockIdx.x * 64, d0 = blockIdx.y * 64;
    int tid = threadIdx.x;
    __shared__ bf16 T[64][72];
    const bf16* src = Vb + ((size_t)b * NS + s0) * HID2 + h * ND + d0;
#pragma unroll
    for (int i = 0; i < 2; ++i) {
        int r = i * 32 + (tid >> 3);
        int c = (tid & 7) * 8;
        *(bf16x8*)(&T[r][c]) = *(const bf16x8*)(src + (size_t)r * HID2 + c);
    }
    __syncthreads();
    bf16* dst = Vt + ((size_t)(b * NH + h) * ND + d0) * NS + s0;
#pragma unroll
    for (int i = 0; i < 2; ++i) {
        int dr = i * 32 + (tid >> 3);
        int sc = (tid & 7) * 8;
        bf16x8 o;
#pragma unroll
        for (int j = 0; j < 8; ++j) o[j] = T[sc + j][dr];
        *(bf16x8*)(dst + (size_t)dr * NS + sc) = o;
    }
}

// ---------------------------------------------------------------- flash attention (v3)
// Swapped QK^T; 1/sqrt(D) pre-folded into Q scale; setprio around MFMA clusters.
__device__ __forceinline__ void stage_load(const bf16* __restrict__ Kp, const bf16* __restrict__ Vp,
                                           int kt, int tid, bf16x8 kreg[4], bf16x8 vreg[4]) {
#pragma unroll
    for (int i = 0; i < 4; ++i) {
        kreg[i] = *(const bf16x8*)(Kp + (size_t)(kt * 64 + i * 16 + (tid >> 4)) * HID2 + (tid & 15) * 8);
        vreg[i] = *(const bf16x8*)(Vp + (size_t)(i * 32 + (tid >> 3)) * NS + kt * 64 + (tid & 7) * 8);
    }
}

__global__ __launch_bounds__(256, 2) void flash_kernel(
    const bf16* __restrict__ Qb, const bf16* __restrict__ Kb, const bf16* __restrict__ Vt,
    const float* __restrict__ ent, const float* __restrict__ mask, bf16* __restrict__ Ctx) {
    int qt = blockIdx.x;   // 0..15
    int bh = blockIdx.y;   // 0..31
    int b = bh >> 4, h = bh & 15;
    int tid = threadIdx.x, wid = tid >> 6, lane = tid & 63;
    int l15 = lane & 15, l4 = lane >> 4;

    __shared__ bf16 Ks[64 * 136];
    __shared__ bf16 Vs[128 * 72];
    __shared__ bf16 Ps[4][32 * 72];

    const bf16* Qp = Qb + ((size_t)b * NS + qt * 128) * HID2 + h * ND;
    const bf16* Kp = Kb + (size_t)b * NS * HID2 + h * ND;
    const bf16* Vp = Vt + (size_t)(b * NH + h) * ND * NS;
    const float* maskp = mask + (size_t)b * NS;

    bf16x8 qf[2][4];
#pragma unroll
    for (int m = 0; m < 2; ++m)
#pragma unroll
        for (int kk = 0; kk < 4; ++kk)
            qf[m][kk] = *(const bf16x8*)(Qp + (size_t)(wid * 32 + m * 16 + l15) * HID2 + kk * 32 + l4 * 8);

    float eb[4];
#pragma unroll
    for (int r = 0; r < 4; ++r) eb[r] = ent[h * NH + l4 * 4 + r];

    float mrun[2], lrun[2];
    mrun[0] = mrun[1] = -INFINITY;
    lrun[0] = lrun[1] = 0.f;
    f32x4 oacc[2][8] = {};

    bf16x8 kreg[4], vreg[4];
    stage_load(Kp, Vp, 0, tid, kreg, vreg);
#pragma unroll
    for (int i = 0; i < 4; ++i) {
        *(bf16x8*)(&Ks[(i * 16 + (tid >> 4)) * 136 + (tid & 15) * 8]) = kreg[i];
        *(bf16x8*)(&Vs[(i * 32 + (tid >> 3)) * 72 + (tid & 7) * 8]) = vreg[i];
    }

    for (int kt = 0; kt < NS / 64; ++kt) {
        __syncthreads();
        if (kt + 1 < NS / 64) stage_load(Kp, Vp, kt + 1, tid, kreg, vreg);

        f32x4 s[2][4] = {};
        __builtin_amdgcn_s_setprio(1);
#pragma unroll
        for (int kk = 0; kk < 4; ++kk) {
            bf16x8 kf[4];
#pragma unroll
            for (int n = 0; n < 4; ++n)
                kf[n] = *(const bf16x8*)(&Ks[(n * 16 + l15) * 136 + kk * 32 + l4 * 8]);
#pragma unroll
            for (int m = 0; m < 2; ++m)
#pragma unroll
                for (int n = 0; n < 4; ++n)
                    s[m][n] = __builtin_amdgcn_mfma_f32_16x16x32_bf16(kf[n], qf[m][kk], s[m][n], 0, 0, 0);
        }
        __builtin_amdgcn_s_setprio(0);

        float4 mk[4];
#pragma unroll
        for (int n = 0; n < 4; ++n)
            mk[n] = *(const float4*)(maskp + kt * 64 + n * 16 + l4 * 4);

#pragma unroll
        for (int mq = 0; mq < 2; ++mq) {
            float sv[4][4];
#pragma unroll
            for (int n = 0; n < 4; ++n) {
                sv[n][0] = s[mq][n][0] + eb[0] + mk[n].x;
                sv[n][1] = s[mq][n][1] + eb[1] + mk[n].y;
                sv[n][2] = s[mq][n][2] + eb[2] + mk[n].z;
                sv[n][3] = s[mq][n][3] + eb[3] + mk[n].w;
            }
            float tmax = sv[0][0];
#pragma unroll
            for (int n = 0; n < 4; ++n)
#pragma unroll
                for (int r = 0; r < 4; ++r) tmax = fmaxf(tmax, sv[n][r]);
            tmax = fmaxf(tmax, __shfl_xor(tmax, 16));
            tmax = fmaxf(tmax, __shfl_xor(tmax, 32));

            if (__any(tmax > mrun[mq] + 8.0f)) {
                float mnew = fmaxf(mrun[mq], tmax);
                float corr = __expf(mrun[mq] - mnew);
                mrun[mq] = mnew;
                lrun[mq] *= corr;
#pragma unroll
                for (int r = 0; r < 4; ++r) {
                    float cr = __shfl(corr, l4 * 4 + r);
#pragma unroll
                    for (int n = 0; n < 8; ++n) oacc[mq][n][r] *= cr;
                }
            }

            float psum = 0.f;
#pragma unroll
            for (int n = 0; n < 4; ++n) {
                bf16x4 pv;
#pragma unroll
                for (int r = 0; r < 4; ++r) {
                    float p = __expf(sv[n][r] - mrun[mq]);
                    psum += p;
                    pv[r] = (bf16)p;
                }
                *(bf16x4*)(&Ps[wid][(mq * 16 + l15) * 72 + n * 16 + l4 * 4]) = pv;
            }
            psum += __shfl_xor(psum, 16);
            psum += __shfl_xor(psum, 32);
            lrun[mq] += psum;
        }

        __builtin_amdgcn_s_setprio(1);
#pragma unroll
        for (int kk = 0; kk < 2; ++kk) {
            bf16x8 pa[2], vb[8];
#pragma unroll
            for (int m = 0; m < 2; ++m)
                pa[m] = *(const bf16x8*)(&Ps[wid][(m * 16 + l15) * 72 + kk * 32 + l4 * 8]);
#pragma unroll
            for (int n = 0; n < 8; ++n)
                vb[n] = *(const bf16x8*)(&Vs[(n * 16 + l15) * 72 + kk * 32 + l4 * 8]);
#pragma unroll
            for (int m = 0; m < 2; ++m)
#pragma unroll
                for (int n = 0; n < 8; ++n)
                    oacc[m][n] = __builtin_amdgcn_mfma_f32_16x16x32_bf16(pa[m], vb[n], oacc[m][n], 0, 0, 0);
        }
        __builtin_amdgcn_s_setprio(0);
        __syncthreads();
        if (kt + 1 < NS / 64) {
#pragma unroll
            for (int i = 0; i < 4; ++i) {
                *(bf16x8*)(&Ks[(i * 16 + (tid >> 4)) * 136 + (tid & 15) * 8]) = kreg[i];
                *(bf16x8*)(&Vs[(i * 32 + (tid >> 3)) * 72 + (tid & 7) * 8]) = vreg[i];
            }
        }
    }

#pragma unroll
    for (int m = 0; m < 2; ++m) {
        float inv = 1.0f / lrun[m];
        float invr[4];
#pragma unroll
        for (int r = 0; r < 4; ++r) invr[r] = __shfl(inv, l4 * 4 + r);
#pragma unroll
        for (int r = 0; r < 4; ++r) {
            int row = qt * 128 + wid * 32 + m * 16 + l4 * 4 + r;
            bf16* Cp = Ctx + ((size_t)b * NS + row) * HID2 + h * ND;
#pragma unroll
            for (int n = 0; n < 8; ++n)
                Cp[n * 16 + l15] = (bf16)(oacc[m][n][r] * invr[r]);
        }
    }
}

// ---------------------------------------------------------------- launch
extern "C" void kernel_launch(void* const* d_in, const int* in_sizes, int n_in,
                              void* d_out, int out_size, void* d_ws, size_t ws_size,
                              hipStream_t stream) {
    const float* hidden = (const float*)d_in[0];
    const float* mask   = (const float*)d_in[1];
    const float* q_real = (const float*)d_in[2];
    const float* q_imag = (const float*)d_in[3];
    const float* q_mag  = (const float*)d_in[5];
    const float* k_real = (const float*)d_in[6];
    const float* k_imag = (const float*)d_in[7];
    const float* k_mag  = (const float*)d_in[9];
    const float* v_real = (const float*)d_in[10];
    const float* v_imag = (const float*)d_in[11];
    const float* v_mag  = (const float*)d_in[13];
    const float* Wq = (const float*)d_in[14];
    const float* bq = (const float*)d_in[15];
    const float* Wk = (const float*)d_in[16];
    const float* bk = (const float*)d_in[17];
    const float* Wv = (const float*)d_in[18];
    const float* bv = (const float*)d_in[19];
    const float* Wo = (const float*)d_in[20];
    const float* bo = (const float*)d_in[21];
    const float* ent = (const float*)d_in[22];

    char* ws = (char*)d_ws;
    bf16* Xb    = (bf16*)(ws);
    bf16* Wb    = (bf16*)(ws + 16777216);        // Wq,Wk,Wv,Wo bf16 contiguous
    bf16* Wob   = (bf16*)(ws + 41943040);
    bf16* QKV   = (bf16*)(ws + 50331648);        // Q,K,V bf16 stacked
    bf16* Vt    = (bf16*)(ws + 100663296);
    bf16* Ctx   = (bf16*)(ws + 117440512);
    float* scales = (float*)(ws + 134217728);

    cvt_f32_bf16<<<4096, 256, 0, stream>>>(hidden, Xb, MROWS * HID2 / 8);
    cvt_w4<<<dim3(2048, 4), 256, 0, stream>>>(Wq, Wk, Wv, Wo, Wb);
    qscale_kernel<<<8, 256, 0, stream>>>(q_real, q_imag, q_mag, k_real, k_imag, k_mag,
                                         v_real, v_imag, v_mag, scales);
    gemm_qkv<<<512, 256, 0, stream>>>(Xb, Wb, bq, bk, bv, scales, QKV);
    const bf16* Vb = QKV + (size_t)2 * MROWS * HID2;
    transpose_v<<<dim3(32, 2, 32), 256, 0, stream>>>(Vb, Vt);
    flash_kernel<<<dim3(16, 32), 256, 0, stream>>>(QKV, QKV + (size_t)MROWS * HID2, Vt, ent, mask, Ctx);
    gemm_out<<<256, 512, 0, stream>>>(Ctx, Wob, bo, (float*)d_out);
}

// Round 13
// 292.452 us; speedup vs baseline: 1.3963x; 1.0063x over previous
//
#include <hip/hip_runtime.h>
#include <hip/hip_bf16.h>

#define NB 2
#define NS 2048
#define NH 16
#define ND 128
#define HID2 2048
#define MROWS 4096   // NB*NS

typedef __bf16 bf16;
typedef bf16 bf16x8 __attribute__((ext_vector_type(8)));
typedef bf16 bf16x4 __attribute__((ext_vector_type(4)));
typedef float f32x4 __attribute__((ext_vector_type(4)));
typedef unsigned int u32;

#define GLOBAL_AS __attribute__((address_space(1)))
#define LDS_AS __attribute__((address_space(3)))

__device__ __forceinline__ void async16(void* lds, const void* g) {
    __builtin_amdgcn_global_load_lds((const GLOBAL_AS u32*)g, (LDS_AS u32*)lds, 16, 0, 0);
}

// ---------------------------------------------------------------- converts
__global__ void cvt_f32_bf16(const float* __restrict__ src, bf16* __restrict__ dst, int n8) {
    int i = blockIdx.x * blockDim.x + threadIdx.x;
    if (i >= n8) return;
    const float4* s4 = (const float4*)src;
    float4 a = s4[2 * i], b = s4[2 * i + 1];
    bf16x8 o;
    o[0] = (bf16)a.x; o[1] = (bf16)a.y; o[2] = (bf16)a.z; o[3] = (bf16)a.w;
    o[4] = (bf16)b.x; o[5] = (bf16)b.y; o[6] = (bf16)b.z; o[7] = (bf16)b.w;
    ((bf16x8*)dst)[i] = o;
}

__global__ void cvt_w4(const float* __restrict__ Wq, const float* __restrict__ Wk,
                       const float* __restrict__ Wv, const float* __restrict__ Wo,
                       bf16* __restrict__ dst) {
    int z = blockIdx.y;
    const float* src = (z == 0) ? Wq : (z == 1) ? Wk : (z == 2) ? Wv : Wo;
    int i = blockIdx.x * blockDim.x + threadIdx.x;
    const float4* s4 = (const float4*)src;
    float4 a = s4[2 * i], b = s4[2 * i + 1];
    bf16x8 o;
    o[0] = (bf16)a.x; o[1] = (bf16)a.y; o[2] = (bf16)a.z; o[3] = (bf16)a.w;
    o[4] = (bf16)b.x; o[5] = (bf16)b.y; o[6] = (bf16)b.z; o[7] = (bf16)b.w;
    ((bf16x8*)(dst + (size_t)z * HID2 * HID2))[i] = o;
}

// Q scale absorbs 1/sqrt(D): flash softmax then skips the per-element mul.
__global__ void qscale_kernel(const float* qr, const float* qi, const float* qm,
                              const float* kr, const float* ki, const float* km,
                              const float* vr, const float* vi, const float* vm,
                              float* out) {
    int i = blockIdx.x * blockDim.x + threadIdx.x;
    if (i >= HID2) return;
    const float RSQD = 0.08838834764831845f;  // 1/sqrt(128)
    out[i]            = sqrtf(qr[i] * qr[i] + qi[i] * qi[i]) * fabsf(qm[i]) * RSQD;
    out[HID2 + i]     = sqrtf(kr[i] * kr[i] + ki[i] * ki[i]) * fabsf(km[i]);
    out[2 * HID2 + i] = sqrtf(vr[i] * vr[i] + vi[i] * vi[i]) * fabsf(vm[i]);
}

// ---------------------------------------------------------------- loose GEMM (r7 core, balanced multi-tile)
__device__ __forceinline__ void stage12(const char* gA, const char* gB,
                                        char* sa, char* sb, int w, int lane, size_t kb) {
    int r8 = lane >> 3;
    int cx = (lane & 7) * 16;
#pragma unroll
    for (int j = 0; j < 4; ++j) {
        int r = w * 32 + j * 8 + r8;
        async16(sa + (w * 32 + j * 8) * 128,
                gA + (size_t)r * (HID2 * 2) + kb + (cx ^ ((r & 7) << 4)));
    }
#pragma unroll
    for (int j = 0; j < 8; ++j) {
        int r = w * 64 + j * 8 + r8;
        async16(sb + (w * 64 + j * 8) * 128,
                gB + (size_t)r * (HID2 * 2) + kb + (cx ^ ((r & 7) << 4)));
    }
}

__global__ __launch_bounds__(256, 2) void gemm_qkv(
    const bf16* __restrict__ X, const bf16* __restrict__ Wb,
    const float* __restrict__ bq, const float* __restrict__ bk, const float* __restrict__ bv,
    const float* __restrict__ scales, bf16* __restrict__ QKV) {
    __shared__ bf16 sA[128 * 64];   // 16 KB
    __shared__ bf16 sB[256 * 64];   // 32 KB
    int b0 = blockIdx.x;            // 0..511
    int tid = threadIdx.x, w = tid >> 6, lane = tid & 63;
    int wr = w >> 1, wc = w & 1;
    int l15 = lane & 15, l4 = lane >> 4;
    int xorb = (l15 & 7) << 4;
    int ntile = (b0 < 256) ? 2 : 1;

    for (int it = 0; it < ntile; ++it) {
        int t = (it == 0) ? b0 : 512 + b0;
        int p = t & 7, q = t >> 3;      // XCD p keeps B-panel p resident
        int z = q >> 5, tm = q & 31, tn = p;
        const bf16* Bt = Wb + (size_t)z * HID2 * HID2;
        const float* bias = (z == 0) ? bq : (z == 1) ? bk : bv;
        const float* scale = scales + z * HID2;
        bf16* Cout = QKV + (size_t)z * MROWS * HID2;

        const char* gA = (const char*)X + (size_t)tm * 128 * (HID2 * 2);
        const char* gB = (const char*)Bt + (size_t)tn * 256 * (HID2 * 2);
        const char* pa = (const char*)sA;
        const char* pb = (const char*)sB;

        f32x4 acc[4][8] = {};

        for (int kt = 0; kt < HID2 / 64; ++kt) {
            stage12(gA, gB, (char*)sA, (char*)sB, w, lane, (size_t)kt * 128);
            __syncthreads();
#pragma unroll
            for (int kk = 0; kk < 2; ++kk) {
                int kc = (kk * 64 + l4 * 16) ^ xorb;
                bf16x8 af[4], bg[4];
#pragma unroll
                for (int m = 0; m < 4; ++m)
                    af[m] = *(const bf16x8*)(pa + (wr * 64 + m * 16 + l15) * 128 + kc);
#pragma unroll
                for (int n = 0; n < 4; ++n)
                    bg[n] = *(const bf16x8*)(pb + (wc * 128 + n * 16 + l15) * 128 + kc);
#pragma unroll
                for (int m = 0; m < 4; ++m)
#pragma unroll
                    for (int n = 0; n < 4; ++n)
                        acc[m][n] = __builtin_amdgcn_mfma_f32_16x16x32_bf16(af[m], bg[n], acc[m][n], 0, 0, 0);
#pragma unroll
                for (int n = 0; n < 4; ++n)
                    bg[n] = *(const bf16x8*)(pb + (wc * 128 + (n + 4) * 16 + l15) * 128 + kc);
#pragma unroll
                for (int m = 0; m < 4; ++m)
#pragma unroll
                    for (int n = 0; n < 4; ++n)
                        acc[m][n + 4] = __builtin_amdgcn_mfma_f32_16x16x32_bf16(af[m], bg[n], acc[m][n + 4], 0, 0, 0);
            }
            __syncthreads();
        }

        // epilogue: bf16 out = |acc + bias| * scale
#pragma unroll
        for (int n = 0; n < 8; ++n) {
            int col = tn * 256 + wc * 128 + n * 16 + l15;
            float bv2 = bias[col];
            float sc = scale[col];
#pragma unroll
            for (int m = 0; m < 4; ++m) {
                int row = tm * 128 + wr * 64 + m * 16 + l4 * 4;
#pragma unroll
                for (int r = 0; r < 4; ++r)
                    Cout[(size_t)(row + r) * HID2 + col] = (bf16)(fabsf(acc[m][n][r] + bv2) * sc);
            }
        }
    }
}

// ---------------------------------------------------------------- phased GEMM (r8, for out)
__device__ __forceinline__ void stage2A(const char* gA, char* sa, int w, int lane, size_t kb) {
#pragma unroll
    for (int j = 0; j < 2; ++j) {
        int r = w * 16 + j * 8 + (lane >> 3);
        async16(sa + (w * 16 + j * 8) * 128,
                gA + (size_t)r * (HID2 * 2) + kb + (((lane & 7) * 16) ^ ((r & 7) << 4)));
    }
}
__device__ __forceinline__ void stage2B(const char* gB, char* sb, int w, int lane, int half, size_t kb) {
#pragma unroll
    for (int j = 0; j < 2; ++j) {
        int r = half * 128 + w * 16 + j * 8 + (lane >> 3);
        async16(sb + (half * 128 + w * 16 + j * 8) * 128,
                gB + (size_t)r * (HID2 * 2) + kb + (((lane & 7) * 16) ^ ((r & 7) << 4)));
    }
}

#define G_BARRIER() do { asm volatile("" ::: "memory"); __builtin_amdgcn_s_barrier(); \
                         asm volatile("" ::: "memory"); } while (0)

__global__ __launch_bounds__(512, 2) void gemm_out(
    const bf16* __restrict__ Ctx, const bf16* __restrict__ Wo,
    const float* __restrict__ bo, float* __restrict__ out) {
    __shared__ bf16 sA[3][128 * 64];
    __shared__ bf16 sB[3][256 * 64];
    const int NT = HID2 / 64;  // 32
    int bid = blockIdx.x;             // 0..255 = 1 exact round
    int tn = bid & 7, tm = bid >> 3;
    int tid = threadIdx.x, w = tid >> 6, lane = tid & 63;
    int wr = w >> 2, wc = w & 3;
    int l15 = lane & 15, l4 = lane >> 4;
    int xorb = (l15 & 7) << 4;

    const char* gA = (const char*)Ctx + (size_t)tm * 128 * (HID2 * 2);
    const char* gB = (const char*)Wo + (size_t)tn * 256 * (HID2 * 2);

    f32x4 acc[4][4] = {};

    stage2A(gA, (char*)sA[0], w, lane, 0);
    stage2B(gB, (char*)sB[0], w, lane, 0, 0);
    stage2B(gB, (char*)sB[0], w, lane, 1, 0);
    stage2A(gA, (char*)sA[1], w, lane, 128);
    stage2B(gB, (char*)sB[1], w, lane, 0, 128);
    stage2B(gB, (char*)sB[1], w, lane, 1, 128);
    asm volatile("s_waitcnt vmcnt(6)" ::: "memory");
    G_BARRIER();

    int cur = 0;
    for (int t = 0; t < NT; ++t) {
        const char* pa = (const char*)sA[cur];
        const char* pb = (const char*)sB[cur];
        int nb = cur + 2; if (nb >= 3) nb -= 3;
        const bool pre = (t + 2 < NT);
        size_t kb = (size_t)(t + 2) * 128;
        bf16x8 af[4], bg[4];

        {
            int kc = (l4 * 16) ^ xorb;
#pragma unroll
            for (int m = 0; m < 4; ++m)
                af[m] = *(const bf16x8*)(pa + (wr * 64 + m * 16 + l15) * 128 + kc);
#pragma unroll
            for (int n = 0; n < 4; ++n)
                bg[n] = *(const bf16x8*)(pb + (wc * 64 + n * 16 + l15) * 128 + kc);
        }
        if (pre) { stage2A(gA, (char*)sA[nb], w, lane, kb); stage2B(gB, (char*)sB[nb], w, lane, 0, kb); }
        G_BARRIER();
        asm volatile("s_waitcnt lgkmcnt(0)" ::: "memory");
        __builtin_amdgcn_sched_barrier(0);
        __builtin_amdgcn_s_setprio(1);
#pragma unroll
        for (int m = 0; m < 4; ++m)
#pragma unroll
            for (int n = 0; n < 4; ++n)
                acc[m][n] = __builtin_amdgcn_mfma_f32_16x16x32_bf16(af[m], bg[n], acc[m][n], 0, 0, 0);
        __builtin_amdgcn_s_setprio(0);
        G_BARRIER();

        {
            int kc = (64 + l4 * 16) ^ xorb;
#pragma unroll
            for (int m = 0; m < 4; ++m)
                af[m] = *(const bf16x8*)(pa + (wr * 64 + m * 16 + l15) * 128 + kc);
#pragma unroll
            for (int n = 0; n < 4; ++n)
                bg[n] = *(const bf16x8*)(pb + (wc * 64 + n * 16 + l15) * 128 + kc);
        }
        if (pre) stage2B(gB, (char*)sB[nb], w, lane, 1, kb);
        G_BARRIER();
        asm volatile("s_waitcnt lgkmcnt(0)" ::: "memory");
        __builtin_amdgcn_sched_barrier(0);
        __builtin_amdgcn_s_setprio(1);
#pragma unroll
        for (int m = 0; m < 4; ++m)
#pragma unroll
            for (int n = 0; n < 4; ++n)
                acc[m][n] = __builtin_amdgcn_mfma_f32_16x16x32_bf16(af[m], bg[n], acc[m][n], 0, 0, 0);
        __builtin_amdgcn_s_setprio(0);
        if (pre)               { asm volatile("s_waitcnt vmcnt(6)" ::: "memory"); }
        else if (t + 2 == NT)  { asm volatile("s_waitcnt vmcnt(0)" ::: "memory"); }
        G_BARRIER();

        cur = cur + 1; if (cur == 3) cur = 0;
    }

#pragma unroll
    for (int n = 0; n < 4; ++n) {
        int col = tn * 256 + wc * 64 + n * 16 + l15;
        float bv = bo[col];
#pragma unroll
        for (int m = 0; m < 4; ++m) {
            int row = tm * 128 + wr * 64 + m * 16 + l4 * 4;
#pragma unroll
            for (int r = 0; r < 4; ++r)
                out[(size_t)(row + r) * HID2 + col] = acc[m][n][r] + bv;
        }
    }
}

// ---------------------------------------------------------------- V transpose
__global__ void transpose_v(const bf16* __restrict__ Vb, bf16* __restrict__ Vt) {
    int bh = blockIdx.z;
    int b = bh >> 4, h = bh & 15;
    int s0 = blockIdx.x * 64, d0 = blockIdx.y * 64;
    int tid = threadIdx.x;
    __shared__ bf16 T[64][72];
    const bf16* src = Vb + ((size_t)b * NS + s0) * HID2 + h * ND + d0;
#pragma unroll
    for (int i = 0; i < 2; ++i) {
        int r = i * 32 + (tid >> 3);
        int c = (tid & 7) * 8;
        *(bf16x8*)(&T[r][c]) = *(const bf16x8*)(src + (size_t)r * HID2 + c);
    }
    __syncthreads();
    bf16* dst = Vt + ((size_t)(b * NH + h) * ND + d0) * NS + s0;
#pragma unroll
    for (int i = 0; i < 2; ++i) {
        int dr = i * 32 + (tid >> 3);
        int sc = (tid & 7) * 8;
        bf16x8 o;
#pragma unroll
        for (int j = 0; j < 8; ++j) o[j] = T[sc + j][dr];
        *(bf16x8*)(dst + (size_t)dr * NS + sc) = o;
    }
}

// ---------------------------------------------------------------- flash attention (v4)
// Swapped QK^T; 1/sqrt(D) folded into Q scale; NO setprio (lockstep 4-wave
// block = m190's harmful regime). XCD-aware grid: all 16 q-tiles of a bh
// land on one XCD -> K/Vt panel (1MB) stays L2-resident (4 bh x 1MB per XCD).
__device__ __forceinline__ void stage_load(const bf16* __restrict__ Kp, const bf16* __restrict__ Vp,
                                           int kt, int tid, bf16x8 kreg[4], bf16x8 vreg[4]) {
#pragma unroll
    for (int i = 0; i < 4; ++i) {
        kreg[i] = *(const bf16x8*)(Kp + (size_t)(kt * 64 + i * 16 + (tid >> 4)) * HID2 + (tid & 15) * 8);
        vreg[i] = *(const bf16x8*)(Vp + (size_t)(i * 32 + (tid >> 3)) * NS + kt * 64 + (tid & 7) * 8);
    }
}

__global__ __launch_bounds__(256, 2) void flash_kernel(
    const bf16* __restrict__ Qb, const bf16* __restrict__ Kb, const bf16* __restrict__ Vt,
    const float* __restrict__ ent, const float* __restrict__ mask, bf16* __restrict__ Ctx) {
    int bid = blockIdx.x;                       // 0..511
    int qt = bid >> 5;                          // 0..15
    int bh = (bid & 7) * 4 + ((bid >> 3) & 3);  // XCD (bid%8) owns bh 4x..4x+3
    int b = bh >> 4, h = bh & 15;
    int tid = threadIdx.x, wid = tid >> 6, lane = tid & 63;
    int l15 = lane & 15, l4 = lane >> 4;

    __shared__ bf16 Ks[64 * 136];
    __shared__ bf16 Vs[128 * 72];
    __shared__ bf16 Ps[4][32 * 72];

    const bf16* Qp = Qb + ((size_t)b * NS + qt * 128) * HID2 + h * ND;
    const bf16* Kp = Kb + (size_t)b * NS * HID2 + h * ND;
    const bf16* Vp = Vt + (size_t)(b * NH + h) * ND * NS;
    const float* maskp = mask + (size_t)b * NS;

    bf16x8 qf[2][4];
#pragma unroll
    for (int m = 0; m < 2; ++m)
#pragma unroll
        for (int kk = 0; kk < 4; ++kk)
            qf[m][kk] = *(const bf16x8*)(Qp + (size_t)(wid * 32 + m * 16 + l15) * HID2 + kk * 32 + l4 * 8);

    float eb[4];
#pragma unroll
    for (int r = 0; r < 4; ++r) eb[r] = ent[h * NH + l4 * 4 + r];

    float mrun[2], lrun[2];
    mrun[0] = mrun[1] = -INFINITY;
    lrun[0] = lrun[1] = 0.f;
    f32x4 oacc[2][8] = {};

    bf16x8 kreg[4], vreg[4];
    stage_load(Kp, Vp, 0, tid, kreg, vreg);
#pragma unroll
    for (int i = 0; i < 4; ++i) {
        *(bf16x8*)(&Ks[(i * 16 + (tid >> 4)) * 136 + (tid & 15) * 8]) = kreg[i];
        *(bf16x8*)(&Vs[(i * 32 + (tid >> 3)) * 72 + (tid & 7) * 8]) = vreg[i];
    }

    for (int kt = 0; kt < NS / 64; ++kt) {
        __syncthreads();
        if (kt + 1 < NS / 64) stage_load(Kp, Vp, kt + 1, tid, kreg, vreg);

        f32x4 s[2][4] = {};
#pragma unroll
        for (int kk = 0; kk < 4; ++kk) {
            bf16x8 kf[4];
#pragma unroll
            for (int n = 0; n < 4; ++n)
                kf[n] = *(const bf16x8*)(&Ks[(n * 16 + l15) * 136 + kk * 32 + l4 * 8]);
#pragma unroll
            for (int m = 0; m < 2; ++m)
#pragma unroll
                for (int n = 0; n < 4; ++n)
                    s[m][n] = __builtin_amdgcn_mfma_f32_16x16x32_bf16(kf[n], qf[m][kk], s[m][n], 0, 0, 0);
        }

        float4 mk[4];
#pragma unroll
        for (int n = 0; n < 4; ++n)
            mk[n] = *(const float4*)(maskp + kt * 64 + n * 16 + l4 * 4);

#pragma unroll
        for (int mq = 0; mq < 2; ++mq) {
            float sv[4][4];
#pragma unroll
            for (int n = 0; n < 4; ++n) {
                sv[n][0] = s[mq][n][0] + eb[0] + mk[n].x;
                sv[n][1] = s[mq][n][1] + eb[1] + mk[n].y;
                sv[n][2] = s[mq][n][2] + eb[2] + mk[n].z;
                sv[n][3] = s[mq][n][3] + eb[3] + mk[n].w;
            }
            float tmax = sv[0][0];
#pragma unroll
            for (int n = 0; n < 4; ++n)
#pragma unroll
                for (int r = 0; r < 4; ++r) tmax = fmaxf(tmax, sv[n][r]);
            tmax = fmaxf(tmax, __shfl_xor(tmax, 16));
            tmax = fmaxf(tmax, __shfl_xor(tmax, 32));

            if (__any(tmax > mrun[mq] + 8.0f)) {
                float mnew = fmaxf(mrun[mq], tmax);
                float corr = __expf(mrun[mq] - mnew);
                mrun[mq] = mnew;
                lrun[mq] *= corr;
#pragma unroll
                for (int r = 0; r < 4; ++r) {
                    float cr = __shfl(corr, l4 * 4 + r);
#pragma unroll
                    for (int n = 0; n < 8; ++n) oacc[mq][n][r] *= cr;
                }
            }

            float psum = 0.f;
#pragma unroll
            for (int n = 0; n < 4; ++n) {
                bf16x4 pv;
#pragma unroll
                for (int r = 0; r < 4; ++r) {
                    float p = __expf(sv[n][r] - mrun[mq]);
                    psum += p;
                    pv[r] = (bf16)p;
                }
                *(bf16x4*)(&Ps[wid][(mq * 16 + l15) * 72 + n * 16 + l4 * 4]) = pv;
            }
            psum += __shfl_xor(psum, 16);
            psum += __shfl_xor(psum, 32);
            lrun[mq] += psum;
        }

#pragma unroll
        for (int kk = 0; kk < 2; ++kk) {
            bf16x8 pa[2], vb[8];
#pragma unroll
            for (int m = 0; m < 2; ++m)
                pa[m] = *(const bf16x8*)(&Ps[wid][(m * 16 + l15) * 72 + kk * 32 + l4 * 8]);
#pragma unroll
            for (int n = 0; n < 8; ++n)
                vb[n] = *(const bf16x8*)(&Vs[(n * 16 + l15) * 72 + kk * 32 + l4 * 8]);
#pragma unroll
            for (int m = 0; m < 2; ++m)
#pragma unroll
                for (int n = 0; n < 8; ++n)
                    oacc[m][n] = __builtin_amdgcn_mfma_f32_16x16x32_bf16(pa[m], vb[n], oacc[m][n], 0, 0, 0);
        }
        __syncthreads();
        if (kt + 1 < NS / 64) {
#pragma unroll
            for (int i = 0; i < 4; ++i) {
                *(bf16x8*)(&Ks[(i * 16 + (tid >> 4)) * 136 + (tid & 15) * 8]) = kreg[i];
                *(bf16x8*)(&Vs[(i * 32 + (tid >> 3)) * 72 + (tid & 7) * 8]) = vreg[i];
            }
        }
    }

#pragma unroll
    for (int m = 0; m < 2; ++m) {
        float inv = 1.0f / lrun[m];
        float invr[4];
#pragma unroll
        for (int r = 0; r < 4; ++r) invr[r] = __shfl(inv, l4 * 4 + r);
#pragma unroll
        for (int r = 0; r < 4; ++r) {
            int row = qt * 128 + wid * 32 + m * 16 + l4 * 4 + r;
            bf16* Cp = Ctx + ((size_t)b * NS + row) * HID2 + h * ND;
#pragma unroll
            for (int n = 0; n < 8; ++n)
                Cp[n * 16 + l15] = (bf16)(oacc[m][n][r] * invr[r]);
        }
    }
}

// ---------------------------------------------------------------- launch
extern "C" void kernel_launch(void* const* d_in, const int* in_sizes, int n_in,
                              void* d_out, int out_size, void* d_ws, size_t ws_size,
                              hipStream_t stream) {
    const float* hidden = (const float*)d_in[0];
    const float* mask   = (const float*)d_in[1];
    const float* q_real = (const float*)d_in[2];
    const float* q_imag = (const float*)d_in[3];
    const float* q_mag  = (const float*)d_in[5];
    const float* k_real = (const float*)d_in[6];
    const float* k_imag = (const float*)d_in[7];
    const float* k_mag  = (const float*)d_in[9];
    const float* v_real = (const float*)d_in[10];
    const float* v_imag = (const float*)d_in[11];
    const float* v_mag  = (const float*)d_in[13];
    const float* Wq = (const float*)d_in[14];
    const float* bq = (const float*)d_in[15];
    const float* Wk = (const float*)d_in[16];
    const float* bk = (const float*)d_in[17];
    const float* Wv = (const float*)d_in[18];
    const float* bv = (const float*)d_in[19];
    const float* Wo = (const float*)d_in[20];
    const float* bo = (const float*)d_in[21];
    const float* ent = (const float*)d_in[22];

    char* ws = (char*)d_ws;
    bf16* Xb    = (bf16*)(ws);
    bf16* Wb    = (bf16*)(ws + 16777216);        // Wq,Wk,Wv,Wo bf16 contiguous
    bf16* Wob   = (bf16*)(ws + 41943040);
    bf16* QKV   = (bf16*)(ws + 50331648);        // Q,K,V bf16 stacked
    bf16* Vt    = (bf16*)(ws + 100663296);
    bf16* Ctx   = (bf16*)(ws + 117440512);
    float* scales = (float*)(ws + 134217728);

    cvt_f32_bf16<<<4096, 256, 0, stream>>>(hidden, Xb, MROWS * HID2 / 8);
    cvt_w4<<<dim3(2048, 4), 256, 0, stream>>>(Wq, Wk, Wv, Wo, Wb);
    qscale_kernel<<<8, 256, 0, stream>>>(q_real, q_imag, q_mag, k_real, k_imag, k_mag,
                                         v_real, v_imag, v_mag, scales);
    gemm_qkv<<<512, 256, 0, stream>>>(Xb, Wb, bq, bk, bv, scales, QKV);
    const bf16* Vb = QKV + (size_t)2 * MROWS * HID2;
    transpose_v<<<dim3(32, 2, 32), 256, 0, stream>>>(Vb, Vt);
    flash_kernel<<<512, 256, 0, stream>>>(QKV, QKV + (size_t)MROWS * HID2, Vt, ent, mask, Ctx);
    gemm_out<<<256, 512, 0, stream>>>(Ctx, Wob, bo, (float*)d_out);
}

// Round 14
// 283.469 us; speedup vs baseline: 1.4405x; 1.0317x over previous
//
#include <hip/hip_runtime.h>
#include <hip/hip_bf16.h>

#define NB 2
#define NS 2048
#define NH 16
#define ND 128
#define HID2 2048
#define MROWS 4096   // NB*NS

typedef __bf16 bf16;
typedef bf16 bf16x8 __attribute__((ext_vector_type(8)));
typedef bf16 bf16x4 __attribute__((ext_vector_type(4)));
typedef float f32x4 __attribute__((ext_vector_type(4)));
typedef unsigned int u32;

#define GLOBAL_AS __attribute__((address_space(1)))
#define LDS_AS __attribute__((address_space(3)))

__device__ __forceinline__ void async16(void* lds, const void* g) {
    __builtin_amdgcn_global_load_lds((const GLOBAL_AS u32*)g, (LDS_AS u32*)lds, 16, 0, 0);
}

// ---------------------------------------------------------------- fused prep
// One kernel: hidden f32->bf16 (4096 blocks), Wq/Wk/Wv/Wo f32->bf16 (4x2048),
// quantum scales (8 blocks, 1/sqrt(D) folded into Q scale).
__device__ __forceinline__ void cvt8(const float* __restrict__ src, bf16* __restrict__ dst, int i) {
    const float4* s4 = (const float4*)src;
    float4 a = s4[2 * i], b = s4[2 * i + 1];
    bf16x8 o;
    o[0] = (bf16)a.x; o[1] = (bf16)a.y; o[2] = (bf16)a.z; o[3] = (bf16)a.w;
    o[4] = (bf16)b.x; o[5] = (bf16)b.y; o[6] = (bf16)b.z; o[7] = (bf16)b.w;
    ((bf16x8*)dst)[i] = o;
}

__global__ __launch_bounds__(256) void prep_kernel(
    const float* __restrict__ hidden,
    const float* __restrict__ Wq, const float* __restrict__ Wk,
    const float* __restrict__ Wv, const float* __restrict__ Wo,
    const float* __restrict__ qr, const float* __restrict__ qi, const float* __restrict__ qm,
    const float* __restrict__ kr, const float* __restrict__ ki, const float* __restrict__ km,
    const float* __restrict__ vr, const float* __restrict__ vi, const float* __restrict__ vm,
    bf16* __restrict__ Xb, bf16* __restrict__ Wb, float* __restrict__ scales) {
    int gb = blockIdx.x, tid = threadIdx.x;
    if (gb < 4096) {                       // hidden: 4096*256 = MROWS*HID2/8 exactly
        cvt8(hidden, Xb, gb * 256 + tid);
    } else if (gb < 12288) {               // weights: 4 x 2048 blocks, 2048*256 = HID2*HID2/8
        int zz = (gb - 4096) >> 11;
        int i = ((gb - 4096) & 2047) * 256 + tid;
        const float* src = (zz == 0) ? Wq : (zz == 1) ? Wk : (zz == 2) ? Wv : Wo;
        cvt8(src, Wb + (size_t)zz * HID2 * HID2, i);
    } else {                               // qscale: 8 blocks
        int i = (gb - 12288) * 256 + tid;
        if (i < HID2) {
            const float RSQD = 0.08838834764831845f;  // 1/sqrt(128) folded into Q scale
            scales[i]            = sqrtf(qr[i] * qr[i] + qi[i] * qi[i]) * fabsf(qm[i]) * RSQD;
            scales[HID2 + i]     = sqrtf(kr[i] * kr[i] + ki[i] * ki[i]) * fabsf(km[i]);
            scales[2 * HID2 + i] = sqrtf(vr[i] * vr[i] + vi[i] * vi[i]) * fabsf(vm[i]);
        }
    }
}

// ---------------------------------------------------------------- loose GEMM (r7 core, balanced multi-tile)
__device__ __forceinline__ void stage12(const char* gA, const char* gB,
                                        char* sa, char* sb, int w, int lane, size_t kb) {
    int r8 = lane >> 3;
    int cx = (lane & 7) * 16;
#pragma unroll
    for (int j = 0; j < 4; ++j) {
        int r = w * 32 + j * 8 + r8;
        async16(sa + (w * 32 + j * 8) * 128,
                gA + (size_t)r * (HID2 * 2) + kb + (cx ^ ((r & 7) << 4)));
    }
#pragma unroll
    for (int j = 0; j < 8; ++j) {
        int r = w * 64 + j * 8 + r8;
        async16(sb + (w * 64 + j * 8) * 128,
                gB + (size_t)r * (HID2 * 2) + kb + (cx ^ ((r & 7) << 4)));
    }
}

__global__ __launch_bounds__(256, 2) void gemm_qkv(
    const bf16* __restrict__ X, const bf16* __restrict__ Wb,
    const float* __restrict__ bq, const float* __restrict__ bk, const float* __restrict__ bv,
    const float* __restrict__ scales, bf16* __restrict__ QKV) {
    __shared__ bf16 sA[128 * 64];   // 16 KB
    __shared__ bf16 sB[256 * 64];   // 32 KB
    int b0 = blockIdx.x;            // 0..511
    int tid = threadIdx.x, w = tid >> 6, lane = tid & 63;
    int wr = w >> 1, wc = w & 1;
    int l15 = lane & 15, l4 = lane >> 4;
    int xorb = (l15 & 7) << 4;
    int ntile = (b0 < 256) ? 2 : 1;

    for (int it = 0; it < ntile; ++it) {
        int t = (it == 0) ? b0 : 512 + b0;
        int p = t & 7, q = t >> 3;      // XCD p keeps B-panel p resident
        int z = q >> 5, tm = q & 31, tn = p;
        const bf16* Bt = Wb + (size_t)z * HID2 * HID2;
        const float* bias = (z == 0) ? bq : (z == 1) ? bk : bv;
        const float* scale = scales + z * HID2;
        bf16* Cout = QKV + (size_t)z * MROWS * HID2;

        const char* gA = (const char*)X + (size_t)tm * 128 * (HID2 * 2);
        const char* gB = (const char*)Bt + (size_t)tn * 256 * (HID2 * 2);
        const char* pa = (const char*)sA;
        const char* pb = (const char*)sB;

        f32x4 acc[4][8] = {};

        for (int kt = 0; kt < HID2 / 64; ++kt) {
            stage12(gA, gB, (char*)sA, (char*)sB, w, lane, (size_t)kt * 128);
            __syncthreads();
#pragma unroll
            for (int kk = 0; kk < 2; ++kk) {
                int kc = (kk * 64 + l4 * 16) ^ xorb;
                bf16x8 af[4], bg[4];
#pragma unroll
                for (int m = 0; m < 4; ++m)
                    af[m] = *(const bf16x8*)(pa + (wr * 64 + m * 16 + l15) * 128 + kc);
#pragma unroll
                for (int n = 0; n < 4; ++n)
                    bg[n] = *(const bf16x8*)(pb + (wc * 128 + n * 16 + l15) * 128 + kc);
#pragma unroll
                for (int m = 0; m < 4; ++m)
#pragma unroll
                    for (int n = 0; n < 4; ++n)
                        acc[m][n] = __builtin_amdgcn_mfma_f32_16x16x32_bf16(af[m], bg[n], acc[m][n], 0, 0, 0);
#pragma unroll
                for (int n = 0; n < 4; ++n)
                    bg[n] = *(const bf16x8*)(pb + (wc * 128 + (n + 4) * 16 + l15) * 128 + kc);
#pragma unroll
                for (int m = 0; m < 4; ++m)
#pragma unroll
                    for (int n = 0; n < 4; ++n)
                        acc[m][n + 4] = __builtin_amdgcn_mfma_f32_16x16x32_bf16(af[m], bg[n], acc[m][n + 4], 0, 0, 0);
            }
            __syncthreads();
        }

        // epilogue: bf16 out = |acc + bias| * scale
#pragma unroll
        for (int n = 0; n < 8; ++n) {
            int col = tn * 256 + wc * 128 + n * 16 + l15;
            float bv2 = bias[col];
            float sc = scale[col];
#pragma unroll
            for (int m = 0; m < 4; ++m) {
                int row = tm * 128 + wr * 64 + m * 16 + l4 * 4;
#pragma unroll
                for (int r = 0; r < 4; ++r)
                    Cout[(size_t)(row + r) * HID2 + col] = (bf16)(fabsf(acc[m][n][r] + bv2) * sc);
            }
        }
    }
}

// ---------------------------------------------------------------- phased GEMM (r8, for out)
__device__ __forceinline__ void stage2A(const char* gA, char* sa, int w, int lane, size_t kb) {
#pragma unroll
    for (int j = 0; j < 2; ++j) {
        int r = w * 16 + j * 8 + (lane >> 3);
        async16(sa + (w * 16 + j * 8) * 128,
                gA + (size_t)r * (HID2 * 2) + kb + (((lane & 7) * 16) ^ ((r & 7) << 4)));
    }
}
__device__ __forceinline__ void stage2B(const char* gB, char* sb, int w, int lane, int half, size_t kb) {
#pragma unroll
    for (int j = 0; j < 2; ++j) {
        int r = half * 128 + w * 16 + j * 8 + (lane >> 3);
        async16(sb + (half * 128 + w * 16 + j * 8) * 128,
                gB + (size_t)r * (HID2 * 2) + kb + (((lane & 7) * 16) ^ ((r & 7) << 4)));
    }
}

#define G_BARRIER() do { asm volatile("" ::: "memory"); __builtin_amdgcn_s_barrier(); \
                         asm volatile("" ::: "memory"); } while (0)

__global__ __launch_bounds__(512, 2) void gemm_out(
    const bf16* __restrict__ Ctx, const bf16* __restrict__ Wo,
    const float* __restrict__ bo, float* __restrict__ out) {
    __shared__ bf16 sA[3][128 * 64];
    __shared__ bf16 sB[3][256 * 64];
    const int NT = HID2 / 64;  // 32
    int bid = blockIdx.x;             // 0..255 = 1 exact round
    int tn = bid & 7, tm = bid >> 3;
    int tid = threadIdx.x, w = tid >> 6, lane = tid & 63;
    int wr = w >> 2, wc = w & 3;
    int l15 = lane & 15, l4 = lane >> 4;
    int xorb = (l15 & 7) << 4;

    const char* gA = (const char*)Ctx + (size_t)tm * 128 * (HID2 * 2);
    const char* gB = (const char*)Wo + (size_t)tn * 256 * (HID2 * 2);

    f32x4 acc[4][4] = {};

    stage2A(gA, (char*)sA[0], w, lane, 0);
    stage2B(gB, (char*)sB[0], w, lane, 0, 0);
    stage2B(gB, (char*)sB[0], w, lane, 1, 0);
    stage2A(gA, (char*)sA[1], w, lane, 128);
    stage2B(gB, (char*)sB[1], w, lane, 0, 128);
    stage2B(gB, (char*)sB[1], w, lane, 1, 128);
    asm volatile("s_waitcnt vmcnt(6)" ::: "memory");
    G_BARRIER();

    int cur = 0;
    for (int t = 0; t < NT; ++t) {
        const char* pa = (const char*)sA[cur];
        const char* pb = (const char*)sB[cur];
        int nb = cur + 2; if (nb >= 3) nb -= 3;
        const bool pre = (t + 2 < NT);
        size_t kb = (size_t)(t + 2) * 128;
        bf16x8 af[4], bg[4];

        {
            int kc = (l4 * 16) ^ xorb;
#pragma unroll
            for (int m = 0; m < 4; ++m)
                af[m] = *(const bf16x8*)(pa + (wr * 64 + m * 16 + l15) * 128 + kc);
#pragma unroll
            for (int n = 0; n < 4; ++n)
                bg[n] = *(const bf16x8*)(pb + (wc * 64 + n * 16 + l15) * 128 + kc);
        }
        if (pre) { stage2A(gA, (char*)sA[nb], w, lane, kb); stage2B(gB, (char*)sB[nb], w, lane, 0, kb); }
        G_BARRIER();
        asm volatile("s_waitcnt lgkmcnt(0)" ::: "memory");
        __builtin_amdgcn_sched_barrier(0);
        __builtin_amdgcn_s_setprio(1);
#pragma unroll
        for (int m = 0; m < 4; ++m)
#pragma unroll
            for (int n = 0; n < 4; ++n)
                acc[m][n] = __builtin_amdgcn_mfma_f32_16x16x32_bf16(af[m], bg[n], acc[m][n], 0, 0, 0);
        __builtin_amdgcn_s_setprio(0);
        G_BARRIER();

        {
            int kc = (64 + l4 * 16) ^ xorb;
#pragma unroll
            for (int m = 0; m < 4; ++m)
                af[m] = *(const bf16x8*)(pa + (wr * 64 + m * 16 + l15) * 128 + kc);
#pragma unroll
            for (int n = 0; n < 4; ++n)
                bg[n] = *(const bf16x8*)(pb + (wc * 64 + n * 16 + l15) * 128 + kc);
        }
        if (pre) stage2B(gB, (char*)sB[nb], w, lane, 1, kb);
        G_BARRIER();
        asm volatile("s_waitcnt lgkmcnt(0)" ::: "memory");
        __builtin_amdgcn_sched_barrier(0);
        __builtin_amdgcn_s_setprio(1);
#pragma unroll
        for (int m = 0; m < 4; ++m)
#pragma unroll
            for (int n = 0; n < 4; ++n)
                acc[m][n] = __builtin_amdgcn_mfma_f32_16x16x32_bf16(af[m], bg[n], acc[m][n], 0, 0, 0);
        __builtin_amdgcn_s_setprio(0);
        if (pre)               { asm volatile("s_waitcnt vmcnt(6)" ::: "memory"); }
        else if (t + 2 == NT)  { asm volatile("s_waitcnt vmcnt(0)" ::: "memory"); }
        G_BARRIER();

        cur = cur + 1; if (cur == 3) cur = 0;
    }

#pragma unroll
    for (int n = 0; n < 4; ++n) {
        int col = tn * 256 + wc * 64 + n * 16 + l15;
        float bv = bo[col];
#pragma unroll
        for (int m = 0; m < 4; ++m) {
            int row = tm * 128 + wr * 64 + m * 16 + l4 * 4;
#pragma unroll
            for (int r = 0; r < 4; ++r)
                out[(size_t)(row + r) * HID2 + col] = acc[m][n][r] + bv;
        }
    }
}

// ---------------------------------------------------------------- V transpose
__global__ void transpose_v(const bf16* __restrict__ Vb, bf16* __restrict__ Vt) {
    int bh = blockIdx.z;
    int b = bh >> 4, h = bh & 15;
    int s0 = blockIdx.x * 64, d0 = blockIdx.y * 64;
    int tid = threadIdx.x;
    __shared__ bf16 T[64][72];
    const bf16* src = Vb + ((size_t)b * NS + s0) * HID2 + h * ND + d0;
#pragma unroll
    for (int i = 0; i < 2; ++i) {
        int r = i * 32 + (tid >> 3);
        int c = (tid & 7) * 8;
        *(bf16x8*)(&T[r][c]) = *(const bf16x8*)(src + (size_t)r * HID2 + c);
    }
    __syncthreads();
    bf16* dst = Vt + ((size_t)(b * NH + h) * ND + d0) * NS + s0;
#pragma unroll
    for (int i = 0; i < 2; ++i) {
        int dr = i * 32 + (tid >> 3);
        int sc = (tid & 7) * 8;
        bf16x8 o;
#pragma unroll
        for (int j = 0; j < 8; ++j) o[j] = T[sc + j][dr];
        *(bf16x8*)(dst + (size_t)dr * NS + sc) = o;
    }
}

// ---------------------------------------------------------------- flash attention (v4)
__device__ __forceinline__ void stage_load(const bf16* __restrict__ Kp, const bf16* __restrict__ Vp,
                                           int kt, int tid, bf16x8 kreg[4], bf16x8 vreg[4]) {
#pragma unroll
    for (int i = 0; i < 4; ++i) {
        kreg[i] = *(const bf16x8*)(Kp + (size_t)(kt * 64 + i * 16 + (tid >> 4)) * HID2 + (tid & 15) * 8);
        vreg[i] = *(const bf16x8*)(Vp + (size_t)(i * 32 + (tid >> 3)) * NS + kt * 64 + (tid & 7) * 8);
    }
}

__global__ __launch_bounds__(256, 2) void flash_kernel(
    const bf16* __restrict__ Qb, const bf16* __restrict__ Kb, const bf16* __restrict__ Vt,
    const float* __restrict__ ent, const float* __restrict__ mask, bf16* __restrict__ Ctx) {
    int bid = blockIdx.x;                       // 0..511
    int qt = bid >> 5;                          // 0..15
    int bh = (bid & 7) * 4 + ((bid >> 3) & 3);  // XCD (bid%8) owns bh 4x..4x+3
    int b = bh >> 4, h = bh & 15;
    int tid = threadIdx.x, wid = tid >> 6, lane = tid & 63;
    int l15 = lane & 15, l4 = lane >> 4;

    __shared__ bf16 Ks[64 * 136];
    __shared__ bf16 Vs[128 * 72];
    __shared__ bf16 Ps[4][32 * 72];

    const bf16* Qp = Qb + ((size_t)b * NS + qt * 128) * HID2 + h * ND;
    const bf16* Kp = Kb + (size_t)b * NS * HID2 + h * ND;
    const bf16* Vp = Vt + (size_t)(b * NH + h) * ND * NS;
    const float* maskp = mask + (size_t)b * NS;

    bf16x8 qf[2][4];
#pragma unroll
    for (int m = 0; m < 2; ++m)
#pragma unroll
        for (int kk = 0; kk < 4; ++kk)
            qf[m][kk] = *(const bf16x8*)(Qp + (size_t)(wid * 32 + m * 16 + l15) * HID2 + kk * 32 + l4 * 8);

    float eb[4];
#pragma unroll
    for (int r = 0; r < 4; ++r) eb[r] = ent[h * NH + l4 * 4 + r];

    float mrun[2], lrun[2];
    mrun[0] = mrun[1] = -INFINITY;
    lrun[0] = lrun[1] = 0.f;
    f32x4 oacc[2][8] = {};

    bf16x8 kreg[4], vreg[4];
    stage_load(Kp, Vp, 0, tid, kreg, vreg);
#pragma unroll
    for (int i = 0; i < 4; ++i) {
        *(bf16x8*)(&Ks[(i * 16 + (tid >> 4)) * 136 + (tid & 15) * 8]) = kreg[i];
        *(bf16x8*)(&Vs[(i * 32 + (tid >> 3)) * 72 + (tid & 7) * 8]) = vreg[i];
    }

    for (int kt = 0; kt < NS / 64; ++kt) {
        __syncthreads();
        if (kt + 1 < NS / 64) stage_load(Kp, Vp, kt + 1, tid, kreg, vreg);

        f32x4 s[2][4] = {};
#pragma unroll
        for (int kk = 0; kk < 4; ++kk) {
            bf16x8 kf[4];
#pragma unroll
            for (int n = 0; n < 4; ++n)
                kf[n] = *(const bf16x8*)(&Ks[(n * 16 + l15) * 136 + kk * 32 + l4 * 8]);
#pragma unroll
            for (int m = 0; m < 2; ++m)
#pragma unroll
                for (int n = 0; n < 4; ++n)
                    s[m][n] = __builtin_amdgcn_mfma_f32_16x16x32_bf16(kf[n], qf[m][kk], s[m][n], 0, 0, 0);
        }

        float4 mk[4];
#pragma unroll
        for (int n = 0; n < 4; ++n)
            mk[n] = *(const float4*)(maskp + kt * 64 + n * 16 + l4 * 4);

#pragma unroll
        for (int mq = 0; mq < 2; ++mq) {
            float sv[4][4];
#pragma unroll
            for (int n = 0; n < 4; ++n) {
                sv[n][0] = s[mq][n][0] + eb[0] + mk[n].x;
                sv[n][1] = s[mq][n][1] + eb[1] + mk[n].y;
                sv[n][2] = s[mq][n][2] + eb[2] + mk[n].z;
                sv[n][3] = s[mq][n][3] + eb[3] + mk[n].w;
            }
            float tmax = sv[0][0];
#pragma unroll
            for (int n = 0; n < 4; ++n)
#pragma unroll
                for (int r = 0; r < 4; ++r) tmax = fmaxf(tmax, sv[n][r]);
            tmax = fmaxf(tmax, __shfl_xor(tmax, 16));
            tmax = fmaxf(tmax, __shfl_xor(tmax, 32));

            if (__any(tmax > mrun[mq] + 8.0f)) {
                float mnew = fmaxf(mrun[mq], tmax);
                float corr = __expf(mrun[mq] - mnew);
                mrun[mq] = mnew;
                lrun[mq] *= corr;
#pragma unroll
                for (int r = 0; r < 4; ++r) {
                    float cr = __shfl(corr, l4 * 4 + r);
#pragma unroll
                    for (int n = 0; n < 8; ++n) oacc[mq][n][r] *= cr;
                }
            }

            float psum = 0.f;
#pragma unroll
            for (int n = 0; n < 4; ++n) {
                bf16x4 pv;
#pragma unroll
                for (int r = 0; r < 4; ++r) {
                    float p = __expf(sv[n][r] - mrun[mq]);
                    psum += p;
                    pv[r] = (bf16)p;
                }
                *(bf16x4*)(&Ps[wid][(mq * 16 + l15) * 72 + n * 16 + l4 * 4]) = pv;
            }
            psum += __shfl_xor(psum, 16);
            psum += __shfl_xor(psum, 32);
            lrun[mq] += psum;
        }

#pragma unroll
        for (int kk = 0; kk < 2; ++kk) {
            bf16x8 pa[2], vb[8];
#pragma unroll
            for (int m = 0; m < 2; ++m)
                pa[m] = *(const bf16x8*)(&Ps[wid][(m * 16 + l15) * 72 + kk * 32 + l4 * 8]);
#pragma unroll
            for (int n = 0; n < 8; ++n)
                vb[n] = *(const bf16x8*)(&Vs[(n * 16 + l15) * 72 + kk * 32 + l4 * 8]);
#pragma unroll
            for (int m = 0; m < 2; ++m)
#pragma unroll
                for (int n = 0; n < 8; ++n)
                    oacc[m][n] = __builtin_amdgcn_mfma_f32_16x16x32_bf16(pa[m], vb[n], oacc[m][n], 0, 0, 0);
        }
        __syncthreads();
        if (kt + 1 < NS / 64) {
#pragma unroll
            for (int i = 0; i < 4; ++i) {
                *(bf16x8*)(&Ks[(i * 16 + (tid >> 4)) * 136 + (tid & 15) * 8]) = kreg[i];
                *(bf16x8*)(&Vs[(i * 32 + (tid >> 3)) * 72 + (tid & 7) * 8]) = vreg[i];
            }
        }
    }

#pragma unroll
    for (int m = 0; m < 2; ++m) {
        float inv = 1.0f / lrun[m];
        float invr[4];
#pragma unroll
        for (int r = 0; r < 4; ++r) invr[r] = __shfl(inv, l4 * 4 + r);
#pragma unroll
        for (int r = 0; r < 4; ++r) {
            int row = qt * 128 + wid * 32 + m * 16 + l4 * 4 + r;
            bf16* Cp = Ctx + ((size_t)b * NS + row) * HID2 + h * ND;
#pragma unroll
            for (int n = 0; n < 8; ++n)
                Cp[n * 16 + l15] = (bf16)(oacc[m][n][r] * invr[r]);
        }
    }
}

// ---------------------------------------------------------------- launch
extern "C" void kernel_launch(void* const* d_in, const int* in_sizes, int n_in,
                              void* d_out, int out_size, void* d_ws, size_t ws_size,
                              hipStream_t stream) {
    const float* hidden = (const float*)d_in[0];
    const float* mask   = (const float*)d_in[1];
    const float* q_real = (const float*)d_in[2];
    const float* q_imag = (const float*)d_in[3];
    const float* q_mag  = (const float*)d_in[5];
    const float* k_real = (const float*)d_in[6];
    const float* k_imag = (const float*)d_in[7];
    const float* k_mag  = (const float*)d_in[9];
    const float* v_real = (const float*)d_in[10];
    const float* v_imag = (const float*)d_in[11];
    const float* v_mag  = (const float*)d_in[13];
    const float* Wq = (const float*)d_in[14];
    const float* bq = (const float*)d_in[15];
    const float* Wk = (const float*)d_in[16];
    const float* bk = (const float*)d_in[17];
    const float* Wv = (const float*)d_in[18];
    const float* bv = (const float*)d_in[19];
    const float* Wo = (const float*)d_in[20];
    const float* bo = (const float*)d_in[21];
    const float* ent = (const float*)d_in[22];

    char* ws = (char*)d_ws;
    bf16* Xb    = (bf16*)(ws);
    bf16* Wb    = (bf16*)(ws + 16777216);        // Wq,Wk,Wv,Wo bf16 contiguous
    bf16* Wob   = (bf16*)(ws + 41943040);
    bf16* QKV   = (bf16*)(ws + 50331648);        // Q,K,V bf16 stacked
    bf16* Vt    = (bf16*)(ws + 100663296);
    bf16* Ctx   = (bf16*)(ws + 117440512);
    float* scales = (float*)(ws + 134217728);

    prep_kernel<<<12296, 256, 0, stream>>>(hidden, Wq, Wk, Wv, Wo,
                                           q_real, q_imag, q_mag, k_real, k_imag, k_mag,
                                           v_real, v_imag, v_mag, Xb, Wb, scales);
    gemm_qkv<<<512, 256, 0, stream>>>(Xb, Wb, bq, bk, bv, scales, QKV);
    const bf16* Vb = QKV + (size_t)2 * MROWS * HID2;
    transpose_v<<<dim3(32, 2, 32), 256, 0, stream>>>(Vb, Vt);
    flash_kernel<<<512, 256, 0, stream>>>(QKV, QKV + (size_t)MROWS * HID2, Vt, ent, mask, Ctx);
    gemm_out<<<256, 512, 0, stream>>>(Ctx, Wob, bo, (float*)d_out);
}

// Round 15
// 280.331 us; speedup vs baseline: 1.4566x; 1.0112x over previous
//
#include <hip/hip_runtime.h>
#include <hip/hip_bf16.h>

#define NB 2
#define NS 2048
#define NH 16
#define ND 128
#define HID2 2048
#define MROWS 4096   // NB*NS

typedef __bf16 bf16;
typedef bf16 bf16x8 __attribute__((ext_vector_type(8)));
typedef bf16 bf16x4 __attribute__((ext_vector_type(4)));
typedef float f32x4 __attribute__((ext_vector_type(4)));
typedef unsigned int u32;

#define GLOBAL_AS __attribute__((address_space(1)))
#define LDS_AS __attribute__((address_space(3)))

__device__ __forceinline__ void async16(void* lds, const void* g) {
    __builtin_amdgcn_global_load_lds((const GLOBAL_AS u32*)g, (LDS_AS u32*)lds, 16, 0, 0);
}

// ---------------------------------------------------------------- fused prep
__device__ __forceinline__ void cvt8(const float* __restrict__ src, bf16* __restrict__ dst, int i) {
    const float4* s4 = (const float4*)src;
    float4 a = s4[2 * i], b = s4[2 * i + 1];
    bf16x8 o;
    o[0] = (bf16)a.x; o[1] = (bf16)a.y; o[2] = (bf16)a.z; o[3] = (bf16)a.w;
    o[4] = (bf16)b.x; o[5] = (bf16)b.y; o[6] = (bf16)b.z; o[7] = (bf16)b.w;
    ((bf16x8*)dst)[i] = o;
}

__global__ __launch_bounds__(256) void prep_kernel(
    const float* __restrict__ hidden,
    const float* __restrict__ Wq, const float* __restrict__ Wk,
    const float* __restrict__ Wv, const float* __restrict__ Wo,
    const float* __restrict__ qr, const float* __restrict__ qi, const float* __restrict__ qm,
    const float* __restrict__ kr, const float* __restrict__ ki, const float* __restrict__ km,
    const float* __restrict__ vr, const float* __restrict__ vi, const float* __restrict__ vm,
    bf16* __restrict__ Xb, bf16* __restrict__ Wb, float* __restrict__ scales) {
    int gb = blockIdx.x, tid = threadIdx.x;
    if (gb < 4096) {
        cvt8(hidden, Xb, gb * 256 + tid);
    } else if (gb < 12288) {
        int zz = (gb - 4096) >> 11;
        int i = ((gb - 4096) & 2047) * 256 + tid;
        const float* src = (zz == 0) ? Wq : (zz == 1) ? Wk : (zz == 2) ? Wv : Wo;
        cvt8(src, Wb + (size_t)zz * HID2 * HID2, i);
    } else {
        int i = (gb - 12288) * 256 + tid;
        if (i < HID2) {
            const float RSQD = 0.08838834764831845f;  // 1/sqrt(128) folded into Q scale
            scales[i]            = sqrtf(qr[i] * qr[i] + qi[i] * qi[i]) * fabsf(qm[i]) * RSQD;
            scales[HID2 + i]     = sqrtf(kr[i] * kr[i] + ki[i] * ki[i]) * fabsf(km[i]);
            scales[2 * HID2 + i] = sqrtf(vr[i] * vr[i] + vi[i] * vi[i]) * fabsf(vm[i]);
        }
    }
}

// ---------------------------------------------------------------- loose GEMM (r7 core, balanced multi-tile)
__device__ __forceinline__ void stage12(const char* gA, const char* gB,
                                        char* sa, char* sb, int w, int lane, size_t kb) {
    int r8 = lane >> 3;
    int cx = (lane & 7) * 16;
#pragma unroll
    for (int j = 0; j < 4; ++j) {
        int r = w * 32 + j * 8 + r8;
        async16(sa + (w * 32 + j * 8) * 128,
                gA + (size_t)r * (HID2 * 2) + kb + (cx ^ ((r & 7) << 4)));
    }
#pragma unroll
    for (int j = 0; j < 8; ++j) {
        int r = w * 64 + j * 8 + r8;
        async16(sb + (w * 64 + j * 8) * 128,
                gB + (size_t)r * (HID2 * 2) + kb + (cx ^ ((r & 7) << 4)));
    }
}

__global__ __launch_bounds__(256, 2) void gemm_qkv(
    const bf16* __restrict__ X, const bf16* __restrict__ Wb,
    const float* __restrict__ bq, const float* __restrict__ bk, const float* __restrict__ bv,
    const float* __restrict__ scales, bf16* __restrict__ QKV) {
    __shared__ bf16 sA[128 * 64];   // 16 KB
    __shared__ bf16 sB[256 * 64];   // 32 KB
    int b0 = blockIdx.x;            // 0..511
    int tid = threadIdx.x, w = tid >> 6, lane = tid & 63;
    int wr = w >> 1, wc = w & 1;
    int l15 = lane & 15, l4 = lane >> 4;
    int xorb = (l15 & 7) << 4;
    int ntile = (b0 < 256) ? 2 : 1;

    for (int it = 0; it < ntile; ++it) {
        int t = (it == 0) ? b0 : 512 + b0;
        int p = t & 7, q = t >> 3;
        int z = q >> 5, tm = q & 31, tn = p;
        const bf16* Bt = Wb + (size_t)z * HID2 * HID2;
        const float* bias = (z == 0) ? bq : (z == 1) ? bk : bv;
        const float* scale = scales + z * HID2;
        bf16* Cout = QKV + (size_t)z * MROWS * HID2;

        const char* gA = (const char*)X + (size_t)tm * 128 * (HID2 * 2);
        const char* gB = (const char*)Bt + (size_t)tn * 256 * (HID2 * 2);
        const char* pa = (const char*)sA;
        const char* pb = (const char*)sB;

        f32x4 acc[4][8] = {};

        for (int kt = 0; kt < HID2 / 64; ++kt) {
            stage12(gA, gB, (char*)sA, (char*)sB, w, lane, (size_t)kt * 128);
            __syncthreads();
#pragma unroll
            for (int kk = 0; kk < 2; ++kk) {
                int kc = (kk * 64 + l4 * 16) ^ xorb;
                bf16x8 af[4], bg[4];
#pragma unroll
                for (int m = 0; m < 4; ++m)
                    af[m] = *(const bf16x8*)(pa + (wr * 64 + m * 16 + l15) * 128 + kc);
#pragma unroll
                for (int n = 0; n < 4; ++n)
                    bg[n] = *(const bf16x8*)(pb + (wc * 128 + n * 16 + l15) * 128 + kc);
#pragma unroll
                for (int m = 0; m < 4; ++m)
#pragma unroll
                    for (int n = 0; n < 4; ++n)
                        acc[m][n] = __builtin_amdgcn_mfma_f32_16x16x32_bf16(af[m], bg[n], acc[m][n], 0, 0, 0);
#pragma unroll
                for (int n = 0; n < 4; ++n)
                    bg[n] = *(const bf16x8*)(pb + (wc * 128 + (n + 4) * 16 + l15) * 128 + kc);
#pragma unroll
                for (int m = 0; m < 4; ++m)
#pragma unroll
                    for (int n = 0; n < 4; ++n)
                        acc[m][n + 4] = __builtin_amdgcn_mfma_f32_16x16x32_bf16(af[m], bg[n], acc[m][n + 4], 0, 0, 0);
            }
            __syncthreads();
        }

#pragma unroll
        for (int n = 0; n < 8; ++n) {
            int col = tn * 256 + wc * 128 + n * 16 + l15;
            float bv2 = bias[col];
            float sc = scale[col];
#pragma unroll
            for (int m = 0; m < 4; ++m) {
                int row = tm * 128 + wr * 64 + m * 16 + l4 * 4;
#pragma unroll
                for (int r = 0; r < 4; ++r)
                    Cout[(size_t)(row + r) * HID2 + col] = (bf16)(fabsf(acc[m][n][r] + bv2) * sc);
            }
        }
    }
}

// ---------------------------------------------------------------- phased GEMM (r8, for out)
__device__ __forceinline__ void stage2A(const char* gA, char* sa, int w, int lane, size_t kb) {
#pragma unroll
    for (int j = 0; j < 2; ++j) {
        int r = w * 16 + j * 8 + (lane >> 3);
        async16(sa + (w * 16 + j * 8) * 128,
                gA + (size_t)r * (HID2 * 2) + kb + (((lane & 7) * 16) ^ ((r & 7) << 4)));
    }
}
__device__ __forceinline__ void stage2B(const char* gB, char* sb, int w, int lane, int half, size_t kb) {
#pragma unroll
    for (int j = 0; j < 2; ++j) {
        int r = half * 128 + w * 16 + j * 8 + (lane >> 3);
        async16(sb + (half * 128 + w * 16 + j * 8) * 128,
                gB + (size_t)r * (HID2 * 2) + kb + (((lane & 7) * 16) ^ ((r & 7) << 4)));
    }
}

#define G_BARRIER() do { asm volatile("" ::: "memory"); __builtin_amdgcn_s_barrier(); \
                         asm volatile("" ::: "memory"); } while (0)

__global__ __launch_bounds__(512, 2) void gemm_out(
    const bf16* __restrict__ Ctx, const bf16* __restrict__ Wo,
    const float* __restrict__ bo, float* __restrict__ out) {
    __shared__ bf16 sA[3][128 * 64];
    __shared__ bf16 sB[3][256 * 64];
    const int NT = HID2 / 64;  // 32
    int bid = blockIdx.x;
    int tn = bid & 7, tm = bid >> 3;
    int tid = threadIdx.x, w = tid >> 6, lane = tid & 63;
    int wr = w >> 2, wc = w & 3;
    int l15 = lane & 15, l4 = lane >> 4;
    int xorb = (l15 & 7) << 4;

    const char* gA = (const char*)Ctx + (size_t)tm * 128 * (HID2 * 2);
    const char* gB = (const char*)Wo + (size_t)tn * 256 * (HID2 * 2);

    f32x4 acc[4][4] = {};

    stage2A(gA, (char*)sA[0], w, lane, 0);
    stage2B(gB, (char*)sB[0], w, lane, 0, 0);
    stage2B(gB, (char*)sB[0], w, lane, 1, 0);
    stage2A(gA, (char*)sA[1], w, lane, 128);
    stage2B(gB, (char*)sB[1], w, lane, 0, 128);
    stage2B(gB, (char*)sB[1], w, lane, 1, 128);
    asm volatile("s_waitcnt vmcnt(6)" ::: "memory");
    G_BARRIER();

    int cur = 0;
    for (int t = 0; t < NT; ++t) {
        const char* pa = (const char*)sA[cur];
        const char* pb = (const char*)sB[cur];
        int nb = cur + 2; if (nb >= 3) nb -= 3;
        const bool pre = (t + 2 < NT);
        size_t kb = (size_t)(t + 2) * 128;
        bf16x8 af[4], bg[4];

        {
            int kc = (l4 * 16) ^ xorb;
#pragma unroll
            for (int m = 0; m < 4; ++m)
                af[m] = *(const bf16x8*)(pa + (wr * 64 + m * 16 + l15) * 128 + kc);
#pragma unroll
            for (int n = 0; n < 4; ++n)
                bg[n] = *(const bf16x8*)(pb + (wc * 64 + n * 16 + l15) * 128 + kc);
        }
        if (pre) { stage2A(gA, (char*)sA[nb], w, lane, kb); stage2B(gB, (char*)sB[nb], w, lane, 0, kb); }
        G_BARRIER();
        asm volatile("s_waitcnt lgkmcnt(0)" ::: "memory");
        __builtin_amdgcn_sched_barrier(0);
        __builtin_amdgcn_s_setprio(1);
#pragma unroll
        for (int m = 0; m < 4; ++m)
#pragma unroll
            for (int n = 0; n < 4; ++n)
                acc[m][n] = __builtin_amdgcn_mfma_f32_16x16x32_bf16(af[m], bg[n], acc[m][n], 0, 0, 0);
        __builtin_amdgcn_s_setprio(0);
        G_BARRIER();

        {
            int kc = (64 + l4 * 16) ^ xorb;
#pragma unroll
            for (int m = 0; m < 4; ++m)
                af[m] = *(const bf16x8*)(pa + (wr * 64 + m * 16 + l15) * 128 + kc);
#pragma unroll
            for (int n = 0; n < 4; ++n)
                bg[n] = *(const bf16x8*)(pb + (wc * 64 + n * 16 + l15) * 128 + kc);
        }
        if (pre) stage2B(gB, (char*)sB[nb], w, lane, 1, kb);
        G_BARRIER();
        asm volatile("s_waitcnt lgkmcnt(0)" ::: "memory");
        __builtin_amdgcn_sched_barrier(0);
        __builtin_amdgcn_s_setprio(1);
#pragma unroll
        for (int m = 0; m < 4; ++m)
#pragma unroll
            for (int n = 0; n < 4; ++n)
                acc[m][n] = __builtin_amdgcn_mfma_f32_16x16x32_bf16(af[m], bg[n], acc[m][n], 0, 0, 0);
        __builtin_amdgcn_s_setprio(0);
        if (pre)               { asm volatile("s_waitcnt vmcnt(6)" ::: "memory"); }
        else if (t + 2 == NT)  { asm volatile("s_waitcnt vmcnt(0)" ::: "memory"); }
        G_BARRIER();

        cur = cur + 1; if (cur == 3) cur = 0;
    }

#pragma unroll
    for (int n = 0; n < 4; ++n) {
        int col = tn * 256 + wc * 64 + n * 16 + l15;
        float bv = bo[col];
#pragma unroll
        for (int m = 0; m < 4; ++m) {
            int row = tm * 128 + wr * 64 + m * 16 + l4 * 4;
#pragma unroll
            for (int r = 0; r < 4; ++r)
                out[(size_t)(row + r) * HID2 + col] = acc[m][n][r] + bv;
        }
    }
}

// ---------------------------------------------------------------- V transpose
__global__ void transpose_v(const bf16* __restrict__ Vb, bf16* __restrict__ Vt) {
    int bh = blockIdx.z;
    int b = bh >> 4, h = bh & 15;
    int s0 = blockIdx.x * 64, d0 = blockIdx.y * 64;
    int tid = threadIdx.x;
    __shared__ bf16 T[64][72];
    const bf16* src = Vb + ((size_t)b * NS + s0) * HID2 + h * ND + d0;
#pragma unroll
    for (int i = 0; i < 2; ++i) {
        int r = i * 32 + (tid >> 3);
        int c = (tid & 7) * 8;
        *(bf16x8*)(&T[r][c]) = *(const bf16x8*)(src + (size_t)r * HID2 + c);
    }
    __syncthreads();
    bf16* dst = Vt + ((size_t)(b * NH + h) * ND + d0) * NS + s0;
#pragma unroll
    for (int i = 0; i < 2; ++i) {
        int dr = i * 32 + (tid >> 3);
        int sc = (tid & 7) * 8;
        bf16x8 o;
#pragma unroll
        for (int j = 0; j < 8; ++j) o[j] = T[sc + j][dr];
        *(bf16x8*)(dst + (size_t)dr * NS + sc) = o;
    }
}

// ---------------------------------------------------------------- flash attention (v5)
// Direct global_load_lds staging for K and V (double-buffered, linear LDS with
// the proven (row&7)<<4 slot swizzle via pre-swizzled global source). ONE
// barrier per K-tile: after it each wave issues tile kt+1's async16 into
// buf^1 (freed at the kt-1 barrier); the compiler's vmcnt(0)+lgkmcnt(0) drain
// before s_barrier makes staged data globally visible. Ps swizzled-linear.
// LDS = 32K + 32K + 16K = 81920 B = exactly 2 blocks/CU.
__device__ __forceinline__ void stageKV(const char* Kp, const char* Vp,
                                        char* ksDst, char* vsDst, int w, int lane) {
#pragma unroll
    for (int i = 0; i < 4; ++i) {
        int c = (w * 4 + i) * 64 + lane;
        int key = c >> 4, s16 = c & 15;
        async16(ksDst + (size_t)(w * 4 + i) * 1024,
                Kp + (size_t)key * (HID2 * 2) + (((s16 ^ (key & 7)) << 4)));
        int d = c >> 3, s8 = c & 7;
        async16(vsDst + (size_t)(w * 4 + i) * 1024,
                Vp + (size_t)d * (NS * 2) + (((s8 ^ (d & 7)) << 4)));
    }
}

__global__ __launch_bounds__(256, 2) void flash_kernel(
    const bf16* __restrict__ Qb, const bf16* __restrict__ Kb, const bf16* __restrict__ Vt,
    const float* __restrict__ ent, const float* __restrict__ mask, bf16* __restrict__ Ctx) {
    int bid = blockIdx.x;                       // 0..511
    int qt = bid >> 5;                          // 0..15
    int bh = (bid & 7) * 4 + ((bid >> 3) & 3);  // XCD (bid%8) owns bh 4x..4x+3
    int b = bh >> 4, h = bh & 15;
    int tid = threadIdx.x, wid = tid >> 6, lane = tid & 63;
    int l15 = lane & 15, l4 = lane >> 4;
    int xorb = (l15 & 7) << 4;

    __shared__ bf16 Ks[2][64 * 128];   // 32 KB  [key][d] swizzled slots
    __shared__ bf16 Vs[2][128 * 64];   // 32 KB  [d][key] swizzled slots
    __shared__ bf16 Ps[4][32 * 64];    // 16 KB  per-wave [q][key] swizzled

    const bf16* Qp = Qb + ((size_t)b * NS + qt * 128) * HID2 + h * ND;
    const char* Kp = (const char*)(Kb + (size_t)b * NS * HID2 + h * ND);
    const char* Vp = (const char*)(Vt + (size_t)(b * NH + h) * ND * NS);
    const float* maskp = mask + (size_t)b * NS;

    bf16x8 qf[2][4];
#pragma unroll
    for (int m = 0; m < 2; ++m)
#pragma unroll
        for (int kk = 0; kk < 4; ++kk)
            qf[m][kk] = *(const bf16x8*)(Qp + (size_t)(wid * 32 + m * 16 + l15) * HID2 + kk * 32 + l4 * 8);

    float eb[4];
#pragma unroll
    for (int r = 0; r < 4; ++r) eb[r] = ent[h * NH + l4 * 4 + r];

    float mrun[2], lrun[2];
    mrun[0] = mrun[1] = -INFINITY;
    lrun[0] = lrun[1] = 0.f;
    f32x4 oacc[2][8] = {};

    stageKV(Kp, Vp, (char*)Ks[0], (char*)Vs[0], wid, lane);
    __syncthreads();   // drains vmcnt -> tile 0 staged for all waves

    for (int kt = 0; kt < NS / 64; ++kt) {
        int kb = kt & 1;
        if (kt + 1 < NS / 64)
            stageKV(Kp + (size_t)(kt + 1) * 64 * (HID2 * 2), Vp + (size_t)(kt + 1) * 128,
                    (char*)Ks[kb ^ 1], (char*)Vs[kb ^ 1], wid, lane);

        const char* ks = (const char*)Ks[kb];
        const char* vs = (const char*)Vs[kb];
        const char* ps = (const char*)Ps[wid];

        // S' = K Q^T  (rows = keys, cols = q)
        f32x4 s[2][4] = {};
#pragma unroll
        for (int kk = 0; kk < 4; ++kk) {
            bf16x8 kf[4];
#pragma unroll
            for (int n = 0; n < 4; ++n)
                kf[n] = *(const bf16x8*)(ks + (n * 16 + l15) * 256 + ((kk * 64 + l4 * 16) ^ xorb));
#pragma unroll
            for (int m = 0; m < 2; ++m)
#pragma unroll
                for (int n = 0; n < 4; ++n)
                    s[m][n] = __builtin_amdgcn_mfma_f32_16x16x32_bf16(kf[n], qf[m][kk], s[m][n], 0, 0, 0);
        }

        float4 mk[4];
#pragma unroll
        for (int n = 0; n < 4; ++n)
            mk[n] = *(const float4*)(maskp + kt * 64 + n * 16 + l4 * 4);

#pragma unroll
        for (int mq = 0; mq < 2; ++mq) {
            float sv[4][4];
#pragma unroll
            for (int n = 0; n < 4; ++n) {
                sv[n][0] = s[mq][n][0] + eb[0] + mk[n].x;
                sv[n][1] = s[mq][n][1] + eb[1] + mk[n].y;
                sv[n][2] = s[mq][n][2] + eb[2] + mk[n].z;
                sv[n][3] = s[mq][n][3] + eb[3] + mk[n].w;
            }
            float tmax = sv[0][0];
#pragma unroll
            for (int n = 0; n < 4; ++n)
#pragma unroll
                for (int r = 0; r < 4; ++r) tmax = fmaxf(tmax, sv[n][r]);
            tmax = fmaxf(tmax, __shfl_xor(tmax, 16));
            tmax = fmaxf(tmax, __shfl_xor(tmax, 32));

            if (__any(tmax > mrun[mq] + 8.0f)) {
                float mnew = fmaxf(mrun[mq], tmax);
                float corr = __expf(mrun[mq] - mnew);
                mrun[mq] = mnew;
                lrun[mq] *= corr;
#pragma unroll
                for (int r = 0; r < 4; ++r) {
                    float cr = __shfl(corr, l4 * 4 + r);
#pragma unroll
                    for (int n = 0; n < 8; ++n) oacc[mq][n][r] *= cr;
                }
            }

            float psum = 0.f;
#pragma unroll
            for (int n = 0; n < 4; ++n) {
                bf16x4 pv;
#pragma unroll
                for (int r = 0; r < 4; ++r) {
                    float p = __expf(sv[n][r] - mrun[mq]);
                    psum += p;
                    pv[r] = (bf16)p;
                }
                // P[q = mq*16+l15][keys n*16+l4*4..+3], swizzled slot
                *(bf16x4*)((char*)ps + (mq * 16 + l15) * 128 + ((n * 32 + l4 * 8) ^ xorb)) = pv;
            }
            psum += __shfl_xor(psum, 16);
            psum += __shfl_xor(psum, 32);
            lrun[mq] += psum;
        }

        // ctx += P V
#pragma unroll
        for (int kk = 0; kk < 2; ++kk) {
            bf16x8 pa[2], vb[8];
#pragma unroll
            for (int m = 0; m < 2; ++m)
                pa[m] = *(const bf16x8*)(ps + (m * 16 + l15) * 128 + ((kk * 64 + l4 * 16) ^ xorb));
#pragma unroll
            for (int n = 0; n < 8; ++n)
                vb[n] = *(const bf16x8*)(vs + (n * 16 + l15) * 128 + ((kk * 64 + l4 * 16) ^ xorb));
#pragma unroll
            for (int m = 0; m < 2; ++m)
#pragma unroll
                for (int n = 0; n < 8; ++n)
                    oacc[m][n] = __builtin_amdgcn_mfma_f32_16x16x32_bf16(pa[m], vb[n], oacc[m][n], 0, 0, 0);
        }
        __syncthreads();   // drains vmcnt (tile kt+1 staged) + all LDS reads of buf kb
    }

    // epilogue: ctx / l
#pragma unroll
    for (int m = 0; m < 2; ++m) {
        float inv = 1.0f / lrun[m];
        float invr[4];
#pragma unroll
        for (int r = 0; r < 4; ++r) invr[r] = __shfl(inv, l4 * 4 + r);
#pragma unroll
        for (int r = 0; r < 4; ++r) {
            int row = qt * 128 + wid * 32 + m * 16 + l4 * 4 + r;
            bf16* Cp = Ctx + ((size_t)b * NS + row) * HID2 + h * ND;
#pragma unroll
            for (int n = 0; n < 8; ++n)
                Cp[n * 16 + l15] = (bf16)(oacc[m][n][r] * invr[r]);
        }
    }
}

// ---------------------------------------------------------------- launch
extern "C" void kernel_launch(void* const* d_in, const int* in_sizes, int n_in,
                              void* d_out, int out_size, void* d_ws, size_t ws_size,
                              hipStream_t stream) {
    const float* hidden = (const float*)d_in[0];
    const float* mask   = (const float*)d_in[1];
    const float* q_real = (const float*)d_in[2];
    const float* q_imag = (const float*)d_in[3];
    const float* q_mag  = (const float*)d_in[5];
    const float* k_real = (const float*)d_in[6];
    const float* k_imag = (const float*)d_in[7];
    const float* k_mag  = (const float*)d_in[9];
    const float* v_real = (const float*)d_in[10];
    const float* v_imag = (const float*)d_in[11];
    const float* v_mag  = (const float*)d_in[13];
    const float* Wq = (const float*)d_in[14];
    const float* bq = (const float*)d_in[15];
    const float* Wk = (const float*)d_in[16];
    const float* bk = (const float*)d_in[17];
    const float* Wv = (const float*)d_in[18];
    const float* bv = (const float*)d_in[19];
    const float* Wo = (const float*)d_in[20];
    const float* bo = (const float*)d_in[21];
    const float* ent = (const float*)d_in[22];

    char* ws = (char*)d_ws;
    bf16* Xb    = (bf16*)(ws);
    bf16* Wb    = (bf16*)(ws + 16777216);        // Wq,Wk,Wv,Wo bf16 contiguous
    bf16* Wob   = (bf16*)(ws + 41943040);
    bf16* QKV   = (bf16*)(ws + 50331648);        // Q,K,V bf16 stacked
    bf16* Vt    = (bf16*)(ws + 100663296);
    bf16* Ctx   = (bf16*)(ws + 117440512);
    float* scales = (float*)(ws + 134217728);

    prep_kernel<<<12296, 256, 0, stream>>>(hidden, Wq, Wk, Wv, Wo,
                                           q_real, q_imag, q_mag, k_real, k_imag, k_mag,
                                           v_real, v_imag, v_mag, Xb, Wb, scales);
    gemm_qkv<<<512, 256, 0, stream>>>(Xb, Wb, bq, bk, bv, scales, QKV);
    const bf16* Vb = QKV + (size_t)2 * MROWS * HID2;
    transpose_v<<<dim3(32, 2, 32), 256, 0, stream>>>(Vb, Vt);
    flash_kernel<<<512, 256, 0, stream>>>(QKV, QKV + (size_t)MROWS * HID2, Vt, ent, mask, Ctx);
    gemm_out<<<256, 512, 0, stream>>>(Ctx, Wob, bo, (float*)d_out);
}

// Round 16
// 270.161 us; speedup vs baseline: 1.5115x; 1.0376x over previous
//
#include <hip/hip_runtime.h>
#include <hip/hip_bf16.h>

#define NB 2
#define NS 2048
#define NH 16
#define ND 128
#define HID2 2048
#define MROWS 4096   // NB*NS

typedef __bf16 bf16;
typedef bf16 bf16x8 __attribute__((ext_vector_type(8)));
typedef bf16 bf16x4 __attribute__((ext_vector_type(4)));
typedef float f32x4 __attribute__((ext_vector_type(4)));
typedef unsigned int u32;

#define GLOBAL_AS __attribute__((address_space(1)))
#define LDS_AS __attribute__((address_space(3)))

__device__ __forceinline__ void async16(void* lds, const void* g) {
    __builtin_amdgcn_global_load_lds((const GLOBAL_AS u32*)g, (LDS_AS u32*)lds, 16, 0, 0);
}

// ---------------------------------------------------------------- fused prep
__device__ __forceinline__ void cvt8(const float* __restrict__ src, bf16* __restrict__ dst, int i) {
    const float4* s4 = (const float4*)src;
    float4 a = s4[2 * i], b = s4[2 * i + 1];
    bf16x8 o;
    o[0] = (bf16)a.x; o[1] = (bf16)a.y; o[2] = (bf16)a.z; o[3] = (bf16)a.w;
    o[4] = (bf16)b.x; o[5] = (bf16)b.y; o[6] = (bf16)b.z; o[7] = (bf16)b.w;
    ((bf16x8*)dst)[i] = o;
}

__global__ __launch_bounds__(256) void prep_kernel(
    const float* __restrict__ hidden,
    const float* __restrict__ Wq, const float* __restrict__ Wk,
    const float* __restrict__ Wv, const float* __restrict__ Wo,
    const float* __restrict__ qr, const float* __restrict__ qi, const float* __restrict__ qm,
    const float* __restrict__ kr, const float* __restrict__ ki, const float* __restrict__ km,
    const float* __restrict__ vr, const float* __restrict__ vi, const float* __restrict__ vm,
    bf16* __restrict__ Xb, bf16* __restrict__ Wb, float* __restrict__ scales) {
    int gb = blockIdx.x, tid = threadIdx.x;
    if (gb < 4096) {
        cvt8(hidden, Xb, gb * 256 + tid);
    } else if (gb < 12288) {
        int zz = (gb - 4096) >> 11;
        int i = ((gb - 4096) & 2047) * 256 + tid;
        const float* src = (zz == 0) ? Wq : (zz == 1) ? Wk : (zz == 2) ? Wv : Wo;
        cvt8(src, Wb + (size_t)zz * HID2 * HID2, i);
    } else {
        int i = (gb - 12288) * 256 + tid;
        if (i < HID2) {
            const float RSQD = 0.08838834764831845f;  // 1/sqrt(128) folded into Q scale
            scales[i]            = sqrtf(qr[i] * qr[i] + qi[i] * qi[i]) * fabsf(qm[i]) * RSQD;
            scales[HID2 + i]     = sqrtf(kr[i] * kr[i] + ki[i] * ki[i]) * fabsf(km[i]);
            scales[2 * HID2 + i] = sqrtf(vr[i] * vr[i] + vi[i] * vi[i]) * fabsf(vm[i]);
        }
    }
}

// ---------------------------------------------------------------- loose GEMM (r7 core, balanced multi-tile)
// z=0,1 (Q,K): row-major bf16 out = |acc+bias|*scale.
// z=2 (V): same value written TRANSPOSED to Vt[(b*16+h)*128+d][s] (bf16x4,
// s-contiguous) -> transpose_v pass deleted. Runtime z branch (single
// instantiation: no LDS doubling (r9), no (256,3) spill (r10)).
__device__ __forceinline__ void stage12(const char* gA, const char* gB,
                                        char* sa, char* sb, int w, int lane, size_t kb) {
    int r8 = lane >> 3;
    int cx = (lane & 7) * 16;
#pragma unroll
    for (int j = 0; j < 4; ++j) {
        int r = w * 32 + j * 8 + r8;
        async16(sa + (w * 32 + j * 8) * 128,
                gA + (size_t)r * (HID2 * 2) + kb + (cx ^ ((r & 7) << 4)));
    }
#pragma unroll
    for (int j = 0; j < 8; ++j) {
        int r = w * 64 + j * 8 + r8;
        async16(sb + (w * 64 + j * 8) * 128,
                gB + (size_t)r * (HID2 * 2) + kb + (cx ^ ((r & 7) << 4)));
    }
}

__global__ __launch_bounds__(256, 2) void gemm_qkv(
    const bf16* __restrict__ X, const bf16* __restrict__ Wb,
    const float* __restrict__ bq, const float* __restrict__ bk, const float* __restrict__ bv,
    const float* __restrict__ scales, bf16* __restrict__ QKV, bf16* __restrict__ Vt) {
    __shared__ bf16 sA[128 * 64];   // 16 KB
    __shared__ bf16 sB[256 * 64];   // 32 KB
    int b0 = blockIdx.x;            // 0..511
    int tid = threadIdx.x, w = tid >> 6, lane = tid & 63;
    int wr = w >> 1, wc = w & 1;
    int l15 = lane & 15, l4 = lane >> 4;
    int xorb = (l15 & 7) << 4;
    int ntile = (b0 < 256) ? 2 : 1;

    for (int it = 0; it < ntile; ++it) {
        int t = (it == 0) ? b0 : 512 + b0;
        int p = t & 7, q = t >> 3;
        int z = q >> 5, tm = q & 31, tn = p;
        const bf16* Bt = Wb + (size_t)z * HID2 * HID2;
        const float* bias = (z == 0) ? bq : (z == 1) ? bk : bv;
        const float* scale = scales + z * HID2;
        bf16* Cout = QKV + (size_t)z * MROWS * HID2;

        const char* gA = (const char*)X + (size_t)tm * 128 * (HID2 * 2);
        const char* gB = (const char*)Bt + (size_t)tn * 256 * (HID2 * 2);
        const char* pa = (const char*)sA;
        const char* pb = (const char*)sB;

        f32x4 acc[4][8] = {};

        for (int kt = 0; kt < HID2 / 64; ++kt) {
            stage12(gA, gB, (char*)sA, (char*)sB, w, lane, (size_t)kt * 128);
            __syncthreads();
#pragma unroll
            for (int kk = 0; kk < 2; ++kk) {
                int kc = (kk * 64 + l4 * 16) ^ xorb;
                bf16x8 af[4], bg[4];
#pragma unroll
                for (int m = 0; m < 4; ++m)
                    af[m] = *(const bf16x8*)(pa + (wr * 64 + m * 16 + l15) * 128 + kc);
#pragma unroll
                for (int n = 0; n < 4; ++n)
                    bg[n] = *(const bf16x8*)(pb + (wc * 128 + n * 16 + l15) * 128 + kc);
#pragma unroll
                for (int m = 0; m < 4; ++m)
#pragma unroll
                    for (int n = 0; n < 4; ++n)
                        acc[m][n] = __builtin_amdgcn_mfma_f32_16x16x32_bf16(af[m], bg[n], acc[m][n], 0, 0, 0);
#pragma unroll
                for (int n = 0; n < 4; ++n)
                    bg[n] = *(const bf16x8*)(pb + (wc * 128 + (n + 4) * 16 + l15) * 128 + kc);
#pragma unroll
                for (int m = 0; m < 4; ++m)
#pragma unroll
                    for (int n = 0; n < 4; ++n)
                        acc[m][n + 4] = __builtin_amdgcn_mfma_f32_16x16x32_bf16(af[m], bg[n], acc[m][n + 4], 0, 0, 0);
            }
            __syncthreads();
        }

        // epilogue
#pragma unroll
        for (int n = 0; n < 8; ++n) {
            int col = tn * 256 + wc * 128 + n * 16 + l15;
            float bv2 = bias[col];
            float sc = scale[col];
#pragma unroll
            for (int m = 0; m < 4; ++m) {
                int row = tm * 128 + wr * 64 + m * 16 + l4 * 4;
                if (z != 2) {
#pragma unroll
                    for (int r = 0; r < 4; ++r)
                        Cout[(size_t)(row + r) * HID2 + col] = (bf16)(fabsf(acc[m][n][r] + bv2) * sc);
                } else {
                    // transposed V: Vt[(b*16+h)*128 + d][s], s = row..row+3 contiguous
                    int h = col >> 7, d = col & 127;
                    int bb = row >> 11, s = row & 2047;
                    bf16x4 pv;
#pragma unroll
                    for (int r = 0; r < 4; ++r)
                        pv[r] = (bf16)(fabsf(acc[m][n][r] + bv2) * sc);
                    *(bf16x4*)(Vt + ((size_t)(bb * NH + h) * ND + d) * NS + s) = pv;
                }
            }
        }
    }
}

// ---------------------------------------------------------------- phased GEMM (r8, for out)
__device__ __forceinline__ void stage2A(const char* gA, char* sa, int w, int lane, size_t kb) {
#pragma unroll
    for (int j = 0; j < 2; ++j) {
        int r = w * 16 + j * 8 + (lane >> 3);
        async16(sa + (w * 16 + j * 8) * 128,
                gA + (size_t)r * (HID2 * 2) + kb + (((lane & 7) * 16) ^ ((r & 7) << 4)));
    }
}
__device__ __forceinline__ void stage2B(const char* gB, char* sb, int w, int lane, int half, size_t kb) {
#pragma unroll
    for (int j = 0; j < 2; ++j) {
        int r = half * 128 + w * 16 + j * 8 + (lane >> 3);
        async16(sb + (half * 128 + w * 16 + j * 8) * 128,
                gB + (size_t)r * (HID2 * 2) + kb + (((lane & 7) * 16) ^ ((r & 7) << 4)));
    }
}

#define G_BARRIER() do { asm volatile("" ::: "memory"); __builtin_amdgcn_s_barrier(); \
                         asm volatile("" ::: "memory"); } while (0)

__global__ __launch_bounds__(512, 2) void gemm_out(
    const bf16* __restrict__ Ctx, const bf16* __restrict__ Wo,
    const float* __restrict__ bo, float* __restrict__ out) {
    __shared__ bf16 sA[3][128 * 64];
    __shared__ bf16 sB[3][256 * 64];
    const int NT = HID2 / 64;  // 32
    int bid = blockIdx.x;
    int tn = bid & 7, tm = bid >> 3;
    int tid = threadIdx.x, w = tid >> 6, lane = tid & 63;
    int wr = w >> 2, wc = w & 3;
    int l15 = lane & 15, l4 = lane >> 4;
    int xorb = (l15 & 7) << 4;

    const char* gA = (const char*)Ctx + (size_t)tm * 128 * (HID2 * 2);
    const char* gB = (const char*)Wo + (size_t)tn * 256 * (HID2 * 2);

    f32x4 acc[4][4] = {};

    stage2A(gA, (char*)sA[0], w, lane, 0);
    stage2B(gB, (char*)sB[0], w, lane, 0, 0);
    stage2B(gB, (char*)sB[0], w, lane, 1, 0);
    stage2A(gA, (char*)sA[1], w, lane, 128);
    stage2B(gB, (char*)sB[1], w, lane, 0, 128);
    stage2B(gB, (char*)sB[1], w, lane, 1, 128);
    asm volatile("s_waitcnt vmcnt(6)" ::: "memory");
    G_BARRIER();

    int cur = 0;
    for (int t = 0; t < NT; ++t) {
        const char* pa = (const char*)sA[cur];
        const char* pb = (const char*)sB[cur];
        int nb = cur + 2; if (nb >= 3) nb -= 3;
        const bool pre = (t + 2 < NT);
        size_t kb = (size_t)(t + 2) * 128;
        bf16x8 af[4], bg[4];

        {
            int kc = (l4 * 16) ^ xorb;
#pragma unroll
            for (int m = 0; m < 4; ++m)
                af[m] = *(const bf16x8*)(pa + (wr * 64 + m * 16 + l15) * 128 + kc);
#pragma unroll
            for (int n = 0; n < 4; ++n)
                bg[n] = *(const bf16x8*)(pb + (wc * 64 + n * 16 + l15) * 128 + kc);
        }
        if (pre) { stage2A(gA, (char*)sA[nb], w, lane, kb); stage2B(gB, (char*)sB[nb], w, lane, 0, kb); }
        G_BARRIER();
        asm volatile("s_waitcnt lgkmcnt(0)" ::: "memory");
        __builtin_amdgcn_sched_barrier(0);
        __builtin_amdgcn_s_setprio(1);
#pragma unroll
        for (int m = 0; m < 4; ++m)
#pragma unroll
            for (int n = 0; n < 4; ++n)
                acc[m][n] = __builtin_amdgcn_mfma_f32_16x16x32_bf16(af[m], bg[n], acc[m][n], 0, 0, 0);
        __builtin_amdgcn_s_setprio(0);
        G_BARRIER();

        {
            int kc = (64 + l4 * 16) ^ xorb;
#pragma unroll
            for (int m = 0; m < 4; ++m)
                af[m] = *(const bf16x8*)(pa + (wr * 64 + m * 16 + l15) * 128 + kc);
#pragma unroll
            for (int n = 0; n < 4; ++n)
                bg[n] = *(const bf16x8*)(pb + (wc * 64 + n * 16 + l15) * 128 + kc);
        }
        if (pre) stage2B(gB, (char*)sB[nb], w, lane, 1, kb);
        G_BARRIER();
        asm volatile("s_waitcnt lgkmcnt(0)" ::: "memory");
        __builtin_amdgcn_sched_barrier(0);
        __builtin_amdgcn_s_setprio(1);
#pragma unroll
        for (int m = 0; m < 4; ++m)
#pragma unroll
            for (int n = 0; n < 4; ++n)
                acc[m][n] = __builtin_amdgcn_mfma_f32_16x16x32_bf16(af[m], bg[n], acc[m][n], 0, 0, 0);
        __builtin_amdgcn_s_setprio(0);
        if (pre)               { asm volatile("s_waitcnt vmcnt(6)" ::: "memory"); }
        else if (t + 2 == NT)  { asm volatile("s_waitcnt vmcnt(0)" ::: "memory"); }
        G_BARRIER();

        cur = cur + 1; if (cur == 3) cur = 0;
    }

#pragma unroll
    for (int n = 0; n < 4; ++n) {
        int col = tn * 256 + wc * 64 + n * 16 + l15;
        float bv = bo[col];
#pragma unroll
        for (int m = 0; m < 4; ++m) {
            int row = tm * 128 + wr * 64 + m * 16 + l4 * 4;
#pragma unroll
            for (int r = 0; r < 4; ++r)
                out[(size_t)(row + r) * HID2 + col] = acc[m][n][r] + bv;
        }
    }
}

// ---------------------------------------------------------------- flash attention (v5)
__device__ __forceinline__ void stageKV(const char* Kp, const char* Vp,
                                        char* ksDst, char* vsDst, int w, int lane) {
#pragma unroll
    for (int i = 0; i < 4; ++i) {
        int c = (w * 4 + i) * 64 + lane;
        int key = c >> 4, s16 = c & 15;
        async16(ksDst + (size_t)(w * 4 + i) * 1024,
                Kp + (size_t)key * (HID2 * 2) + (((s16 ^ (key & 7)) << 4)));
        int d = c >> 3, s8 = c & 7;
        async16(vsDst + (size_t)(w * 4 + i) * 1024,
                Vp + (size_t)d * (NS * 2) + (((s8 ^ (d & 7)) << 4)));
    }
}

__global__ __launch_bounds__(256, 2) void flash_kernel(
    const bf16* __restrict__ Qb, const bf16* __restrict__ Kb, const bf16* __restrict__ Vt,
    const float* __restrict__ ent, const float* __restrict__ mask, bf16* __restrict__ Ctx) {
    int bid = blockIdx.x;                       // 0..511
    int qt = bid >> 5;                          // 0..15
    int bh = (bid & 7) * 4 + ((bid >> 3) & 3);  // XCD (bid%8) owns bh 4x..4x+3
    int b = bh >> 4, h = bh & 15;
    int tid = threadIdx.x, wid = tid >> 6, lane = tid & 63;
    int l15 = lane & 15, l4 = lane >> 4;
    int xorb = (l15 & 7) << 4;

    __shared__ bf16 Ks[2][64 * 128];   // 32 KB
    __shared__ bf16 Vs[2][128 * 64];   // 32 KB
    __shared__ bf16 Ps[4][32 * 64];    // 16 KB

    const bf16* Qp = Qb + ((size_t)b * NS + qt * 128) * HID2 + h * ND;
    const char* Kp = (const char*)(Kb + (size_t)b * NS * HID2 + h * ND);
    const char* Vp = (const char*)(Vt + (size_t)(b * NH + h) * ND * NS);
    const float* maskp = mask + (size_t)b * NS;

    bf16x8 qf[2][4];
#pragma unroll
    for (int m = 0; m < 2; ++m)
#pragma unroll
        for (int kk = 0; kk < 4; ++kk)
            qf[m][kk] = *(const bf16x8*)(Qp + (size_t)(wid * 32 + m * 16 + l15) * HID2 + kk * 32 + l4 * 8);

    float eb[4];
#pragma unroll
    for (int r = 0; r < 4; ++r) eb[r] = ent[h * NH + l4 * 4 + r];

    float mrun[2], lrun[2];
    mrun[0] = mrun[1] = -INFINITY;
    lrun[0] = lrun[1] = 0.f;
    f32x4 oacc[2][8] = {};

    stageKV(Kp, Vp, (char*)Ks[0], (char*)Vs[0], wid, lane);
    __syncthreads();

    for (int kt = 0; kt < NS / 64; ++kt) {
        int kb = kt & 1;
        if (kt + 1 < NS / 64)
            stageKV(Kp + (size_t)(kt + 1) * 64 * (HID2 * 2), Vp + (size_t)(kt + 1) * 128,
                    (char*)Ks[kb ^ 1], (char*)Vs[kb ^ 1], wid, lane);

        const char* ks = (const char*)Ks[kb];
        const char* vs = (const char*)Vs[kb];
        const char* ps = (const char*)Ps[wid];

        f32x4 s[2][4] = {};
#pragma unroll
        for (int kk = 0; kk < 4; ++kk) {
            bf16x8 kf[4];
#pragma unroll
            for (int n = 0; n < 4; ++n)
                kf[n] = *(const bf16x8*)(ks + (n * 16 + l15) * 256 + ((kk * 64 + l4 * 16) ^ xorb));
#pragma unroll
            for (int m = 0; m < 2; ++m)
#pragma unroll
                for (int n = 0; n < 4; ++n)
                    s[m][n] = __builtin_amdgcn_mfma_f32_16x16x32_bf16(kf[n], qf[m][kk], s[m][n], 0, 0, 0);
        }

        float4 mk[4];
#pragma unroll
        for (int n = 0; n < 4; ++n)
            mk[n] = *(const float4*)(maskp + kt * 64 + n * 16 + l4 * 4);

#pragma unroll
        for (int mq = 0; mq < 2; ++mq) {
            float sv[4][4];
#pragma unroll
            for (int n = 0; n < 4; ++n) {
                sv[n][0] = s[mq][n][0] + eb[0] + mk[n].x;
                sv[n][1] = s[mq][n][1] + eb[1] + mk[n].y;
                sv[n][2] = s[mq][n][2] + eb[2] + mk[n].z;
                sv[n][3] = s[mq][n][3] + eb[3] + mk[n].w;
            }
            float tmax = sv[0][0];
#pragma unroll
            for (int n = 0; n < 4; ++n)
#pragma unroll
                for (int r = 0; r < 4; ++r) tmax = fmaxf(tmax, sv[n][r]);
            tmax = fmaxf(tmax, __shfl_xor(tmax, 16));
            tmax = fmaxf(tmax, __shfl_xor(tmax, 32));

            if (__any(tmax > mrun[mq] + 8.0f)) {
                float mnew = fmaxf(mrun[mq], tmax);
                float corr = __expf(mrun[mq] - mnew);
                mrun[mq] = mnew;
                lrun[mq] *= corr;
#pragma unroll
                for (int r = 0; r < 4; ++r) {
                    float cr = __shfl(corr, l4 * 4 + r);
#pragma unroll
                    for (int n = 0; n < 8; ++n) oacc[mq][n][r] *= cr;
                }
            }

            float psum = 0.f;
#pragma unroll
            for (int n = 0; n < 4; ++n) {
                bf16x4 pv;
#pragma unroll
                for (int r = 0; r < 4; ++r) {
                    float p = __expf(sv[n][r] - mrun[mq]);
                    psum += p;
                    pv[r] = (bf16)p;
                }
                *(bf16x4*)((char*)ps + (mq * 16 + l15) * 128 + ((n * 32 + l4 * 8) ^ xorb)) = pv;
            }
            psum += __shfl_xor(psum, 16);
            psum += __shfl_xor(psum, 32);
            lrun[mq] += psum;
        }

#pragma unroll
        for (int kk = 0; kk < 2; ++kk) {
            bf16x8 pa[2], vb[8];
#pragma unroll
            for (int m = 0; m < 2; ++m)
                pa[m] = *(const bf16x8*)(ps + (m * 16 + l15) * 128 + ((kk * 64 + l4 * 16) ^ xorb));
#pragma unroll
            for (int n = 0; n < 8; ++n)
                vb[n] = *(const bf16x8*)(vs + (n * 16 + l15) * 128 + ((kk * 64 + l4 * 16) ^ xorb));
#pragma unroll
            for (int m = 0; m < 2; ++m)
#pragma unroll
                for (int n = 0; n < 8; ++n)
                    oacc[m][n] = __builtin_amdgcn_mfma_f32_16x16x32_bf16(pa[m], vb[n], oacc[m][n], 0, 0, 0);
        }
        __syncthreads();
    }

#pragma unroll
    for (int m = 0; m < 2; ++m) {
        float inv = 1.0f / lrun[m];
        float invr[4];
#pragma unroll
        for (int r = 0; r < 4; ++r) invr[r] = __shfl(inv, l4 * 4 + r);
#pragma unroll
        for (int r = 0; r < 4; ++r) {
            int row = qt * 128 + wid * 32 + m * 16 + l4 * 4 + r;
            bf16* Cp = Ctx + ((size_t)b * NS + row) * HID2 + h * ND;
#pragma unroll
            for (int n = 0; n < 8; ++n)
                Cp[n * 16 + l15] = (bf16)(oacc[m][n][r] * invr[r]);
        }
    }
}

// ---------------------------------------------------------------- launch
extern "C" void kernel_launch(void* const* d_in, const int* in_sizes, int n_in,
                              void* d_out, int out_size, void* d_ws, size_t ws_size,
                              hipStream_t stream) {
    const float* hidden = (const float*)d_in[0];
    const float* mask   = (const float*)d_in[1];
    const float* q_real = (const float*)d_in[2];
    const float* q_imag = (const float*)d_in[3];
    const float* q_mag  = (const float*)d_in[5];
    const float* k_real = (const float*)d_in[6];
    const float* k_imag = (const float*)d_in[7];
    const float* k_mag  = (const float*)d_in[9];
    const float* v_real = (const float*)d_in[10];
    const float* v_imag = (const float*)d_in[11];
    const float* v_mag  = (const float*)d_in[13];
    const float* Wq = (const float*)d_in[14];
    const float* bq = (const float*)d_in[15];
    const float* Wk = (const float*)d_in[16];
    const float* bk = (const float*)d_in[17];
    const float* Wv = (const float*)d_in[18];
    const float* bv = (const float*)d_in[19];
    const float* Wo = (const float*)d_in[20];
    const float* bo = (const float*)d_in[21];
    const float* ent = (const float*)d_in[22];

    char* ws = (char*)d_ws;
    bf16* Xb    = (bf16*)(ws);
    bf16* Wb    = (bf16*)(ws + 16777216);        // Wq,Wk,Wv,Wo bf16 contiguous
    bf16* Wob   = (bf16*)(ws + 41943040);
    bf16* QKV   = (bf16*)(ws + 50331648);        // Q,K bf16 (V slot unused)
    bf16* Vt    = (bf16*)(ws + 100663296);
    bf16* Ctx   = (bf16*)(ws + 117440512);
    float* scales = (float*)(ws + 134217728);

    prep_kernel<<<12296, 256, 0, stream>>>(hidden, Wq, Wk, Wv, Wo,
                                           q_real, q_imag, q_mag, k_real, k_imag, k_mag,
                                           v_real, v_imag, v_mag, Xb, Wb, scales);
    gemm_qkv<<<512, 256, 0, stream>>>(Xb, Wb, bq, bk, bv, scales, QKV, Vt);
    flash_kernel<<<512, 256, 0, stream>>>(QKV, QKV + (size_t)MROWS * HID2, Vt, ent, mask, Ctx);
    gemm_out<<<256, 512, 0, stream>>>(Ctx, Wob, bo, (float*)d_out);
}

// Round 17
// 265.973 us; speedup vs baseline: 1.5353x; 1.0157x over previous
//
#include <hip/hip_runtime.h>
#include <hip/hip_bf16.h>

#define NB 2
#define NS 2048
#define NH 16
#define ND 128
#define HID2 2048
#define MROWS 4096   // NB*NS

typedef __bf16 bf16;
typedef bf16 bf16x8 __attribute__((ext_vector_type(8)));
typedef bf16 bf16x4 __attribute__((ext_vector_type(4)));
typedef float f32x4 __attribute__((ext_vector_type(4)));
typedef unsigned int u32;

#define GLOBAL_AS __attribute__((address_space(1)))
#define LDS_AS __attribute__((address_space(3)))

__device__ __forceinline__ void async16(void* lds, const void* g) {
    __builtin_amdgcn_global_load_lds((const GLOBAL_AS u32*)g, (LDS_AS u32*)lds, 16, 0, 0);
}

// ---------------------------------------------------------------- fused prep
__device__ __forceinline__ void cvt8(const float* __restrict__ src, bf16* __restrict__ dst, int i) {
    const float4* s4 = (const float4*)src;
    float4 a = s4[2 * i], b = s4[2 * i + 1];
    bf16x8 o;
    o[0] = (bf16)a.x; o[1] = (bf16)a.y; o[2] = (bf16)a.z; o[3] = (bf16)a.w;
    o[4] = (bf16)b.x; o[5] = (bf16)b.y; o[6] = (bf16)b.z; o[7] = (bf16)b.w;
    ((bf16x8*)dst)[i] = o;
}

__global__ __launch_bounds__(256) void prep_kernel(
    const float* __restrict__ hidden,
    const float* __restrict__ Wq, const float* __restrict__ Wk,
    const float* __restrict__ Wv, const float* __restrict__ Wo,
    const float* __restrict__ qr, const float* __restrict__ qi, const float* __restrict__ qm,
    const float* __restrict__ kr, const float* __restrict__ ki, const float* __restrict__ km,
    const float* __restrict__ vr, const float* __restrict__ vi, const float* __restrict__ vm,
    bf16* __restrict__ Xb, bf16* __restrict__ Wb, float* __restrict__ scales) {
    int gb = blockIdx.x, tid = threadIdx.x;
    if (gb < 4096) {
        cvt8(hidden, Xb, gb * 256 + tid);
    } else if (gb < 12288) {
        int zz = (gb - 4096) >> 11;
        int i = ((gb - 4096) & 2047) * 256 + tid;
        const float* src = (zz == 0) ? Wq : (zz == 1) ? Wk : (zz == 2) ? Wv : Wo;
        cvt8(src, Wb + (size_t)zz * HID2 * HID2, i);
    } else {
        int i = (gb - 12288) * 256 + tid;
        if (i < HID2) {
            const float RSQD = 0.08838834764831845f;  // 1/sqrt(128) folded into Q scale
            scales[i]            = sqrtf(qr[i] * qr[i] + qi[i] * qi[i]) * fabsf(qm[i]) * RSQD;
            scales[HID2 + i]     = sqrtf(kr[i] * kr[i] + ki[i] * ki[i]) * fabsf(km[i]);
            scales[2 * HID2 + i] = sqrtf(vr[i] * vr[i] + vi[i] * vi[i]) * fabsf(vm[i]);
        }
    }
}

// ---------------------------------------------------------------- loose GEMM (r7 core, balanced multi-tile)
// z=0,1 (Q,K): row-major bf16 out = |acc+bias|*scale.
// z=2 (V): transposed to Vt[(b*16+h)*128+d][s] via LDS epilogue transpose ->
// coalesced bf16x8 stores (256B/d-row), no write amplification.
__device__ __forceinline__ void stage12(const char* gA, const char* gB,
                                        char* sa, char* sb, int w, int lane, size_t kb) {
    int r8 = lane >> 3;
    int cx = (lane & 7) * 16;
#pragma unroll
    for (int j = 0; j < 4; ++j) {
        int r = w * 32 + j * 8 + r8;
        async16(sa + (w * 32 + j * 8) * 128,
                gA + (size_t)r * (HID2 * 2) + kb + (cx ^ ((r & 7) << 4)));
    }
#pragma unroll
    for (int j = 0; j < 8; ++j) {
        int r = w * 64 + j * 8 + r8;
        async16(sb + (w * 64 + j * 8) * 128,
                gB + (size_t)r * (HID2 * 2) + kb + (cx ^ ((r & 7) << 4)));
    }
}

__global__ __launch_bounds__(256, 2) void gemm_qkv(
    const bf16* __restrict__ X, const bf16* __restrict__ Wb,
    const float* __restrict__ bq, const float* __restrict__ bk, const float* __restrict__ bv,
    const float* __restrict__ scales, bf16* __restrict__ QKV, bf16* __restrict__ Vt) {
    __shared__ bf16 smem[128 * 64 + 256 * 64];   // 48 KB: sA | sB, reused as T in epilogue
    bf16* sA = smem;
    bf16* sB = smem + 128 * 64;
    int b0 = blockIdx.x;            // 0..511
    int tid = threadIdx.x, w = tid >> 6, lane = tid & 63;
    int wr = w >> 1, wc = w & 1;
    int l15 = lane & 15, l4 = lane >> 4;
    int xorb = (l15 & 7) << 4;
    int ntile = (b0 < 256) ? 2 : 1;

    for (int it = 0; it < ntile; ++it) {
        int t = (it == 0) ? b0 : 512 + b0;
        int p = t & 7, q = t >> 3;
        int z = q >> 5, tm = q & 31, tn = p;
        const bf16* Bt = Wb + (size_t)z * HID2 * HID2;
        const float* bias = (z == 0) ? bq : (z == 1) ? bk : bv;
        const float* scale = scales + z * HID2;
        bf16* Cout = QKV + (size_t)z * MROWS * HID2;

        const char* gA = (const char*)X + (size_t)tm * 128 * (HID2 * 2);
        const char* gB = (const char*)Bt + (size_t)tn * 256 * (HID2 * 2);
        const char* pa = (const char*)sA;
        const char* pb = (const char*)sB;

        f32x4 acc[4][8] = {};

        for (int kt = 0; kt < HID2 / 64; ++kt) {
            stage12(gA, gB, (char*)sA, (char*)sB, w, lane, (size_t)kt * 128);
            __syncthreads();
#pragma unroll
            for (int kk = 0; kk < 2; ++kk) {
                int kc = (kk * 64 + l4 * 16) ^ xorb;
                bf16x8 af[4], bg[4];
#pragma unroll
                for (int m = 0; m < 4; ++m)
                    af[m] = *(const bf16x8*)(pa + (wr * 64 + m * 16 + l15) * 128 + kc);
#pragma unroll
                for (int n = 0; n < 4; ++n)
                    bg[n] = *(const bf16x8*)(pb + (wc * 128 + n * 16 + l15) * 128 + kc);
#pragma unroll
                for (int m = 0; m < 4; ++m)
#pragma unroll
                    for (int n = 0; n < 4; ++n)
                        acc[m][n] = __builtin_amdgcn_mfma_f32_16x16x32_bf16(af[m], bg[n], acc[m][n], 0, 0, 0);
#pragma unroll
                for (int n = 0; n < 4; ++n)
                    bg[n] = *(const bf16x8*)(pb + (wc * 128 + (n + 4) * 16 + l15) * 128 + kc);
#pragma unroll
                for (int m = 0; m < 4; ++m)
#pragma unroll
                    for (int n = 0; n < 4; ++n)
                        acc[m][n + 4] = __builtin_amdgcn_mfma_f32_16x16x32_bf16(af[m], bg[n], acc[m][n + 4], 0, 0, 0);
            }
            __syncthreads();
        }

        if (z != 2) {
            // row-major epilogue
#pragma unroll
            for (int n = 0; n < 8; ++n) {
                int col = tn * 256 + wc * 128 + n * 16 + l15;
                float bv2 = bias[col];
                float sc = scale[col];
#pragma unroll
                for (int m = 0; m < 4; ++m) {
                    int row = tm * 128 + wr * 64 + m * 16 + l4 * 4;
#pragma unroll
                    for (int r = 0; r < 4; ++r)
                        Cout[(size_t)(row + r) * HID2 + col] = (bf16)(fabsf(acc[m][n][r] + bv2) * sc);
                }
            }
        } else {
            // V: LDS transpose -> coalesced Vt[(b*16+h)*128+d][s] writes.
            // T[d_local 0..127][s_local 0..127], stride 136 (pad 8).
            bf16* T = smem;
            int bb = tm >> 4;           // tile rows tm*128..+127 lie in batch bb
            for (int dh = 0; dh < 2; ++dh) {
                __syncthreads();        // T free (previous reads done)
                if (wc == dh) {
#pragma unroll
                    for (int n = 0; n < 8; ++n) {
                        int dl = n * 16 + l15;
                        int col = tn * 256 + dh * 128 + dl;
                        float bv2 = bias[col];
                        float sc = scale[col];
#pragma unroll
                        for (int m = 0; m < 4; ++m) {
                            int sl = wr * 64 + m * 16 + l4 * 4;
                            bf16x4 pv;
#pragma unroll
                            for (int r = 0; r < 4; ++r)
                                pv[r] = (bf16)(fabsf(acc[m][n][r] + bv2) * sc);
                            *(bf16x4*)(&T[dl * 136 + sl]) = pv;
                        }
                    }
                }
                __syncthreads();        // T populated
#pragma unroll
                for (int i = 0; i < 8; ++i) {
                    int dl = w * 32 + i * 4 + l4;
                    bf16x8 v = *(const bf16x8*)(&T[dl * 136 + l15 * 8]);
                    int colg = tn * 256 + dh * 128 + dl;
                    int h = colg >> 7, d = colg & 127;
                    *(bf16x8*)(Vt + ((size_t)(bb * NH + h) * ND + d) * NS + (tm & 15) * 128 + l15 * 8) = v;
                }
            }
            __syncthreads();            // T reads done before next tile's staging
        }
    }
}

// ---------------------------------------------------------------- phased GEMM (r8, for out)
__device__ __forceinline__ void stage2A(const char* gA, char* sa, int w, int lane, size_t kb) {
#pragma unroll
    for (int j = 0; j < 2; ++j) {
        int r = w * 16 + j * 8 + (lane >> 3);
        async16(sa + (w * 16 + j * 8) * 128,
                gA + (size_t)r * (HID2 * 2) + kb + (((lane & 7) * 16) ^ ((r & 7) << 4)));
    }
}
__device__ __forceinline__ void stage2B(const char* gB, char* sb, int w, int lane, int half, size_t kb) {
#pragma unroll
    for (int j = 0; j < 2; ++j) {
        int r = half * 128 + w * 16 + j * 8 + (lane >> 3);
        async16(sb + (half * 128 + w * 16 + j * 8) * 128,
                gB + (size_t)r * (HID2 * 2) + kb + (((lane & 7) * 16) ^ ((r & 7) << 4)));
    }
}

#define G_BARRIER() do { asm volatile("" ::: "memory"); __builtin_amdgcn_s_barrier(); \
                         asm volatile("" ::: "memory"); } while (0)

__global__ __launch_bounds__(512, 2) void gemm_out(
    const bf16* __restrict__ Ctx, const bf16* __restrict__ Wo,
    const float* __restrict__ bo, float* __restrict__ out) {
    __shared__ bf16 sA[3][128 * 64];
    __shared__ bf16 sB[3][256 * 64];
    const int NT = HID2 / 64;  // 32
    int bid = blockIdx.x;
    int tn = bid & 7, tm = bid >> 3;
    int tid = threadIdx.x, w = tid >> 6, lane = tid & 63;
    int wr = w >> 2, wc = w & 3;
    int l15 = lane & 15, l4 = lane >> 4;
    int xorb = (l15 & 7) << 4;

    const char* gA = (const char*)Ctx + (size_t)tm * 128 * (HID2 * 2);
    const char* gB = (const char*)Wo + (size_t)tn * 256 * (HID2 * 2);

    f32x4 acc[4][4] = {};

    stage2A(gA, (char*)sA[0], w, lane, 0);
    stage2B(gB, (char*)sB[0], w, lane, 0, 0);
    stage2B(gB, (char*)sB[0], w, lane, 1, 0);
    stage2A(gA, (char*)sA[1], w, lane, 128);
    stage2B(gB, (char*)sB[1], w, lane, 0, 128);
    stage2B(gB, (char*)sB[1], w, lane, 1, 128);
    asm volatile("s_waitcnt vmcnt(6)" ::: "memory");
    G_BARRIER();

    int cur = 0;
    for (int t = 0; t < NT; ++t) {
        const char* pa = (const char*)sA[cur];
        const char* pb = (const char*)sB[cur];
        int nb = cur + 2; if (nb >= 3) nb -= 3;
        const bool pre = (t + 2 < NT);
        size_t kb = (size_t)(t + 2) * 128;
        bf16x8 af[4], bg[4];

        {
            int kc = (l4 * 16) ^ xorb;
#pragma unroll
            for (int m = 0; m < 4; ++m)
                af[m] = *(const bf16x8*)(pa + (wr * 64 + m * 16 + l15) * 128 + kc);
#pragma unroll
            for (int n = 0; n < 4; ++n)
                bg[n] = *(const bf16x8*)(pb + (wc * 64 + n * 16 + l15) * 128 + kc);
        }
        if (pre) { stage2A(gA, (char*)sA[nb], w, lane, kb); stage2B(gB, (char*)sB[nb], w, lane, 0, kb); }
        G_BARRIER();
        asm volatile("s_waitcnt lgkmcnt(0)" ::: "memory");
        __builtin_amdgcn_sched_barrier(0);
        __builtin_amdgcn_s_setprio(1);
#pragma unroll
        for (int m = 0; m < 4; ++m)
#pragma unroll
            for (int n = 0; n < 4; ++n)
                acc[m][n] = __builtin_amdgcn_mfma_f32_16x16x32_bf16(af[m], bg[n], acc[m][n], 0, 0, 0);
        __builtin_amdgcn_s_setprio(0);
        G_BARRIER();

        {
            int kc = (64 + l4 * 16) ^ xorb;
#pragma unroll
            for (int m = 0; m < 4; ++m)
                af[m] = *(const bf16x8*)(pa + (wr * 64 + m * 16 + l15) * 128 + kc);
#pragma unroll
            for (int n = 0; n < 4; ++n)
                bg[n] = *(const bf16x8*)(pb + (wc * 64 + n * 16 + l15) * 128 + kc);
        }
        if (pre) stage2B(gB, (char*)sB[nb], w, lane, 1, kb);
        G_BARRIER();
        asm volatile("s_waitcnt lgkmcnt(0)" ::: "memory");
        __builtin_amdgcn_sched_barrier(0);
        __builtin_amdgcn_s_setprio(1);
#pragma unroll
        for (int m = 0; m < 4; ++m)
#pragma unroll
            for (int n = 0; n < 4; ++n)
                acc[m][n] = __builtin_amdgcn_mfma_f32_16x16x32_bf16(af[m], bg[n], acc[m][n], 0, 0, 0);
        __builtin_amdgcn_s_setprio(0);
        if (pre)               { asm volatile("s_waitcnt vmcnt(6)" ::: "memory"); }
        else if (t + 2 == NT)  { asm volatile("s_waitcnt vmcnt(0)" ::: "memory"); }
        G_BARRIER();

        cur = cur + 1; if (cur == 3) cur = 0;
    }

#pragma unroll
    for (int n = 0; n < 4; ++n) {
        int col = tn * 256 + wc * 64 + n * 16 + l15;
        float bv = bo[col];
#pragma unroll
        for (int m = 0; m < 4; ++m) {
            int row = tm * 128 + wr * 64 + m * 16 + l4 * 4;
#pragma unroll
            for (int r = 0; r < 4; ++r)
                out[(size_t)(row + r) * HID2 + col] = acc[m][n][r] + bv;
        }
    }
}

// ---------------------------------------------------------------- flash attention (v5)
__device__ __forceinline__ void stageKV(const char* Kp, const char* Vp,
                                        char* ksDst, char* vsDst, int w, int lane) {
#pragma unroll
    for (int i = 0; i < 4; ++i) {
        int c = (w * 4 + i) * 64 + lane;
        int key = c >> 4, s16 = c & 15;
        async16(ksDst + (size_t)(w * 4 + i) * 1024,
                Kp + (size_t)key * (HID2 * 2) + (((s16 ^ (key & 7)) << 4)));
        int d = c >> 3, s8 = c & 7;
        async16(vsDst + (size_t)(w * 4 + i) * 1024,
                Vp + (size_t)d * (NS * 2) + (((s8 ^ (d & 7)) << 4)));
    }
}

__global__ __launch_bounds__(256, 2) void flash_kernel(
    const bf16* __restrict__ Qb, const bf16* __restrict__ Kb, const bf16* __restrict__ Vt,
    const float* __restrict__ ent, const float* __restrict__ mask, bf16* __restrict__ Ctx) {
    int bid = blockIdx.x;                       // 0..511
    int qt = bid >> 5;                          // 0..15
    int bh = (bid & 7) * 4 + ((bid >> 3) & 3);  // XCD (bid%8) owns bh 4x..4x+3
    int b = bh >> 4, h = bh & 15;
    int tid = threadIdx.x, wid = tid >> 6, lane = tid & 63;
    int l15 = lane & 15, l4 = lane >> 4;
    int xorb = (l15 & 7) << 4;

    __shared__ bf16 Ks[2][64 * 128];   // 32 KB
    __shared__ bf16 Vs[2][128 * 64];   // 32 KB
    __shared__ bf16 Ps[4][32 * 64];    // 16 KB

    const bf16* Qp = Qb + ((size_t)b * NS + qt * 128) * HID2 + h * ND;
    const char* Kp = (const char*)(Kb + (size_t)b * NS * HID2 + h * ND);
    const char* Vp = (const char*)(Vt + (size_t)(b * NH + h) * ND * NS);
    const float* maskp = mask + (size_t)b * NS;

    bf16x8 qf[2][4];
#pragma unroll
    for (int m = 0; m < 2; ++m)
#pragma unroll
        for (int kk = 0; kk < 4; ++kk)
            qf[m][kk] = *(const bf16x8*)(Qp + (size_t)(wid * 32 + m * 16 + l15) * HID2 + kk * 32 + l4 * 8);

    float eb[4];
#pragma unroll
    for (int r = 0; r < 4; ++r) eb[r] = ent[h * NH + l4 * 4 + r];

    float mrun[2], lrun[2];
    mrun[0] = mrun[1] = -INFINITY;
    lrun[0] = lrun[1] = 0.f;
    f32x4 oacc[2][8] = {};

    stageKV(Kp, Vp, (char*)Ks[0], (char*)Vs[0], wid, lane);
    __syncthreads();

    for (int kt = 0; kt < NS / 64; ++kt) {
        int kb = kt & 1;
        if (kt + 1 < NS / 64)
            stageKV(Kp + (size_t)(kt + 1) * 64 * (HID2 * 2), Vp + (size_t)(kt + 1) * 128,
                    (char*)Ks[kb ^ 1], (char*)Vs[kb ^ 1], wid, lane);

        const char* ks = (const char*)Ks[kb];
        const char* vs = (const char*)Vs[kb];
        const char* ps = (const char*)Ps[wid];

        f32x4 s[2][4] = {};
#pragma unroll
        for (int kk = 0; kk < 4; ++kk) {
            bf16x8 kf[4];
#pragma unroll
            for (int n = 0; n < 4; ++n)
                kf[n] = *(const bf16x8*)(ks + (n * 16 + l15) * 256 + ((kk * 64 + l4 * 16) ^ xorb));
#pragma unroll
            for (int m = 0; m < 2; ++m)
#pragma unroll
                for (int n = 0; n < 4; ++n)
                    s[m][n] = __builtin_amdgcn_mfma_f32_16x16x32_bf16(kf[n], qf[m][kk], s[m][n], 0, 0, 0);
        }

        float4 mk[4];
#pragma unroll
        for (int n = 0; n < 4; ++n)
            mk[n] = *(const float4*)(maskp + kt * 64 + n * 16 + l4 * 4);

#pragma unroll
        for (int mq = 0; mq < 2; ++mq) {
            float sv[4][4];
#pragma unroll
            for (int n = 0; n < 4; ++n) {
                sv[n][0] = s[mq][n][0] + eb[0] + mk[n].x;
                sv[n][1] = s[mq][n][1] + eb[1] + mk[n].y;
                sv[n][2] = s[mq][n][2] + eb[2] + mk[n].z;
                sv[n][3] = s[mq][n][3] + eb[3] + mk[n].w;
            }
            float tmax = sv[0][0];
#pragma unroll
            for (int n = 0; n < 4; ++n)
#pragma unroll
                for (int r = 0; r < 4; ++r) tmax = fmaxf(tmax, sv[n][r]);
            tmax = fmaxf(tmax, __shfl_xor(tmax, 16));
            tmax = fmaxf(tmax, __shfl_xor(tmax, 32));

            if (__any(tmax > mrun[mq] + 8.0f)) {
                float mnew = fmaxf(mrun[mq], tmax);
                float corr = __expf(mrun[mq] - mnew);
                mrun[mq] = mnew;
                lrun[mq] *= corr;
#pragma unroll
                for (int r = 0; r < 4; ++r) {
                    float cr = __shfl(corr, l4 * 4 + r);
#pragma unroll
                    for (int n = 0; n < 8; ++n) oacc[mq][n][r] *= cr;
                }
            }

            float psum = 0.f;
#pragma unroll
            for (int n = 0; n < 4; ++n) {
                bf16x4 pv;
#pragma unroll
                for (int r = 0; r < 4; ++r) {
                    float p = __expf(sv[n][r] - mrun[mq]);
                    psum += p;
                    pv[r] = (bf16)p;
                }
                *(bf16x4*)((char*)ps + (mq * 16 + l15) * 128 + ((n * 32 + l4 * 8) ^ xorb)) = pv;
            }
            psum += __shfl_xor(psum, 16);
            psum += __shfl_xor(psum, 32);
            lrun[mq] += psum;
        }

#pragma unroll
        for (int kk = 0; kk < 2; ++kk) {
            bf16x8 pa[2], vb[8];
#pragma unroll
            for (int m = 0; m < 2; ++m)
                pa[m] = *(const bf16x8*)(ps + (m * 16 + l15) * 128 + ((kk * 64 + l4 * 16) ^ xorb));
#pragma unroll
            for (int n = 0; n < 8; ++n)
                vb[n] = *(const bf16x8*)(vs + (n * 16 + l15) * 128 + ((kk * 64 + l4 * 16) ^ xorb));
#pragma unroll
            for (int m = 0; m < 2; ++m)
#pragma unroll
                for (int n = 0; n < 8; ++n)
                    oacc[m][n] = __builtin_amdgcn_mfma_f32_16x16x32_bf16(pa[m], vb[n], oacc[m][n], 0, 0, 0);
        }
        __syncthreads();
    }

#pragma unroll
    for (int m = 0; m < 2; ++m) {
        float inv = 1.0f / lrun[m];
        float invr[4];
#pragma unroll
        for (int r = 0; r < 4; ++r) invr[r] = __shfl(inv, l4 * 4 + r);
#pragma unroll
        for (int r = 0; r < 4; ++r) {
            int row = qt * 128 + wid * 32 + m * 16 + l4 * 4 + r;
            bf16* Cp = Ctx + ((size_t)b * NS + row) * HID2 + h * ND;
#pragma unroll
            for (int n = 0; n < 8; ++n)
                Cp[n * 16 + l15] = (bf16)(oacc[m][n][r] * invr[r]);
        }
    }
}

// ---------------------------------------------------------------- launch
extern "C" void kernel_launch(void* const* d_in, const int* in_sizes, int n_in,
                              void* d_out, int out_size, void* d_ws, size_t ws_size,
                              hipStream_t stream) {
    const float* hidden = (const float*)d_in[0];
    const float* mask   = (const float*)d_in[1];
    const float* q_real = (const float*)d_in[2];
    const float* q_imag = (const float*)d_in[3];
    const float* q_mag  = (const float*)d_in[5];
    const float* k_real = (const float*)d_in[6];
    const float* k_imag = (const float*)d_in[7];
    const float* k_mag  = (const float*)d_in[9];
    const float* v_real = (const float*)d_in[10];
    const float* v_imag = (const float*)d_in[11];
    const float* v_mag  = (const float*)d_in[13];
    const float* Wq = (const float*)d_in[14];
    const float* bq = (const float*)d_in[15];
    const float* Wk = (const float*)d_in[16];
    const float* bk = (const float*)d_in[17];
    const float* Wv = (const float*)d_in[18];
    const float* bv = (const float*)d_in[19];
    const float* Wo = (const float*)d_in[20];
    const float* bo = (const float*)d_in[21];
    const float* ent = (const float*)d_in[22];

    char* ws = (char*)d_ws;
    bf16* Xb    = (bf16*)(ws);
    bf16* Wb    = (bf16*)(ws + 16777216);        // Wq,Wk,Wv,Wo bf16 contiguous
    bf16* Wob   = (bf16*)(ws + 41943040);
    bf16* QKV   = (bf16*)(ws + 50331648);        // Q,K bf16 (V slot unused)
    bf16* Vt    = (bf16*)(ws + 100663296);
    bf16* Ctx   = (bf16*)(ws + 117440512);
    float* scales = (float*)(ws + 134217728);

    prep_kernel<<<12296, 256, 0, stream>>>(hidden, Wq, Wk, Wv, Wo,
                                           q_real, q_imag, q_mag, k_real, k_imag, k_mag,
                                           v_real, v_imag, v_mag, Xb, Wb, scales);
    gemm_qkv<<<512, 256, 0, stream>>>(Xb, Wb, bq, bk, bv, scales, QKV, Vt);
    flash_kernel<<<512, 256, 0, stream>>>(QKV, QKV + (size_t)MROWS * HID2, Vt, ent, mask, Ctx);
    gemm_out<<<256, 512, 0, stream>>>(Ctx, Wob, bo, (float*)d_out);
}